// Round 10
// baseline (545.725 us; speedup 1.0000x reference)
//
#include <hip/hip_runtime.h>
#include <math.h>

typedef _Float16 half2_t __attribute__((ext_vector_type(2)));
typedef _Float16 half8 __attribute__((ext_vector_type(8)));
typedef float floatx4 __attribute__((ext_vector_type(4)));

__device__ __forceinline__ unsigned packh2(float a, float b) {
  half2_t h;
  h.x = (_Float16)a;
  h.y = (_Float16)b;
  return __builtin_bit_cast(unsigned, h);
}
__device__ __forceinline__ unsigned short f2h(float a) {
  return __builtin_bit_cast(unsigned short, (_Float16)a);
}
__device__ __forceinline__ float h2f(unsigned short u) {
  return (float)__builtin_bit_cast(_Float16, u);
}
__device__ __forceinline__ float dot2acc(unsigned a, unsigned b, float c) {
  half2_t ha = __builtin_bit_cast(half2_t, a);
  half2_t hb = __builtin_bit_cast(half2_t, b);
#if __has_builtin(__builtin_amdgcn_fdot2)
  return __builtin_amdgcn_fdot2(ha, hb, c, false);
#else
  c = fmaf((float)ha.x, (float)hb.x, c);
  return fmaf((float)ha.y, (float)hb.y, c);
#endif
}
__device__ __forceinline__ half8 splat8(_Float16 x) {
  half8 r;
#pragma unroll
  for (int j = 0; j < 8; ++j) r[j] = x;
  return r;
}

// ---------------- dc/ddc weight pair pack ----------------
// [0..3456): dc convs 0..2: [conv][k][cp][o] u32 f16-pairs (cin pairs)
// [3456..3600): ddc dg=2: [k][g][jp][o] u32 f16-pairs
__global__ __launch_bounds__(256) void wdcpair_k(
    const float* __restrict__ a, const float* __restrict__ b,
    const float* __restrict__ c, const float* __restrict__ d,
    unsigned* __restrict__ out) {
  int t = blockIdx.x * 256 + threadIdx.x;
  if (t < 3456) {
    int conv = t / 1152, r = t % 1152;
    int k = r / 128, cp = (r / 16) % 8, o = r & 15;
    const float* w = conv == 0 ? a : (conv == 1 ? b : c);
    out[t] = packh2(w[(o * 16 + 2 * cp) * 9 + k], w[(o * 16 + 2 * cp + 1) * 9 + k]);
  } else if (t < 3600) {
    int r = t - 3456;
    int o = r & 1, jp = (r >> 1) & 3, g = (r >> 3) & 1, k = r >> 4;
    out[t] = packh2(d[(o * 16 + g * 8 + 2 * jp) * 9 + k],
                    d[(o * 16 + g * 8 + 2 * jp + 1) * 9 + k]);
  }
}

// ---------------- MFMA prepack, 16-cin convs (K=144 pad 160, 5 chunks, 2 taps/chunk) ----------------
// conv 0..4: regular 16-cin packs; conv 5: fe0 conv1 (cin=1 padded to 16, only cin0 nonzero)
__global__ __launch_bounds__(256) void wmfma_k(
    const float* __restrict__ w0, const float* __restrict__ w1,
    const float* __restrict__ w2, const float* __restrict__ w3,
    const float* __restrict__ w4, const float* __restrict__ w5,
    unsigned short* __restrict__ out) {
  int t = blockIdx.x * 256 + threadIdx.x;
  if (t >= 15360) return;
  int conv = t / 2560, r = t % 2560;
  int c = r / 512, L = (r / 8) % 64, j = r & 7;
  int quad = L >> 4, o = L & 15;
  int k = 32 * c + quad * 8 + j;
  int tap = k >> 4, cin = k & 15;
  float v;
  if (conv == 5) {
    v = (tap < 9 && cin == 0) ? w5[o * 9 + tap] : 0.f;
  } else {
    const float* w = conv == 0 ? w0 : conv == 1 ? w1 : conv == 2 ? w2 : conv == 3 ? w3 : w4;
    v = (tap < 9) ? w[((size_t)o * 16 + cin) * 9 + tap] : 0.f;
  }
  out[t] = f2h(v);
}

// ---------------- MFMA prepack, 32-cin convs (K=tap*32+c, 9 chunks = 1 tap each) ----------------
struct W32Entry { const float* src; int cin; };
struct W32Table { W32Entry e[8]; };  // 7 used
__global__ __launch_bounds__(256) void wmfma32_k(W32Table t, unsigned short* __restrict__ out) {
  int i = blockIdx.x * 256 + threadIdx.x;
  if (i >= 7 * 4608) return;
  int conv = i / 4608, r = i % 4608;
  int tap = r / 512, L = (r / 8) % 64, j = r & 7;
  int quad = L >> 4, o = L & 15;
  int c = quad * 8 + j;
  W32Entry en = t.e[conv];
  float v = (c < en.cin) ? en.src[((size_t)o * en.cin + c) * 9 + tap] : 0.f;
  out[i] = f2h(v);
}

// ---------------- split-cin MFMA prepack for og/dog: [A: ct*5*64*8][B: ct*9*64*8] ----------------
// A covers cin 0..15 (wmfma_k format); B covers cin 16..cin-1 padded to 32 (wmfma32_k format)
struct SPEntry { const float* src; int cin; int cout; int ct; int dstoff; };
struct SPTable { SPEntry e[4]; };
__global__ __launch_bounds__(256) void wsplit_k(SPTable t, unsigned short* __restrict__ out) {
  SPEntry en = t.e[blockIdx.y];
  int aSize = en.ct * 2560;
  int bSize = (en.cin > 16) ? en.ct * 4608 : 0;
  int i = blockIdx.x * 256 + threadIdx.x;
  if (i >= aSize + bSize) return;
  float v;
  if (i < aSize) {
    int ct = i / 2560, r = i % 2560;
    int c = r / 512, L = (r / 8) % 64, j = r & 7;
    int quad = L >> 4, o16 = L & 15;
    int k = 32 * c + quad * 8 + j;
    int tap = k >> 4, cin = k & 15;
    int o = ct * 16 + o16;
    v = (tap < 9 && o < en.cout) ? en.src[((size_t)o * en.cin + cin) * 9 + tap] : 0.f;
  } else {
    int r2 = i - aSize;
    int ct = r2 / 4608, r = r2 % 4608;
    int tap = r / 512, L = (r / 8) % 64, j = r & 7;
    int quad = L >> 4, o16 = L & 15;
    int cin = quad * 8 + j;
    int o = ct * 16 + o16;
    v = (cin < en.cin - 16 && o < en.cout)
            ? en.src[((size_t)o * en.cin + 16 + cin) * 9 + tap] : 0.f;
  }
  out[en.dstoff + i] = f2h(v);
}

// ---------------- MFMA 16-cin 3x3 conv over LDS HWC-16 tile (R15-verified) ----------------
// DPS: dst position stride in u16 units (16 = packed HWC16, 18 = bank-padded pool input)
__device__ __forceinline__ void conv_mfma(
    const unsigned short* __restrict__ src, int SW,
    unsigned short* __restrict__ dst, int DPS, const half8* __restrict__ bf,
    const float* __restrict__ bias, int POS, int OW, int tid, int relu,
    int domask, int gby, int gbx, int bound) {
  const int lane = tid & 63, wid = tid >> 6;
  const int quad = lane >> 4, m = lane & 15;
  const int tap01 = quad >> 1, cin8 = (quad & 1) * 8;
  const int ntiles = (POS + 15) >> 4;
  float bs = bias[m];
  half8 zero;
#pragma unroll
  for (int j = 0; j < 8; ++j) zero[j] = (_Float16)0;
  for (int T = wid; T < ntiles; T += 4) {
    int pa = T * 16 + m;
    pa = pa < POS ? pa : POS - 1;
    int ya = pa / OW, xa = pa - ya * OW;
    floatx4 acc = {0.f, 0.f, 0.f, 0.f};
#pragma unroll
    for (int c = 0; c < 5; ++c) {
      int tap = 2 * c + tap01;
      half8 a = zero;
      if (tap < 9) {
        int dy = tap / 3, dx = tap - (tap / 3) * 3;
        a = *(const half8*)(src + ((ya + dy) * SW + xa + dx) * 16 + cin8);
      }
      acc = __builtin_amdgcn_mfma_f32_16x16x32_f16(a, bf[c], acc, 0, 0, 0);
    }
#pragma unroll
    for (int r = 0; r < 4; ++r) {
      int pd = T * 16 + quad * 4 + r;
      if (pd < POS) {
        float v = acc[r] + bs;
        if (relu) v = fmaxf(v, 0.f);
        if (domask) {
          int yd = pd / OW, xd = pd - (pd / OW) * OW;
          int gy = gby + yd, gx = gbx + xd;
          if (gy < 0 || gy >= bound || gx < 0 || gx >= bound) v = 0.f;
        }
        dst[pd * DPS + m] = f2h(v);
      }
    }
  }
}

// ---------------- MFMA 32-cin 3x3 conv over LDS HWC-32 tile -> LDS HWC-16 out ----------------
__device__ __forceinline__ void conv_mfma32(
    const unsigned short* __restrict__ src, int SW,
    unsigned short* __restrict__ dst, int DPS, const half8* __restrict__ bf,
    const float* __restrict__ bias, int POS, int OW, int tid, int relu,
    int domask, int gby, int gbx, int bound) {
  const int lane = tid & 63, wid = tid >> 6;
  const int quad = lane >> 4, m = lane & 15;
  const int ntiles = (POS + 15) >> 4;
  float bs = bias[m];
  for (int T = wid; T < ntiles; T += 4) {
    int pa = T * 16 + m;
    pa = pa < POS ? pa : POS - 1;
    int ya = pa / OW, xa = pa - ya * OW;
    floatx4 acc = {0.f, 0.f, 0.f, 0.f};
#pragma unroll
    for (int tap = 0; tap < 9; ++tap) {
      int dy = tap / 3, dx = tap - (tap / 3) * 3;
      half8 a = *(const half8*)(src + ((ya + dy) * SW + xa + dx) * 32 + quad * 8);
      acc = __builtin_amdgcn_mfma_f32_16x16x32_f16(a, bf[tap], acc, 0, 0, 0);
    }
#pragma unroll
    for (int r = 0; r < 4; ++r) {
      int pd = T * 16 + quad * 4 + r;
      if (pd < POS) {
        float v = acc[r] + bs;
        if (relu) v = fmaxf(v, 0.f);
        if (domask) {
          int yd = pd / OW, xd = pd - (pd / OW) * OW;
          int gy = gby + yd, gx = gbx + xd;
          if (gy < 0 || gy >= bound || gx < 0 || gx >= bound) v = 0.f;
        }
        dst[pd * DPS + m] = f2h(v);
      }
    }
  }
}

// ---------------- split-cin MFMA 3x3 conv (16ch stride-18 LDS + optional 32ch stride-34 LDS) ----
// NT position-tiles of 16 (NT=4: 16x16 out, NT=2: 16x8 out); out width fixed 16.
// Writes f32 (+bias, opt relu) to outLds[pd*OSTRIDE + o]. Internal barrier between reads/writes.
template <int CT, int HASB, int NT>
__device__ __forceinline__ void conv_split_mfma(
    const unsigned short* __restrict__ srcB, const unsigned short* __restrict__ srcO,
    const unsigned short* __restrict__ wbase, float* __restrict__ outLds, int OSTRIDE,
    const float* __restrict__ bias, int NOUT, int relu, int tid) {
  const int lane = tid & 63, wid = tid >> 6;
  const int quad = lane >> 4, m = lane & 15;
  const int tap01 = quad >> 1, cin8 = (quad & 1) * 8;
  half8 zero;
#pragma unroll
  for (int j = 0; j < 8; ++j) zero[j] = (_Float16)0;
  floatx4 acc[CT][NT];
#pragma unroll
  for (int ct = 0; ct < CT; ++ct)
#pragma unroll
    for (int t = 0; t < NT; ++t) acc[ct][t] = floatx4{0.f, 0.f, 0.f, 0.f};
  // pass A: cin 0..15 from srcB (stride 18 u16), 5 K-chunks (2 taps/chunk)
#pragma unroll
  for (int ct = 0; ct < CT; ++ct) {
    half8 bfA[5];
#pragma unroll
    for (int c = 0; c < 5; ++c)
      bfA[c] = *(const half8*)(wbase + ((ct * 5 + c) * 64 + lane) * 8);
#pragma unroll
    for (int t = 0; t < NT; ++t) {
      int pa = (wid + 4 * t) * 16 + m;
      int ya = pa >> 4, xa = pa & 15;
#pragma unroll
      for (int c = 0; c < 5; ++c) {
        int tap = 2 * c + tap01;
        half8 a = zero;
        if (tap < 9) {
          int dy = tap / 3, dx = tap - (tap / 3) * 3;
          a = *(const half8*)(srcB + ((ya + dy) * 18 + xa + dx) * 18 + cin8);
        }
        acc[ct][t] = __builtin_amdgcn_mfma_f32_16x16x32_f16(a, bfA[c], acc[ct][t], 0, 0, 0);
      }
    }
  }
  if (HASB) {  // pass B: cin 16.. from srcO (HWC 32-pad, stride 34 u16), 9 chunks
    const unsigned short* wb = wbase + CT * 2560;
#pragma unroll
    for (int ct = 0; ct < CT; ++ct) {
      half8 bfB[9];
#pragma unroll
      for (int c = 0; c < 9; ++c)
        bfB[c] = *(const half8*)(wb + ((ct * 9 + c) * 64 + lane) * 8);
#pragma unroll
      for (int t = 0; t < NT; ++t) {
        int pa = (wid + 4 * t) * 16 + m;
        int ya = pa >> 4, xa = pa & 15;
#pragma unroll
        for (int tap = 0; tap < 9; ++tap) {
          int dy = tap / 3, dx = tap - (tap / 3) * 3;
          half8 a = *(const half8*)(srcO + ((ya + dy) * 18 + xa + dx) * 34 + quad * 8);
          acc[ct][t] = __builtin_amdgcn_mfma_f32_16x16x32_f16(a, bfB[tap], acc[ct][t], 0, 0, 0);
        }
      }
    }
  }
  __syncthreads();  // all LDS reads complete; safe to overwrite with output
#pragma unroll
  for (int ct = 0; ct < CT; ++ct) {
    int o = ct * 16 + m;
#pragma unroll
    for (int t = 0; t < NT; ++t) {
#pragma unroll
      for (int r = 0; r < 4; ++r) {
        int pd = (wid + 4 * t) * 16 + quad * 4 + r;
        if (o < NOUT) {
          float v = acc[ct][t][r] + bias[o];
          if (relu) v = fmaxf(v, 0.f);
          outLds[pd * OSTRIDE + o] = v;
        }
      }
    }
  }
}

// ---------------- fused FE level-0: conv1 via MFMA (cin padded 1->16) ----------------
__global__ __launch_bounds__(256) void fe0_fused_k(
    const float* __restrict__ refI, const float* __restrict__ unrI,
    const unsigned short* __restrict__ wm1, const float* __restrict__ b1,
    const unsigned short* __restrict__ wm2, const float* __restrict__ b2,
    float* __restrict__ outR, float* __restrict__ outU,
    unsigned short* __restrict__ outUH) {
  __shared__ __attribute__((aligned(16))) unsigned short bufA[441 * 16];
  __shared__ __attribute__((aligned(16))) unsigned short c1h[361 * 16];
  const int z = blockIdx.z;
  const int im = z >> 2, n = z & 3;
  const float* img = (im ? unrI : refI) + (size_t)n * 512 * 512;
  float* outp = (im ? outU : outR) + (size_t)n * 16 * 256 * 256;
  const int py0 = blockIdx.y * 8, px0 = blockIdx.x * 8;
  const int tid = threadIdx.x;

  half8 bf1[5], bf2[5];
  {
    const int lane = tid & 63;
#pragma unroll
    for (int c = 0; c < 5; ++c) {
      bf1[c] = *(const half8*)(wm1 + (c * 64 + lane) * 8);
      bf2[c] = *(const half8*)(wm2 + (c * 64 + lane) * 8);
    }
  }

  {
    unsigned* s32 = (unsigned*)bufA;
    for (int i = tid; i < 441; i += 256) {
      int yi = i / 21, xi = i - yi * 21;
      int gy = 2 * py0 - 3 + yi, gx = 2 * px0 - 3 + xi;
      float v = 0.f;
      if (gy >= 0 && gy < 512 && gx >= 0 && gx < 512) v = img[gy * 512 + gx];
      uint4 q0 = {packh2(v, 0.f), 0u, 0u, 0u};
      uint4 q1 = {0u, 0u, 0u, 0u};
      *(uint4*)(s32 + i * 8) = q0;
      *(uint4*)(s32 + i * 8 + 4) = q1;
    }
  }
  __syncthreads();

  conv_mfma(bufA, 21, c1h, 16, bf1, b1, 361, 19, tid, 1, 1, 2 * py0 - 2, 2 * px0 - 2, 512);
  __syncthreads();
  conv_mfma(c1h, 19, bufA, 18, bf2, b2, 289, 17, tid, 1, 0, 0, 0, 0);
  __syncthreads();

  unsigned short* stage = c1h;
  for (int i = tid; i < 1024; i += 256) {
    int c = i & 15, r = i >> 4;
    int py = r >> 3, px = r & 7;
    unsigned short m = 0;
#pragma unroll
    for (int dy = 0; dy < 3; ++dy) {
      int gy = 2 * (py0 + py) - 1 + dy;
      if (gy < 0 || gy >= 512) continue;
#pragma unroll
      for (int dx = 0; dx < 3; ++dx) {
        int gx = 2 * (px0 + px) - 1 + dx;
        if (gx < 0 || gx >= 512) continue;
        unsigned short v = bufA[((2 * py + dy) * 17 + 2 * px + dx) * 18 + c];
        m = (v > m) ? v : m;
      }
    }
    stage[r * 18 + c] = m;
  }
  __syncthreads();

  for (int i = tid; i < 1024; i += 256) {
    int c = i >> 6, r = i & 63, py = r >> 3, px = r & 7;
    unsigned short hb = stage[r * 18 + c];
    outp[((size_t)c * 256 + py0 + py) * 256 + px0 + px] = h2f(hb);
    if (im)
      outUH[(((size_t)n * 256 + py0 + py) * 256 + px0 + px) * 16 + c] = hb;
  }
}

// ---------------- fused FE level-1/2 (R15-proven) ----------------
__global__ __launch_bounds__(256) void fe12_fused_k(
    const float* __restrict__ in,
    const unsigned short* __restrict__ wm1, const float* __restrict__ b1,
    const unsigned short* __restrict__ wm2, const float* __restrict__ b2,
    float* __restrict__ outC, unsigned short* __restrict__ outHWC, int Hin) {
  __shared__ __attribute__((aligned(16))) unsigned short inh[441 * 16];
  __shared__ __attribute__((aligned(16))) unsigned short c1h[361 * 16];
  const int n = blockIdx.z;
  const int Ho = Hin >> 1;
  const int py0 = blockIdx.y * 8, px0 = blockIdx.x * 8;
  const int tid = threadIdx.x;
  const float* inN = in + (size_t)n * 16 * Hin * Hin;
  const size_t HH = (size_t)Hin * Hin;

  half8 bf1[5], bf2[5];
  {
    const int lane = tid & 63;
#pragma unroll
    for (int c = 0; c < 5; ++c) {
      bf1[c] = *(const half8*)(wm1 + (c * 64 + lane) * 8);
      bf2[c] = *(const half8*)(wm2 + (c * 64 + lane) * 8);
    }
  }

  unsigned* inh32 = (unsigned*)inh;
  for (int i = tid; i < 8 * 441; i += 256) {
    int cp = i / 441, r = i - cp * 441;
    int yi = r / 21, xi = r - yi * 21;
    int gy = 2 * py0 - 3 + yi, gx = 2 * px0 - 3 + xi;
    float v0 = 0.f, v1 = 0.f;
    if (gy >= 0 && gy < Hin && gx >= 0 && gx < Hin) {
      const float* s = inN + (size_t)(2 * cp) * HH + (size_t)gy * Hin + gx;
      v0 = s[0];
      v1 = s[HH];
    }
    inh32[r * 8 + cp] = packh2(v0, v1);
  }
  __syncthreads();

  conv_mfma(inh, 21, c1h, 16, bf1, b1, 361, 19, tid, 1, 1, 2 * py0 - 2, 2 * px0 - 2, Hin);
  __syncthreads();
  conv_mfma(c1h, 19, inh, 18, bf2, b2, 289, 17, tid, 1, 0, 0, 0, 0);
  __syncthreads();

  unsigned short* stage = c1h;
  for (int i = tid; i < 1024; i += 256) {
    int c = i & 15, r = i >> 4;
    int py = r >> 3, px = r & 7;
    unsigned short m = 0;
#pragma unroll
    for (int dy = 0; dy < 3; ++dy) {
      int gy = 2 * (py0 + py) - 1 + dy;
      if (gy < 0 || gy >= Hin) continue;
#pragma unroll
      for (int dx = 0; dx < 3; ++dx) {
        int gx = 2 * (px0 + px) - 1 + dx;
        if (gx < 0 || gx >= Hin) continue;
        unsigned short v = inh[((2 * py + dy) * 17 + 2 * px + dx) * 18 + c];
        m = (v > m) ? v : m;
      }
    }
    stage[r * 18 + c] = m;
  }
  __syncthreads();

  float* outp = outC + (size_t)n * 16 * Ho * Ho;
  for (int i = tid; i < 1024; i += 256) {
    int c = i >> 6, r = i & 63, py = r >> 3, px = r & 7;
    unsigned short hb = stage[r * 18 + c];
    outp[((size_t)c * Ho + py0 + py) * Ho + px0 + px] = h2f(hb);
    if (n >= 4)
      outHWC[(((size_t)(n - 4) * Ho + py0 + py) * Ho + px0 + px) * 16 + c] = hb;
  }
}

// ---------------- fused offset head (16x8 tiles): ob(MFMA) -> og(split MFMA) -> offs ----------------
template <int HAS_UP>
__global__ __launch_bounds__(256) void obog_k(
    const float* __restrict__ rf, const float* __restrict__ uf,
    const float* __restrict__ offsUp,
    const unsigned short* __restrict__ wmob, const float* __restrict__ bob,
    const unsigned short* __restrict__ wog, const float* __restrict__ bog,
    float* __restrict__ offsOut, int H) {
  // POOL u32: [0..3840) input HWC-32 12x20 / offs-up HWC-17 (3060) / og-out f32 s19 (2432)
  //           [3840..5460) ob-out HWC-16 10x18 stride-18 u16
  __shared__ __attribute__((aligned(16))) unsigned POOL[5460];
  const int n = blockIdx.z;
  const int bx = blockIdx.x * 16, by = blockIdx.y * 8;
  const int tid = threadIdx.x;
  const size_t HH = (size_t)H * H;
  const float* r0 = rf + (size_t)n * 16 * HH;
  const float* u0 = uf + (size_t)n * 16 * HH;

  for (int i = tid; i < 3840; i += 256) {
    int cp = i / 240, r = i - cp * 240;
    int ly = r / 20, lx = r - ly * 20;
    int gy = by + ly - 2, gx = bx + lx - 2;
    float v0 = 0.f, v1 = 0.f;
    if (gy >= 0 && gy < H && gx >= 0 && gx < H) {
      const float* s = (cp < 8) ? r0 + (size_t)(2 * cp) * HH : u0 + (size_t)(2 * cp - 16) * HH;
      size_t off = (size_t)gy * H + gx;
      v0 = s[off];
      v1 = s[HH + off];
    }
    POOL[r * 16 + cp] = packh2(v0, v1);
  }
  __syncthreads();

  {
    half8 bf[9];
    const int lane = tid & 63;
#pragma unroll
    for (int c = 0; c < 9; ++c) bf[c] = *(const half8*)(wmob + (c * 64 + lane) * 8);
    conv_mfma32((const unsigned short*)POOL, 20, (unsigned short*)(POOL + 3840), 18,
                bf, bob, 180, 18, tid, 1, 1, by - 1, bx - 1, H);
  }
  __syncthreads();

  if (HAS_UP) {  // stage up2(offsUp) as HWC (18ch pad 32) stride-17 u32, overlaying input region
    const int H2 = H >> 1;
    const float* os = offsUp + (size_t)n * 18 * H2 * H2;
    for (int i = tid; i < 16 * 180; i += 256) {
      int cp = i / 180, r = i - cp * 180;
      unsigned val = 0u;
      if (cp < 9) {
        int y1 = r / 18, x1 = r - y1 * 18;
        int gy = by + y1 - 1, gx = bx + x1 - 1;
        if (gy >= 0 && gy < H && gx >= 0 && gx < H) {
          float sy = 0.5f * gy - 0.25f, sx = 0.5f * gx - 0.25f;
          float y0f = floorf(sy), x0f = floorf(sx);
          float wy = sy - y0f, wx = sx - x0f;
          int y0 = (int)y0f, x0 = (int)x0f;
          int y0c = min(max(y0, 0), H2 - 1), y1c = min(max(y0 + 1, 0), H2 - 1);
          int x0c = min(max(x0, 0), H2 - 1), x1c = min(max(x0 + 1, 0), H2 - 1);
          const float* sp = os + (size_t)(2 * cp) * H2 * H2;
          float v0 = (1.f - wy) * ((1.f - wx) * sp[y0c * H2 + x0c] + wx * sp[y0c * H2 + x1c]) +
                     wy * ((1.f - wx) * sp[y1c * H2 + x0c] + wx * sp[y1c * H2 + x1c]);
          sp += (size_t)H2 * H2;
          float v1 = (1.f - wy) * ((1.f - wx) * sp[y0c * H2 + x0c] + wx * sp[y0c * H2 + x1c]) +
                     wy * ((1.f - wx) * sp[y1c * H2 + x0c] + wx * sp[y1c * H2 + x1c]);
          val = packh2(v0, v1);
        }
      }
      POOL[r * 17 + cp] = val;
    }
    __syncthreads();
  }

  // og: split MFMA (16ch ob-out + optional 18ch offs-up), relu, f32 out stride 19, 128 pos
  conv_split_mfma<2, HAS_UP, 2>((const unsigned short*)(POOL + 3840),
                                (const unsigned short*)POOL, wog,
                                (float*)POOL, 19, bog, 18, 1, tid);
  __syncthreads();

  {
    int pix = tid & 127, half = tid >> 7;
    const float* of = (const float*)POOL + (size_t)pix * 19 + half * 9;
    int ty = pix >> 4, tx = pix & 15;
    float* op = offsOut + (size_t)n * 18 * HH + (size_t)(half * 9) * HH +
                (size_t)(by + ty) * H + (bx + tx);
#pragma unroll
    for (int o = 0; o < 9; ++o) op[(size_t)o * HH] = of[o];
  }
}

// ---------------- fused feature head: deform(f16 pk blend + dot2 MAC) -> fc(MFMA) ----------------
template <int HAS_UP>
__global__ __launch_bounds__(256) void defc_k(
    const unsigned short* __restrict__ ufHWC, const float* __restrict__ offs,
    const unsigned* __restrict__ wdc2, const float* __restrict__ featsUp,
    const unsigned short* __restrict__ wmfc, const float* __restrict__ bfc,
    float* __restrict__ featsOut, unsigned short* __restrict__ outHwc, int H) {
  __shared__ __attribute__((aligned(16))) unsigned ldsC[180 * 17];  // 10x18 HWC-32 + 1-u32 pad
  const int n = blockIdx.z;
  const int bx = blockIdx.x * 16, by = blockIdx.y * 8;
  const int tid = threadIdx.x;
  const size_t HH = (size_t)H * H;
  const unsigned short* inN = ufHWC + (size_t)n * HH * 16;
  const float* offN = offs + (size_t)n * 18 * HH;

  half8 bf[9];
  {
    const int lane = tid & 63;
#pragma unroll
    for (int c = 0; c < 9; ++c) bf[c] = *(const half8*)(wmfc + (c * 64 + lane) * 8);
  }

  for (int p = tid; p < 180; p += 256) {
    int y1 = p / 18, x1 = p - y1 * 18;
    int h = by + y1 - 1, w = bx + x1 - 1;
    bool valid = (h >= 0 && h < H && w >= 0 && w < H);
    float acc[16];
#pragma unroll
    for (int o = 0; o < 16; ++o) acc[o] = 0.f;
    if (valid) {
      size_t hw = (size_t)h * H + w;
#pragma unroll
      for (int k = 0; k < 9; ++k) {
        int ky = k / 3 - 1, kx = k % 3 - 1;
        float oy = offN[(size_t)(2 * k) * HH + hw];
        float ox = offN[(size_t)(2 * k + 1) * HH + hw];
        float py = (float)(h + ky) + oy;
        float px = (float)(w + kx) + ox;
        float y0f = floorf(py), x0f = floorf(px);
        float fy = py - y0f, fx = px - x0f;
        int y0 = (int)y0f, x0 = (int)x0f;
        bool vy0 = ((unsigned)y0 < (unsigned)H);
        bool vy1 = ((unsigned)(y0 + 1) < (unsigned)H);
        bool vx0 = ((unsigned)x0 < (unsigned)H);
        bool vx1 = ((unsigned)(x0 + 1) < (unsigned)H);
        int y0c = min(max(y0, 0), H - 1), y1c = min(max(y0 + 1, 0), H - 1);
        int x0c = min(max(x0, 0), H - 1), x1c = min(max(x0 + 1, 0), H - 1);
        float w00 = (vy0 && vx0) ? (1.f - fy) * (1.f - fx) : 0.f;
        float w01 = (vy0 && vx1) ? (1.f - fy) * fx : 0.f;
        float w10 = (vy1 && vx0) ? fy * (1.f - fx) : 0.f;
        float w11 = (vy1 && vx1) ? fy * fx : 0.f;
        half8 s00 = splat8((_Float16)w00);
        half8 s01 = splat8((_Float16)w01);
        half8 s10 = splat8((_Float16)w10);
        half8 s11 = splat8((_Float16)w11);
        const unsigned short* p00 = inN + ((size_t)y0c * H + x0c) * 16;
        const unsigned short* p01 = inN + ((size_t)y0c * H + x1c) * 16;
        const unsigned short* p10 = inN + ((size_t)y1c * H + x0c) * 16;
        const unsigned short* p11 = inN + ((size_t)y1c * H + x1c) * 16;
        const unsigned* wk2 = wdc2 + k * 128;
#pragma unroll
        for (int c8 = 0; c8 < 2; ++c8) {
          half8 a00 = *(const half8*)(p00 + c8 * 8);
          half8 a01 = *(const half8*)(p01 + c8 * 8);
          half8 a10 = *(const half8*)(p10 + c8 * 8);
          half8 a11 = *(const half8*)(p11 + c8 * 8);
          half8 vb = a00 * s00 + a01 * s01 + a10 * s10 + a11 * s11;
          uint4 vp = __builtin_bit_cast(uint4, vb);
          unsigned vpa[4] = {vp.x, vp.y, vp.z, vp.w};
#pragma unroll
          for (int jp = 0; jp < 4; ++jp) {
            const unsigned* wrow = wk2 + (c8 * 4 + jp) * 16;
#pragma unroll
            for (int o = 0; o < 16; ++o)
              acc[o] = dot2acc(vpa[jp], wrow[o], acc[o]);
          }
        }
      }
    }
#pragma unroll
    for (int cc = 0; cc < 8; ++cc) {
      float a0 = valid ? fmaxf(acc[2 * cc], 0.f) : 0.f;
      float a1 = valid ? fmaxf(acc[2 * cc + 1], 0.f) : 0.f;
      ldsC[p * 17 + cc] = packh2(a0, a1);
      if (!HAS_UP) ldsC[p * 17 + 8 + cc] = 0u;
    }
  }

  if (HAS_UP) {  // up2(featsUp) -> channels 16..31
    const int H2 = H >> 1;
    const float* fu = featsUp + (size_t)n * 16 * H2 * H2;
    for (int i = tid; i < 8 * 180; i += 256) {
      int cp = i / 180, r = i - cp * 180;
      int y1 = r / 18, x1 = r - y1 * 18;
      int gy = by + y1 - 1, gx = bx + x1 - 1;
      float v0 = 0.f, v1 = 0.f;
      if (gy >= 0 && gy < H && gx >= 0 && gx < H) {
        float sy = 0.5f * gy - 0.25f, sx = 0.5f * gx - 0.25f;
        float y0f = floorf(sy), x0f = floorf(sx);
        float wy = sy - y0f, wx = sx - x0f;
        int y0 = (int)y0f, x0 = (int)x0f;
        int y0c = min(max(y0, 0), H2 - 1), y1c = min(max(y0 + 1, 0), H2 - 1);
        int x0c = min(max(x0, 0), H2 - 1), x1c = min(max(x0 + 1, 0), H2 - 1);
        const float* sp = fu + (size_t)(2 * cp) * H2 * H2;
        v0 = (1.f - wy) * ((1.f - wx) * sp[y0c * H2 + x0c] + wx * sp[y0c * H2 + x1c]) +
             wy * ((1.f - wx) * sp[y1c * H2 + x0c] + wx * sp[y1c * H2 + x1c]);
        sp += (size_t)H2 * H2;
        v1 = (1.f - wy) * ((1.f - wx) * sp[y0c * H2 + x0c] + wx * sp[y0c * H2 + x1c]) +
             wy * ((1.f - wx) * sp[y1c * H2 + x0c] + wx * sp[y1c * H2 + x1c]);
      }
      ldsC[r * 17 + 8 + cp] = packh2(v0, v1);
    }
  }
  __syncthreads();

  // fc via MFMA: 128 output positions (8x16), pos stride 34 u16
  {
    const int lane = tid & 63, wid = tid >> 6;
    const int quad = lane >> 4, m = lane & 15;
    const unsigned short* src = (const unsigned short*)ldsC;
    float bs = bfc[m];
    for (int T = wid; T < 8; T += 4) {
      int pa = T * 16 + m;
      int ya = pa >> 4, xa = pa & 15;
      floatx4 acc = {0.f, 0.f, 0.f, 0.f};
#pragma unroll
      for (int tap = 0; tap < 9; ++tap) {
        int dy = tap / 3, dx = tap - (tap / 3) * 3;
        half8 a = *(const half8*)(src + ((ya + dy) * 18 + xa + dx) * 34 + quad * 8);
        acc = __builtin_amdgcn_mfma_f32_16x16x32_f16(a, bf[tap], acc, 0, 0, 0);
      }
#pragma unroll
      for (int r = 0; r < 4; ++r) {
        int pd = T * 16 + quad * 4 + r;
        int yd = pd >> 4, xd = pd & 15;
        float v = fmaxf(acc[r] + bs, 0.f);
        if (featsOut)
          featsOut[(size_t)n * 16 * HH + (size_t)m * HH + (size_t)(by + yd) * H + bx + xd] = v;
        if (outHwc)
          outHwc[((size_t)n * HH + (size_t)(by + yd) * H + bx + xd) * 16 + m] = f2h(v);
      }
    }
  }
}

// ---------------- fused final head (16x16): dob -> dog(split MFMA) -> deform dg=2 (pk+dot2) ----
__global__ __launch_bounds__(256) void final_k(
    const float* __restrict__ rf0, const unsigned short* __restrict__ f0hwc,
    const float* __restrict__ offs0,
    const unsigned short* __restrict__ wmdob, const float* __restrict__ bdob,
    const unsigned short* __restrict__ wdog, const float* __restrict__ bdog,
    const unsigned* __restrict__ wddc2, float* __restrict__ out) {
  // POOL u32 regions: [0..6400) input HWC-32 / offs0 HWC-17 / a36 f32 stride-37 (spans all)
  //                   [6400..9316) dob-out HWC-16 stride-18 u16
  __shared__ __attribute__((aligned(16))) unsigned POOL[9472];
  const int H = 256;
  const size_t HH = 65536;
  const int n = blockIdx.z;
  const int bx = blockIdx.x * 16, by = blockIdx.y * 16;
  const int tid = threadIdx.x;
  const float* r0 = rf0 + (size_t)n * 16 * HH;
  const unsigned short* f0h = f0hwc + (size_t)n * HH * 16;

  for (int i = tid; i < 6400; i += 256) {
    int cp = i / 400, r = i - cp * 400;
    int ly = r / 20, lx = r - ly * 20;
    int gy = by + ly - 2, gx = bx + lx - 2;
    unsigned val = 0u;
    if (gy >= 0 && gy < H && gx >= 0 && gx < H) {
      if (cp < 8) {
        const float* s = r0 + (size_t)(2 * cp) * HH + (size_t)gy * H + gx;
        val = packh2(s[0], s[HH]);
      } else {
        val = *(const unsigned*)(f0h + ((size_t)gy * H + gx) * 16 + (2 * cp - 16));
      }
    }
    POOL[r * 16 + cp] = val;
  }
  __syncthreads();

  {
    half8 bf[9];
    const int lane = tid & 63;
#pragma unroll
    for (int c = 0; c < 9; ++c) bf[c] = *(const half8*)(wmdob + (c * 64 + lane) * 8);
    conv_mfma32((const unsigned short*)POOL, 20, (unsigned short*)(POOL + 6400), 18,
                bf, bdob, 324, 18, tid, 0, 1, by - 1, bx - 1, H);
  }
  __syncthreads();

  {  // stage offs0 as HWC (18ch pad 32) stride-17 u32, overlaying input region
    const float* os = offs0 + (size_t)n * 18 * HH;
    for (int i = tid; i < 16 * 324; i += 256) {
      int cp = i / 324, r = i - cp * 324;
      unsigned val = 0u;
      if (cp < 9) {
        int y1 = r / 18, x1 = r - y1 * 18;
        int gy = by + y1 - 1, gx = bx + x1 - 1;
        if (gy >= 0 && gy < H && gx >= 0 && gx < H) {
          const float* s = os + (size_t)(2 * cp) * HH + (size_t)gy * H + gx;
          val = packh2(s[0], s[HH]);
        }
      }
      POOL[r * 17 + cp] = val;
    }
    __syncthreads();
  }

  // dog: split MFMA (16ch dob-out + 18ch offs0), no relu, f32 out stride 37
  conv_split_mfma<3, 1, 4>((const unsigned short*)(POOL + 6400),
                           (const unsigned short*)POOL, wdog,
                           (float*)POOL, 37, bdog, 36, 0, tid);
  __syncthreads();

  {
    const int ty = tid >> 4, tx = tid & 15;
    const int h = by + ty, w = bx + tx;
    const float* a36 = (const float*)POOL + (size_t)tid * 37;
    float rr[2] = {0.f, 0.f};
#pragma unroll
    for (int g = 0; g < 2; ++g) {
#pragma unroll
      for (int k = 0; k < 9; ++k) {
        int ky = k / 3 - 1, kx = k % 3 - 1;
        float oy = a36[(g * 9 + k) * 2 + 0];
        float ox = a36[(g * 9 + k) * 2 + 1];
        float py = (float)(h + ky) + oy;
        float px = (float)(w + kx) + ox;
        float y0f = floorf(py), x0f = floorf(px);
        float fy = py - y0f, fx = px - x0f;
        int y0 = (int)y0f, x0 = (int)x0f;
        bool vy0 = ((unsigned)y0 < (unsigned)H);
        bool vy1 = ((unsigned)(y0 + 1) < (unsigned)H);
        bool vx0 = ((unsigned)x0 < (unsigned)H);
        bool vx1 = ((unsigned)(x0 + 1) < (unsigned)H);
        int y0c = min(max(y0, 0), H - 1), y1c = min(max(y0 + 1, 0), H - 1);
        int x0c = min(max(x0, 0), H - 1), x1c = min(max(x0 + 1, 0), H - 1);
        float w00 = (vy0 && vx0) ? (1.f - fy) * (1.f - fx) : 0.f;
        float w01 = (vy0 && vx1) ? (1.f - fy) * fx : 0.f;
        float w10 = (vy1 && vx0) ? fy * (1.f - fx) : 0.f;
        float w11 = (vy1 && vx1) ? fy * fx : 0.f;
        half8 s00 = splat8((_Float16)w00);
        half8 s01 = splat8((_Float16)w01);
        half8 s10 = splat8((_Float16)w10);
        half8 s11 = splat8((_Float16)w11);
        const unsigned short* p00 = f0h + ((size_t)y0c * H + x0c) * 16 + g * 8;
        const unsigned short* p01 = f0h + ((size_t)y0c * H + x1c) * 16 + g * 8;
        const unsigned short* p10 = f0h + ((size_t)y1c * H + x0c) * 16 + g * 8;
        const unsigned short* p11 = f0h + ((size_t)y1c * H + x1c) * 16 + g * 8;
        half8 a00 = *(const half8*)p00;
        half8 a01 = *(const half8*)p01;
        half8 a10 = *(const half8*)p10;
        half8 a11 = *(const half8*)p11;
        half8 vb = a00 * s00 + a01 * s01 + a10 * s10 + a11 * s11;
        uint4 vp = __builtin_bit_cast(uint4, vb);
        unsigned vpa[4] = {vp.x, vp.y, vp.z, vp.w};
        const unsigned* wk2 = wddc2 + ((size_t)k * 2 + g) * 8;
#pragma unroll
        for (int jp = 0; jp < 4; ++jp) {
          rr[0] = dot2acc(vpa[jp], wk2[jp * 2 + 0], rr[0]);
          rr[1] = dot2acc(vpa[jp], wk2[jp * 2 + 1], rr[1]);
        }
      }
    }
    out[((size_t)n * 2 + 0) * HH + (size_t)h * H + w] = rr[0];
    out[((size_t)n * 2 + 1) * HH + (size_t)h * H + w] = rr[1];
  }
}

extern "C" void kernel_launch(void* const* d_in, const int* in_sizes, int n_in,
                              void* d_out, int out_size, void* d_ws, size_t ws_size,
                              hipStream_t stream) {
  auto F = [&](int i) { return (const float*)d_in[i]; };
  const float* ref = F(0);
  const float* unr = F(1);
  const float* few1[3] = {F(2), F(6), F(10)};
  const float* feb1[3] = {F(3), F(7), F(11)};
  const float* few2[3] = {F(4), F(8), F(12)};
  const float* feb2[3] = {F(5), F(9), F(13)};
  const float* obw[3] = {F(14), F(16), F(18)};
  const float* obb[3] = {F(15), F(17), F(19)};
  const float* ogw[3] = {F(20), F(22), F(24)};
  const float* ogb[3] = {F(21), F(23), F(25)};
  const float* dcw[3] = {F(26), F(27), F(28)};
  const float* fcw[3] = {F(29), F(31), F(33)};
  const float* fcb[3] = {F(30), F(32), F(34)};
  const float* dobw = F(35);
  const float* dobb = F(36);
  const float* dogw = F(37);
  const float* dogb = F(38);
  const float* ddcw = F(39);

  // ---- workspace (floats) ----
  float* ws = (float*)d_ws;
  size_t p = 0;
  auto alloc = [&](size_t nf) { float* r = ws + p; p += nf; return r; };
  float* rf0 = alloc((size_t)4 * 16 * 65536);
  float* uf0 = alloc((size_t)4 * 16 * 65536);
  float* rf1 = alloc((size_t)4 * 16 * 16384);
  float* uf1 = alloc((size_t)4 * 16 * 16384);
  float* rf2 = alloc((size_t)4 * 16 * 4096);
  float* uf2 = alloc((size_t)4 * 16 * 4096);
  float* offs0 = alloc((size_t)4 * 18 * 65536);
  float* offs1 = alloc((size_t)4 * 18 * 16384);
  float* offs2 = alloc((size_t)4 * 18 * 4096);
  float* feats1 = alloc((size_t)4 * 16 * 16384);
  float* feats2 = alloc((size_t)4 * 16 * 4096);
  unsigned short* ufH0 = (unsigned short*)alloc((size_t)4 * 16 * 65536 / 2);  // f16 HWC
  unsigned short* ufH1 = (unsigned short*)alloc((size_t)4 * 16 * 16384 / 2);
  unsigned short* ufH2 = (unsigned short*)alloc((size_t)4 * 16 * 4096 / 2);
  unsigned short* fHwc = (unsigned short*)alloc((size_t)4 * 16 * 65536 / 2);
  float* wdc2f = alloc(3600);   // dc dot2 pairs (3456) + ddc pairs (144)
  float* wmf = alloc(7680);     // 16-cin MFMA pack: 15360 u16 (5 convs + fe0 conv1)
  float* wm32f = alloc(16200);  // 32-cin MFMA pack: 32256 u16
  float* wspl = alloc(27648);   // split packs og0/og1/og2/dog: 55296 u16
  if (p * sizeof(float) > ws_size) return;
  unsigned* wdc2 = (unsigned*)wdc2f;
  unsigned short* wmh = (unsigned short*)wmf;
  unsigned short* wm32 = (unsigned short*)wm32f;
  unsigned short* wsp = (unsigned short*)wspl;

  // ---- 32-cin MFMA table: ob0 ob1 ob2 dob fc0 fc1 fc2(pad) ----
  W32Table T32;
  T32.e[0] = {obw[0], 32}; T32.e[1] = {obw[1], 32}; T32.e[2] = {obw[2], 32};
  T32.e[3] = {dobw, 32};   T32.e[4] = {fcw[0], 32}; T32.e[5] = {fcw[1], 32};
  T32.e[6] = {fcw[2], 16};
  auto o32 = [](int i) { return i * 4608; };

  // ---- split-pack table: og0, og1, og2(A only), dog ----
  SPTable TS;
  TS.e[0] = {ogw[0], 34, 18, 2, 0};
  TS.e[1] = {ogw[1], 34, 18, 2, 14336};
  TS.e[2] = {ogw[2], 16, 18, 2, 28672};
  TS.e[3] = {dogw, 34, 36, 3, 33792};
  const int o_og[3] = {0, 14336, 28672};
  const int o_dog = 33792;

  wdcpair_k<<<15, 256, 0, stream>>>(dcw[0], dcw[1], dcw[2], ddcw, wdc2);
  wmfma_k<<<60, 256, 0, stream>>>(few2[0], few1[1], few2[1], few1[2], few2[2],
                                  few1[0], wmh);
  wmfma32_k<<<126, 256, 0, stream>>>(T32, wm32);
  wsplit_k<<<dim3(84, 4), 256, 0, stream>>>(TS, wsp);

  // ---- feature pyramids ----
  fe0_fused_k<<<dim3(32, 32, 8), 256, 0, stream>>>(
      ref, unr, wmh + 5 * 2560, feb1[0], wmh, feb2[0], rf0, uf0, ufH0);
  fe12_fused_k<<<dim3(16, 16, 8), 256, 0, stream>>>(
      rf0, wmh + 2560, feb1[1], wmh + 2 * 2560, feb2[1], rf1, ufH1, 256);
  fe12_fused_k<<<dim3(8, 8, 8), 256, 0, stream>>>(
      rf1, wmh + 3 * 2560, feb1[2], wmh + 4 * 2560, feb2[2], rf2, ufH2, 128);

  // ---- coarse-to-fine: fused [ob->og] then [deform->fc] per level ----
  obog_k<0><<<dim3(4, 8, 4), 256, 0, stream>>>(
      rf2, uf2, nullptr, wm32 + o32(2), obb[2], wsp + o_og[2], ogb[2], offs2, 64);
  defc_k<0><<<dim3(4, 8, 4), 256, 0, stream>>>(
      ufH2, offs2, wdc2 + 2 * 1152, nullptr, wm32 + o32(6), fcb[2], feats2, nullptr, 64);
  obog_k<1><<<dim3(8, 16, 4), 256, 0, stream>>>(
      rf1, uf1, offs2, wm32 + o32(1), obb[1], wsp + o_og[1], ogb[1], offs1, 128);
  defc_k<1><<<dim3(8, 16, 4), 256, 0, stream>>>(
      ufH1, offs1, wdc2 + 1 * 1152, feats2, wm32 + o32(5), fcb[1], feats1, nullptr, 128);
  obog_k<1><<<dim3(16, 32, 4), 256, 0, stream>>>(
      rf0, uf0, offs1, wm32 + o32(0), obb[0], wsp + o_og[0], ogb[0], offs0, 256);
  defc_k<1><<<dim3(16, 32, 4), 256, 0, stream>>>(
      ufH0, offs0, wdc2, feats1, wm32 + o32(4), fcb[0], nullptr, fHwc, 256);

  // ---- fused final head (16x16 tiles, pk blend + dot2 tail) ----
  final_k<<<dim3(16, 16, 4), 256, 0, stream>>>(
      rf0, fHwc, offs0, wm32 + o32(3), dobb, wsp + o_dog, dogb, wdc2 + 3456,
      (float*)d_out);
}

// Round 11
// 540.779 us; speedup vs baseline: 1.0091x; 1.0091x over previous
//
#include <hip/hip_runtime.h>
#include <math.h>

typedef _Float16 half2_t __attribute__((ext_vector_type(2)));
typedef _Float16 half8 __attribute__((ext_vector_type(8)));
typedef float floatx4 __attribute__((ext_vector_type(4)));

__device__ __forceinline__ unsigned packh2(float a, float b) {
  half2_t h;
  h.x = (_Float16)a;
  h.y = (_Float16)b;
  return __builtin_bit_cast(unsigned, h);
}
__device__ __forceinline__ unsigned short f2h(float a) {
  return __builtin_bit_cast(unsigned short, (_Float16)a);
}
__device__ __forceinline__ float h2f(unsigned short u) {
  return (float)__builtin_bit_cast(_Float16, u);
}
__device__ __forceinline__ float dot2acc(unsigned a, unsigned b, float c) {
  half2_t ha = __builtin_bit_cast(half2_t, a);
  half2_t hb = __builtin_bit_cast(half2_t, b);
#if __has_builtin(__builtin_amdgcn_fdot2)
  return __builtin_amdgcn_fdot2(ha, hb, c, false);
#else
  c = fmaf((float)ha.x, (float)hb.x, c);
  return fmaf((float)ha.y, (float)hb.y, c);
#endif
}
__device__ __forceinline__ half8 splat8(_Float16 x) {
  half8 r;
#pragma unroll
  for (int j = 0; j < 8; ++j) r[j] = x;
  return r;
}

// ---------------- dc/ddc weight pair pack ----------------
// [0..3456): dc convs 0..2: [conv][k][cp][o] u32 f16-pairs (cin pairs)
// [3456..3600): ddc dg=2: [k][g][jp][o] u32 f16-pairs
__global__ __launch_bounds__(256) void wdcpair_k(
    const float* __restrict__ a, const float* __restrict__ b,
    const float* __restrict__ c, const float* __restrict__ d,
    unsigned* __restrict__ out) {
  int t = blockIdx.x * 256 + threadIdx.x;
  if (t < 3456) {
    int conv = t / 1152, r = t % 1152;
    int k = r / 128, cp = (r / 16) % 8, o = r & 15;
    const float* w = conv == 0 ? a : (conv == 1 ? b : c);
    out[t] = packh2(w[(o * 16 + 2 * cp) * 9 + k], w[(o * 16 + 2 * cp + 1) * 9 + k]);
  } else if (t < 3600) {
    int r = t - 3456;
    int o = r & 1, jp = (r >> 1) & 3, g = (r >> 3) & 1, k = r >> 4;
    out[t] = packh2(d[(o * 16 + g * 8 + 2 * jp) * 9 + k],
                    d[(o * 16 + g * 8 + 2 * jp + 1) * 9 + k]);
  }
}

// ---------------- MFMA prepack, 16-cin convs (K=144 pad 160, 5 chunks, 2 taps/chunk) ----------------
// conv 0..4: regular 16-cin packs; conv 5: fe0 conv1 (cin=1 padded to 16, only cin0 nonzero)
__global__ __launch_bounds__(256) void wmfma_k(
    const float* __restrict__ w0, const float* __restrict__ w1,
    const float* __restrict__ w2, const float* __restrict__ w3,
    const float* __restrict__ w4, const float* __restrict__ w5,
    unsigned short* __restrict__ out) {
  int t = blockIdx.x * 256 + threadIdx.x;
  if (t >= 15360) return;
  int conv = t / 2560, r = t % 2560;
  int c = r / 512, L = (r / 8) % 64, j = r & 7;
  int quad = L >> 4, o = L & 15;
  int k = 32 * c + quad * 8 + j;
  int tap = k >> 4, cin = k & 15;
  float v;
  if (conv == 5) {
    v = (tap < 9 && cin == 0) ? w5[o * 9 + tap] : 0.f;
  } else {
    const float* w = conv == 0 ? w0 : conv == 1 ? w1 : conv == 2 ? w2 : conv == 3 ? w3 : w4;
    v = (tap < 9) ? w[((size_t)o * 16 + cin) * 9 + tap] : 0.f;
  }
  out[t] = f2h(v);
}

// ---------------- MFMA prepack, 32-cin convs (K=tap*32+c, 9 chunks = 1 tap each) ----------------
struct W32Entry { const float* src; int cin; };
struct W32Table { W32Entry e[8]; };  // 7 used
__global__ __launch_bounds__(256) void wmfma32_k(W32Table t, unsigned short* __restrict__ out) {
  int i = blockIdx.x * 256 + threadIdx.x;
  if (i >= 7 * 4608) return;
  int conv = i / 4608, r = i % 4608;
  int tap = r / 512, L = (r / 8) % 64, j = r & 7;
  int quad = L >> 4, o = L & 15;
  int c = quad * 8 + j;
  W32Entry en = t.e[conv];
  float v = (c < en.cin) ? en.src[((size_t)o * en.cin + c) * 9 + tap] : 0.f;
  out[i] = f2h(v);
}

// ---------------- split-cin MFMA prepack for og/dog: [A: ct*5*64*8][B: ct*9*64*8] ----------------
// A covers cin 0..15 (wmfma_k format); B covers cin 16..cin-1 padded to 32 (wmfma32_k format)
struct SPEntry { const float* src; int cin; int cout; int ct; int dstoff; };
struct SPTable { SPEntry e[4]; };
__global__ __launch_bounds__(256) void wsplit_k(SPTable t, unsigned short* __restrict__ out) {
  SPEntry en = t.e[blockIdx.y];
  int aSize = en.ct * 2560;
  int bSize = (en.cin > 16) ? en.ct * 4608 : 0;
  int i = blockIdx.x * 256 + threadIdx.x;
  if (i >= aSize + bSize) return;
  float v;
  if (i < aSize) {
    int ct = i / 2560, r = i % 2560;
    int c = r / 512, L = (r / 8) % 64, j = r & 7;
    int quad = L >> 4, o16 = L & 15;
    int k = 32 * c + quad * 8 + j;
    int tap = k >> 4, cin = k & 15;
    int o = ct * 16 + o16;
    v = (tap < 9 && o < en.cout) ? en.src[((size_t)o * en.cin + cin) * 9 + tap] : 0.f;
  } else {
    int r2 = i - aSize;
    int ct = r2 / 4608, r = r2 % 4608;
    int tap = r / 512, L = (r / 8) % 64, j = r & 7;
    int quad = L >> 4, o16 = L & 15;
    int cin = quad * 8 + j;
    int o = ct * 16 + o16;
    v = (cin < en.cin - 16 && o < en.cout)
            ? en.src[((size_t)o * en.cin + 16 + cin) * 9 + tap] : 0.f;
  }
  out[en.dstoff + i] = f2h(v);
}

// ---------------- MFMA 16-cin 3x3 conv over LDS HWC-16 tile (R15-verified) ----------------
// DPS: dst position stride in u16 units (16 = packed HWC16, 18 = bank-padded pool input)
__device__ __forceinline__ void conv_mfma(
    const unsigned short* __restrict__ src, int SW,
    unsigned short* __restrict__ dst, int DPS, const half8* __restrict__ bf,
    const float* __restrict__ bias, int POS, int OW, int tid, int relu,
    int domask, int gby, int gbx, int bound) {
  const int lane = tid & 63, wid = tid >> 6;
  const int quad = lane >> 4, m = lane & 15;
  const int tap01 = quad >> 1, cin8 = (quad & 1) * 8;
  const int ntiles = (POS + 15) >> 4;
  float bs = bias[m];
  half8 zero;
#pragma unroll
  for (int j = 0; j < 8; ++j) zero[j] = (_Float16)0;
  for (int T = wid; T < ntiles; T += 4) {
    int pa = T * 16 + m;
    pa = pa < POS ? pa : POS - 1;
    int ya = pa / OW, xa = pa - ya * OW;
    floatx4 acc = {0.f, 0.f, 0.f, 0.f};
#pragma unroll
    for (int c = 0; c < 5; ++c) {
      int tap = 2 * c + tap01;
      half8 a = zero;
      if (tap < 9) {
        int dy = tap / 3, dx = tap - (tap / 3) * 3;
        a = *(const half8*)(src + ((ya + dy) * SW + xa + dx) * 16 + cin8);
      }
      acc = __builtin_amdgcn_mfma_f32_16x16x32_f16(a, bf[c], acc, 0, 0, 0);
    }
#pragma unroll
    for (int r = 0; r < 4; ++r) {
      int pd = T * 16 + quad * 4 + r;
      if (pd < POS) {
        float v = acc[r] + bs;
        if (relu) v = fmaxf(v, 0.f);
        if (domask) {
          int yd = pd / OW, xd = pd - (pd / OW) * OW;
          int gy = gby + yd, gx = gbx + xd;
          if (gy < 0 || gy >= bound || gx < 0 || gx >= bound) v = 0.f;
        }
        dst[pd * DPS + m] = f2h(v);
      }
    }
  }
}

// ---------------- MFMA 32-cin 3x3 conv over LDS HWC-32 tile -> LDS HWC-16 out ----------------
__device__ __forceinline__ void conv_mfma32(
    const unsigned short* __restrict__ src, int SW,
    unsigned short* __restrict__ dst, int DPS, const half8* __restrict__ bf,
    const float* __restrict__ bias, int POS, int OW, int tid, int relu,
    int domask, int gby, int gbx, int bound) {
  const int lane = tid & 63, wid = tid >> 6;
  const int quad = lane >> 4, m = lane & 15;
  const int ntiles = (POS + 15) >> 4;
  float bs = bias[m];
  for (int T = wid; T < ntiles; T += 4) {
    int pa = T * 16 + m;
    pa = pa < POS ? pa : POS - 1;
    int ya = pa / OW, xa = pa - ya * OW;
    floatx4 acc = {0.f, 0.f, 0.f, 0.f};
#pragma unroll
    for (int tap = 0; tap < 9; ++tap) {
      int dy = tap / 3, dx = tap - (tap / 3) * 3;
      half8 a = *(const half8*)(src + ((ya + dy) * SW + xa + dx) * 32 + quad * 8);
      acc = __builtin_amdgcn_mfma_f32_16x16x32_f16(a, bf[tap], acc, 0, 0, 0);
    }
#pragma unroll
    for (int r = 0; r < 4; ++r) {
      int pd = T * 16 + quad * 4 + r;
      if (pd < POS) {
        float v = acc[r] + bs;
        if (relu) v = fmaxf(v, 0.f);
        if (domask) {
          int yd = pd / OW, xd = pd - (pd / OW) * OW;
          int gy = gby + yd, gx = gbx + xd;
          if (gy < 0 || gy >= bound || gx < 0 || gx >= bound) v = 0.f;
        }
        dst[pd * DPS + m] = f2h(v);
      }
    }
  }
}

// ---------------- split-cin MFMA 3x3 conv (16ch stride-18 LDS + optional 32ch stride-34 LDS) ----
// NT position-tiles of 16 (NT=4: 16x16 out, NT=2: 16x8 out); out width fixed 16.
// Writes f32 (+bias, opt relu) to outLds[pd*OSTRIDE + o]. Internal barrier between reads/writes.
template <int CT, int HASB, int NT>
__device__ __forceinline__ void conv_split_mfma(
    const unsigned short* __restrict__ srcB, const unsigned short* __restrict__ srcO,
    const unsigned short* __restrict__ wbase, float* __restrict__ outLds, int OSTRIDE,
    const float* __restrict__ bias, int NOUT, int relu, int tid) {
  const int lane = tid & 63, wid = tid >> 6;
  const int quad = lane >> 4, m = lane & 15;
  const int tap01 = quad >> 1, cin8 = (quad & 1) * 8;
  half8 zero;
#pragma unroll
  for (int j = 0; j < 8; ++j) zero[j] = (_Float16)0;
  floatx4 acc[CT][NT];
#pragma unroll
  for (int ct = 0; ct < CT; ++ct)
#pragma unroll
    for (int t = 0; t < NT; ++t) acc[ct][t] = floatx4{0.f, 0.f, 0.f, 0.f};
  // pass A: cin 0..15 from srcB (stride 18 u16), 5 K-chunks (2 taps/chunk)
#pragma unroll
  for (int ct = 0; ct < CT; ++ct) {
    half8 bfA[5];
#pragma unroll
    for (int c = 0; c < 5; ++c)
      bfA[c] = *(const half8*)(wbase + ((ct * 5 + c) * 64 + lane) * 8);
#pragma unroll
    for (int t = 0; t < NT; ++t) {
      int pa = (wid + 4 * t) * 16 + m;
      int ya = pa >> 4, xa = pa & 15;
#pragma unroll
      for (int c = 0; c < 5; ++c) {
        int tap = 2 * c + tap01;
        half8 a = zero;
        if (tap < 9) {
          int dy = tap / 3, dx = tap - (tap / 3) * 3;
          a = *(const half8*)(srcB + ((ya + dy) * 18 + xa + dx) * 18 + cin8);
        }
        acc[ct][t] = __builtin_amdgcn_mfma_f32_16x16x32_f16(a, bfA[c], acc[ct][t], 0, 0, 0);
      }
    }
  }
  if (HASB) {  // pass B: cin 16.. from srcO (HWC 32-pad, stride 34 u16), 9 chunks
    const unsigned short* wb = wbase + CT * 2560;
#pragma unroll
    for (int ct = 0; ct < CT; ++ct) {
      half8 bfB[9];
#pragma unroll
      for (int c = 0; c < 9; ++c)
        bfB[c] = *(const half8*)(wb + ((ct * 9 + c) * 64 + lane) * 8);
#pragma unroll
      for (int t = 0; t < NT; ++t) {
        int pa = (wid + 4 * t) * 16 + m;
        int ya = pa >> 4, xa = pa & 15;
#pragma unroll
        for (int tap = 0; tap < 9; ++tap) {
          int dy = tap / 3, dx = tap - (tap / 3) * 3;
          half8 a = *(const half8*)(srcO + ((ya + dy) * 18 + xa + dx) * 34 + quad * 8);
          acc[ct][t] = __builtin_amdgcn_mfma_f32_16x16x32_f16(a, bfB[tap], acc[ct][t], 0, 0, 0);
        }
      }
    }
  }
  __syncthreads();  // all LDS reads complete; safe to overwrite with output
#pragma unroll
  for (int ct = 0; ct < CT; ++ct) {
    int o = ct * 16 + m;
#pragma unroll
    for (int t = 0; t < NT; ++t) {
#pragma unroll
      for (int r = 0; r < 4; ++r) {
        int pd = (wid + 4 * t) * 16 + quad * 4 + r;
        if (o < NOUT) {
          float v = acc[ct][t][r] + bias[o];
          if (relu) v = fmaxf(v, 0.f);
          outLds[pd * OSTRIDE + o] = v;
        }
      }
    }
  }
}

// ---------------- fused FE level-0: conv1 via MFMA (cin padded 1->16) ----------------
__global__ __launch_bounds__(256) void fe0_fused_k(
    const float* __restrict__ refI, const float* __restrict__ unrI,
    const unsigned short* __restrict__ wm1, const float* __restrict__ b1,
    const unsigned short* __restrict__ wm2, const float* __restrict__ b2,
    float* __restrict__ outR, float* __restrict__ outU,
    unsigned short* __restrict__ outRH, unsigned short* __restrict__ outUH) {
  __shared__ __attribute__((aligned(16))) unsigned short bufA[441 * 16];
  __shared__ __attribute__((aligned(16))) unsigned short c1h[361 * 16];
  const int z = blockIdx.z;
  const int im = z >> 2, n = z & 3;
  const float* img = (im ? unrI : refI) + (size_t)n * 512 * 512;
  float* outp = (im ? outU : outR) + (size_t)n * 16 * 256 * 256;
  unsigned short* outh = (im ? outUH : outRH) + (size_t)n * 256 * 256 * 16;
  const int py0 = blockIdx.y * 8, px0 = blockIdx.x * 8;
  const int tid = threadIdx.x;

  half8 bf1[5], bf2[5];
  {
    const int lane = tid & 63;
#pragma unroll
    for (int c = 0; c < 5; ++c) {
      bf1[c] = *(const half8*)(wm1 + (c * 64 + lane) * 8);
      bf2[c] = *(const half8*)(wm2 + (c * 64 + lane) * 8);
    }
  }

  {
    unsigned* s32 = (unsigned*)bufA;
    for (int i = tid; i < 441; i += 256) {
      int yi = i / 21, xi = i - yi * 21;
      int gy = 2 * py0 - 3 + yi, gx = 2 * px0 - 3 + xi;
      float v = 0.f;
      if (gy >= 0 && gy < 512 && gx >= 0 && gx < 512) v = img[gy * 512 + gx];
      uint4 q0 = {packh2(v, 0.f), 0u, 0u, 0u};
      uint4 q1 = {0u, 0u, 0u, 0u};
      *(uint4*)(s32 + i * 8) = q0;
      *(uint4*)(s32 + i * 8 + 4) = q1;
    }
  }
  __syncthreads();

  conv_mfma(bufA, 21, c1h, 16, bf1, b1, 361, 19, tid, 1, 1, 2 * py0 - 2, 2 * px0 - 2, 512);
  __syncthreads();
  conv_mfma(c1h, 19, bufA, 18, bf2, b2, 289, 17, tid, 1, 0, 0, 0, 0);
  __syncthreads();

  unsigned short* stage = c1h;
  for (int i = tid; i < 1024; i += 256) {
    int c = i & 15, r = i >> 4;
    int py = r >> 3, px = r & 7;
    unsigned short m = 0;
#pragma unroll
    for (int dy = 0; dy < 3; ++dy) {
      int gy = 2 * (py0 + py) - 1 + dy;
      if (gy < 0 || gy >= 512) continue;
#pragma unroll
      for (int dx = 0; dx < 3; ++dx) {
        int gx = 2 * (px0 + px) - 1 + dx;
        if (gx < 0 || gx >= 512) continue;
        unsigned short v = bufA[((2 * py + dy) * 17 + 2 * px + dx) * 18 + c];
        m = (v > m) ? v : m;
      }
    }
    stage[r * 18 + c] = m;
  }
  __syncthreads();

  for (int i = tid; i < 1024; i += 256) {
    int c = i >> 6, r = i & 63, py = r >> 3, px = r & 7;
    unsigned short hb = stage[r * 18 + c];
    outp[((size_t)c * 256 + py0 + py) * 256 + px0 + px] = h2f(hb);
    outh[(((size_t)(py0 + py)) * 256 + px0 + px) * 16 + c] = hb;
  }
}

// ---------------- fused FE level-1/2 (R15-proven) ----------------
__global__ __launch_bounds__(256) void fe12_fused_k(
    const float* __restrict__ in,
    const unsigned short* __restrict__ wm1, const float* __restrict__ b1,
    const unsigned short* __restrict__ wm2, const float* __restrict__ b2,
    float* __restrict__ outC, unsigned short* __restrict__ outHWC, int Hin) {
  __shared__ __attribute__((aligned(16))) unsigned short inh[441 * 16];
  __shared__ __attribute__((aligned(16))) unsigned short c1h[361 * 16];
  const int n = blockIdx.z;
  const int Ho = Hin >> 1;
  const int py0 = blockIdx.y * 8, px0 = blockIdx.x * 8;
  const int tid = threadIdx.x;
  const float* inN = in + (size_t)n * 16 * Hin * Hin;
  const size_t HH = (size_t)Hin * Hin;

  half8 bf1[5], bf2[5];
  {
    const int lane = tid & 63;
#pragma unroll
    for (int c = 0; c < 5; ++c) {
      bf1[c] = *(const half8*)(wm1 + (c * 64 + lane) * 8);
      bf2[c] = *(const half8*)(wm2 + (c * 64 + lane) * 8);
    }
  }

  unsigned* inh32 = (unsigned*)inh;
  for (int i = tid; i < 8 * 441; i += 256) {
    int cp = i / 441, r = i - cp * 441;
    int yi = r / 21, xi = r - yi * 21;
    int gy = 2 * py0 - 3 + yi, gx = 2 * px0 - 3 + xi;
    float v0 = 0.f, v1 = 0.f;
    if (gy >= 0 && gy < Hin && gx >= 0 && gx < Hin) {
      const float* s = inN + (size_t)(2 * cp) * HH + (size_t)gy * Hin + gx;
      v0 = s[0];
      v1 = s[HH];
    }
    inh32[r * 8 + cp] = packh2(v0, v1);
  }
  __syncthreads();

  conv_mfma(inh, 21, c1h, 16, bf1, b1, 361, 19, tid, 1, 1, 2 * py0 - 2, 2 * px0 - 2, Hin);
  __syncthreads();
  conv_mfma(c1h, 19, inh, 18, bf2, b2, 289, 17, tid, 1, 0, 0, 0, 0);
  __syncthreads();

  unsigned short* stage = c1h;
  for (int i = tid; i < 1024; i += 256) {
    int c = i & 15, r = i >> 4;
    int py = r >> 3, px = r & 7;
    unsigned short m = 0;
#pragma unroll
    for (int dy = 0; dy < 3; ++dy) {
      int gy = 2 * (py0 + py) - 1 + dy;
      if (gy < 0 || gy >= Hin) continue;
#pragma unroll
      for (int dx = 0; dx < 3; ++dx) {
        int gx = 2 * (px0 + px) - 1 + dx;
        if (gx < 0 || gx >= Hin) continue;
        unsigned short v = inh[((2 * py + dy) * 17 + 2 * px + dx) * 18 + c];
        m = (v > m) ? v : m;
      }
    }
    stage[r * 18 + c] = m;
  }
  __syncthreads();

  float* outp = outC + (size_t)n * 16 * Ho * Ho;
  for (int i = tid; i < 1024; i += 256) {
    int c = i >> 6, r = i & 63, py = r >> 3, px = r & 7;
    unsigned short hb = stage[r * 18 + c];
    outp[((size_t)c * Ho + py0 + py) * Ho + px0 + px] = h2f(hb);
    if (n >= 4)
      outHWC[(((size_t)(n - 4) * Ho + py0 + py) * Ho + px0 + px) * 16 + c] = hb;
  }
}

// ---------------- fused offset head (16x8 tiles): ob(MFMA) -> og(split MFMA) -> offs(f16) ----------------
template <int HAS_UP>
__global__ __launch_bounds__(256) void obog_k(
    const float* __restrict__ rf, const float* __restrict__ uf,
    const unsigned short* __restrict__ offsUp,
    const unsigned short* __restrict__ wmob, const float* __restrict__ bob,
    const unsigned short* __restrict__ wog, const float* __restrict__ bog,
    unsigned short* __restrict__ offsOut, int H) {
  // POOL u32: [0..3840) input HWC-32 12x20 / offs-up HWC-17 (3060) / og-out f32 s19 (2432)
  //           [3840..5460) ob-out HWC-16 10x18 stride-18 u16
  __shared__ __attribute__((aligned(16))) unsigned POOL[5460];
  const int n = blockIdx.z;
  const int bx = blockIdx.x * 16, by = blockIdx.y * 8;
  const int tid = threadIdx.x;
  const size_t HH = (size_t)H * H;
  const float* r0 = rf + (size_t)n * 16 * HH;
  const float* u0 = uf + (size_t)n * 16 * HH;

  for (int i = tid; i < 3840; i += 256) {
    int cp = i / 240, r = i - cp * 240;
    int ly = r / 20, lx = r - ly * 20;
    int gy = by + ly - 2, gx = bx + lx - 2;
    float v0 = 0.f, v1 = 0.f;
    if (gy >= 0 && gy < H && gx >= 0 && gx < H) {
      const float* s = (cp < 8) ? r0 + (size_t)(2 * cp) * HH : u0 + (size_t)(2 * cp - 16) * HH;
      size_t off = (size_t)gy * H + gx;
      v0 = s[off];
      v1 = s[HH + off];
    }
    POOL[r * 16 + cp] = packh2(v0, v1);
  }
  __syncthreads();

  {
    half8 bf[9];
    const int lane = tid & 63;
#pragma unroll
    for (int c = 0; c < 9; ++c) bf[c] = *(const half8*)(wmob + (c * 64 + lane) * 8);
    conv_mfma32((const unsigned short*)POOL, 20, (unsigned short*)(POOL + 3840), 18,
                bf, bob, 180, 18, tid, 1, 1, by - 1, bx - 1, H);
  }
  __syncthreads();

  if (HAS_UP) {  // stage up2(offsUp f16) as HWC (18ch pad 32) stride-17 u32, overlaying input region
    const int H2 = H >> 1;
    const unsigned short* os = offsUp + (size_t)n * 18 * H2 * H2;
    for (int i = tid; i < 16 * 180; i += 256) {
      int cp = i / 180, r = i - cp * 180;
      unsigned val = 0u;
      if (cp < 9) {
        int y1 = r / 18, x1 = r - y1 * 18;
        int gy = by + y1 - 1, gx = bx + x1 - 1;
        if (gy >= 0 && gy < H && gx >= 0 && gx < H) {
          float sy = 0.5f * gy - 0.25f, sx = 0.5f * gx - 0.25f;
          float y0f = floorf(sy), x0f = floorf(sx);
          float wy = sy - y0f, wx = sx - x0f;
          int y0 = (int)y0f, x0 = (int)x0f;
          int y0c = min(max(y0, 0), H2 - 1), y1c = min(max(y0 + 1, 0), H2 - 1);
          int x0c = min(max(x0, 0), H2 - 1), x1c = min(max(x0 + 1, 0), H2 - 1);
          const unsigned short* sp = os + (size_t)(2 * cp) * H2 * H2;
          float v0 = (1.f - wy) * ((1.f - wx) * h2f(sp[y0c * H2 + x0c]) + wx * h2f(sp[y0c * H2 + x1c])) +
                     wy * ((1.f - wx) * h2f(sp[y1c * H2 + x0c]) + wx * h2f(sp[y1c * H2 + x1c]));
          sp += (size_t)H2 * H2;
          float v1 = (1.f - wy) * ((1.f - wx) * h2f(sp[y0c * H2 + x0c]) + wx * h2f(sp[y0c * H2 + x1c])) +
                     wy * ((1.f - wx) * h2f(sp[y1c * H2 + x0c]) + wx * h2f(sp[y1c * H2 + x1c]));
          val = packh2(v0, v1);
        }
      }
      POOL[r * 17 + cp] = val;
    }
    __syncthreads();
  }

  // og: split MFMA (16ch ob-out + optional 18ch offs-up), relu, f32 out stride 19, 128 pos
  conv_split_mfma<2, HAS_UP, 2>((const unsigned short*)(POOL + 3840),
                                (const unsigned short*)POOL, wog,
                                (float*)POOL, 19, bog, 18, 1, tid);
  __syncthreads();

  {
    int pix = tid & 127, half = tid >> 7;
    const float* of = (const float*)POOL + (size_t)pix * 19 + half * 9;
    int ty = pix >> 4, tx = pix & 15;
    unsigned short* op = offsOut + (size_t)n * 18 * HH + (size_t)(half * 9) * HH +
                         (size_t)(by + ty) * H + (bx + tx);
#pragma unroll
    for (int o = 0; o < 9; ++o) op[(size_t)o * HH] = f2h(of[o]);
  }
}

// ---------------- fused feature head: deform(f16 pk blend + dot2 MAC) -> fc(MFMA) ----------------
template <int HAS_UP>
__global__ __launch_bounds__(256) void defc_k(
    const unsigned short* __restrict__ ufHWC, const unsigned short* __restrict__ offs,
    const unsigned* __restrict__ wdc2, const float* __restrict__ featsUp,
    const unsigned short* __restrict__ wmfc, const float* __restrict__ bfc,
    float* __restrict__ featsOut, unsigned short* __restrict__ outHwc, int H) {
  __shared__ __attribute__((aligned(16))) unsigned ldsC[180 * 17];  // 10x18 HWC-32 + 1-u32 pad
  const int n = blockIdx.z;
  const int bx = blockIdx.x * 16, by = blockIdx.y * 8;
  const int tid = threadIdx.x;
  const size_t HH = (size_t)H * H;
  const unsigned short* inN = ufHWC + (size_t)n * HH * 16;
  const unsigned short* offN = offs + (size_t)n * 18 * HH;

  half8 bf[9];
  {
    const int lane = tid & 63;
#pragma unroll
    for (int c = 0; c < 9; ++c) bf[c] = *(const half8*)(wmfc + (c * 64 + lane) * 8);
  }

  for (int p = tid; p < 180; p += 256) {
    int y1 = p / 18, x1 = p - y1 * 18;
    int h = by + y1 - 1, w = bx + x1 - 1;
    bool valid = (h >= 0 && h < H && w >= 0 && w < H);
    float acc[16];
#pragma unroll
    for (int o = 0; o < 16; ++o) acc[o] = 0.f;
    if (valid) {
      size_t hw = (size_t)h * H + w;
#pragma unroll
      for (int k = 0; k < 9; ++k) {
        int ky = k / 3 - 1, kx = k % 3 - 1;
        float oy = h2f(offN[(size_t)(2 * k) * HH + hw]);
        float ox = h2f(offN[(size_t)(2 * k + 1) * HH + hw]);
        float py = (float)(h + ky) + oy;
        float px = (float)(w + kx) + ox;
        float y0f = floorf(py), x0f = floorf(px);
        float fy = py - y0f, fx = px - x0f;
        int y0 = (int)y0f, x0 = (int)x0f;
        bool vy0 = ((unsigned)y0 < (unsigned)H);
        bool vy1 = ((unsigned)(y0 + 1) < (unsigned)H);
        bool vx0 = ((unsigned)x0 < (unsigned)H);
        bool vx1 = ((unsigned)(x0 + 1) < (unsigned)H);
        int y0c = min(max(y0, 0), H - 1), y1c = min(max(y0 + 1, 0), H - 1);
        int x0c = min(max(x0, 0), H - 1), x1c = min(max(x0 + 1, 0), H - 1);
        float w00 = (vy0 && vx0) ? (1.f - fy) * (1.f - fx) : 0.f;
        float w01 = (vy0 && vx1) ? (1.f - fy) * fx : 0.f;
        float w10 = (vy1 && vx0) ? fy * (1.f - fx) : 0.f;
        float w11 = (vy1 && vx1) ? fy * fx : 0.f;
        half8 s00 = splat8((_Float16)w00);
        half8 s01 = splat8((_Float16)w01);
        half8 s10 = splat8((_Float16)w10);
        half8 s11 = splat8((_Float16)w11);
        const unsigned short* p00 = inN + ((size_t)y0c * H + x0c) * 16;
        const unsigned short* p01 = inN + ((size_t)y0c * H + x1c) * 16;
        const unsigned short* p10 = inN + ((size_t)y1c * H + x0c) * 16;
        const unsigned short* p11 = inN + ((size_t)y1c * H + x1c) * 16;
        const unsigned* wk2 = wdc2 + k * 128;
#pragma unroll
        for (int c8 = 0; c8 < 2; ++c8) {
          half8 a00 = *(const half8*)(p00 + c8 * 8);
          half8 a01 = *(const half8*)(p01 + c8 * 8);
          half8 a10 = *(const half8*)(p10 + c8 * 8);
          half8 a11 = *(const half8*)(p11 + c8 * 8);
          half8 vb = a00 * s00 + a01 * s01 + a10 * s10 + a11 * s11;
          uint4 vp = __builtin_bit_cast(uint4, vb);
          unsigned vpa[4] = {vp.x, vp.y, vp.z, vp.w};
#pragma unroll
          for (int jp = 0; jp < 4; ++jp) {
            const unsigned* wrow = wk2 + (c8 * 4 + jp) * 16;
#pragma unroll
            for (int o = 0; o < 16; ++o)
              acc[o] = dot2acc(vpa[jp], wrow[o], acc[o]);
          }
        }
      }
    }
#pragma unroll
    for (int cc = 0; cc < 8; ++cc) {
      float a0 = valid ? fmaxf(acc[2 * cc], 0.f) : 0.f;
      float a1 = valid ? fmaxf(acc[2 * cc + 1], 0.f) : 0.f;
      ldsC[p * 17 + cc] = packh2(a0, a1);
      if (!HAS_UP) ldsC[p * 17 + 8 + cc] = 0u;
    }
  }

  if (HAS_UP) {  // up2(featsUp) -> channels 16..31
    const int H2 = H >> 1;
    const float* fu = featsUp + (size_t)n * 16 * H2 * H2;
    for (int i = tid; i < 8 * 180; i += 256) {
      int cp = i / 180, r = i - cp * 180;
      int y1 = r / 18, x1 = r - y1 * 18;
      int gy = by + y1 - 1, gx = bx + x1 - 1;
      float v0 = 0.f, v1 = 0.f;
      if (gy >= 0 && gy < H && gx >= 0 && gx < H) {
        float sy = 0.5f * gy - 0.25f, sx = 0.5f * gx - 0.25f;
        float y0f = floorf(sy), x0f = floorf(sx);
        float wy = sy - y0f, wx = sx - x0f;
        int y0 = (int)y0f, x0 = (int)x0f;
        int y0c = min(max(y0, 0), H2 - 1), y1c = min(max(y0 + 1, 0), H2 - 1);
        int x0c = min(max(x0, 0), H2 - 1), x1c = min(max(x0 + 1, 0), H2 - 1);
        const float* sp = fu + (size_t)(2 * cp) * H2 * H2;
        v0 = (1.f - wy) * ((1.f - wx) * sp[y0c * H2 + x0c] + wx * sp[y0c * H2 + x1c]) +
             wy * ((1.f - wx) * sp[y1c * H2 + x0c] + wx * sp[y1c * H2 + x1c]);
        sp += (size_t)H2 * H2;
        v1 = (1.f - wy) * ((1.f - wx) * sp[y0c * H2 + x0c] + wx * sp[y0c * H2 + x1c]) +
             wy * ((1.f - wx) * sp[y1c * H2 + x0c] + wx * sp[y1c * H2 + x1c]);
      }
      ldsC[r * 17 + 8 + cp] = packh2(v0, v1);
    }
  }
  __syncthreads();

  // fc via MFMA: 128 output positions (8x16), pos stride 34 u16
  {
    const int lane = tid & 63, wid = tid >> 6;
    const int quad = lane >> 4, m = lane & 15;
    const unsigned short* src = (const unsigned short*)ldsC;
    float bs = bfc[m];
    for (int T = wid; T < 8; T += 4) {
      int pa = T * 16 + m;
      int ya = pa >> 4, xa = pa & 15;
      floatx4 acc = {0.f, 0.f, 0.f, 0.f};
#pragma unroll
      for (int tap = 0; tap < 9; ++tap) {
        int dy = tap / 3, dx = tap - (tap / 3) * 3;
        half8 a = *(const half8*)(src + ((ya + dy) * 18 + xa + dx) * 34 + quad * 8);
        acc = __builtin_amdgcn_mfma_f32_16x16x32_f16(a, bf[tap], acc, 0, 0, 0);
      }
#pragma unroll
      for (int r = 0; r < 4; ++r) {
        int pd = T * 16 + quad * 4 + r;
        int yd = pd >> 4, xd = pd & 15;
        float v = fmaxf(acc[r] + bs, 0.f);
        if (featsOut)
          featsOut[(size_t)n * 16 * HH + (size_t)m * HH + (size_t)(by + yd) * H + bx + xd] = v;
        if (outHwc)
          outHwc[((size_t)n * HH + (size_t)(by + yd) * H + bx + xd) * 16 + m] = f2h(v);
      }
    }
  }
}

// ---------------- fused final head (16x16): dob -> dog(split MFMA) -> deform dg=2 (pk+dot2) ----
// Staging now fully f16: rf0 via rfH0 sidecar, offs0 f16.
__global__ __launch_bounds__(256) void final_k(
    const unsigned short* __restrict__ rfh, const unsigned short* __restrict__ f0hwc,
    const unsigned short* __restrict__ offs0,
    const unsigned short* __restrict__ wmdob, const float* __restrict__ bdob,
    const unsigned short* __restrict__ wdog, const float* __restrict__ bdog,
    const unsigned* __restrict__ wddc2, float* __restrict__ out) {
  // POOL u32 regions: [0..6400) input HWC-32 / offs0 HWC-17 / a36 f32 stride-37 (spans all)
  //                   [6400..9316) dob-out HWC-16 stride-18 u16
  __shared__ __attribute__((aligned(16))) unsigned POOL[9472];
  const int H = 256;
  const size_t HH = 65536;
  const int n = blockIdx.z;
  const int bx = blockIdx.x * 16, by = blockIdx.y * 16;
  const int tid = threadIdx.x;
  const unsigned short* r0h = rfh + (size_t)n * HH * 16;
  const unsigned short* f0h = f0hwc + (size_t)n * HH * 16;

  for (int i = tid; i < 6400; i += 256) {
    int cp = i / 400, r = i - cp * 400;
    int ly = r / 20, lx = r - ly * 20;
    int gy = by + ly - 2, gx = bx + lx - 2;
    unsigned val = 0u;
    if (gy >= 0 && gy < H && gx >= 0 && gx < H) {
      const unsigned short* base = (cp < 8) ? r0h : f0h;
      int ch = (cp < 8) ? 2 * cp : 2 * cp - 16;
      val = *(const unsigned*)(base + ((size_t)gy * H + gx) * 16 + ch);
    }
    POOL[r * 16 + cp] = val;
  }
  __syncthreads();

  {
    half8 bf[9];
    const int lane = tid & 63;
#pragma unroll
    for (int c = 0; c < 9; ++c) bf[c] = *(const half8*)(wmdob + (c * 64 + lane) * 8);
    conv_mfma32((const unsigned short*)POOL, 20, (unsigned short*)(POOL + 6400), 18,
                bf, bdob, 324, 18, tid, 0, 1, by - 1, bx - 1, H);
  }
  __syncthreads();

  {  // stage offs0 (f16) as HWC (18ch pad 32) stride-17 u32, overlaying input region
    const unsigned short* os = offs0 + (size_t)n * 18 * HH;
    for (int i = tid; i < 16 * 324; i += 256) {
      int cp = i / 324, r = i - cp * 324;
      unsigned val = 0u;
      if (cp < 9) {
        int y1 = r / 18, x1 = r - y1 * 18;
        int gy = by + y1 - 1, gx = bx + x1 - 1;
        if (gy >= 0 && gy < H && gx >= 0 && gx < H) {
          const unsigned short* s = os + (size_t)(2 * cp) * HH + (size_t)gy * H + gx;
          val = (unsigned)s[0] | ((unsigned)s[HH] << 16);
        }
      }
      POOL[r * 17 + cp] = val;
    }
    __syncthreads();
  }

  // dog: split MFMA (16ch dob-out + 18ch offs0), no relu, f32 out stride 37
  conv_split_mfma<3, 1, 4>((const unsigned short*)(POOL + 6400),
                           (const unsigned short*)POOL, wdog,
                           (float*)POOL, 37, bdog, 36, 0, tid);
  __syncthreads();

  {
    const int ty = tid >> 4, tx = tid & 15;
    const int h = by + ty, w = bx + tx;
    const float* a36 = (const float*)POOL + (size_t)tid * 37;
    float rr[2] = {0.f, 0.f};
#pragma unroll
    for (int g = 0; g < 2; ++g) {
#pragma unroll
      for (int k = 0; k < 9; ++k) {
        int ky = k / 3 - 1, kx = k % 3 - 1;
        float oy = a36[(g * 9 + k) * 2 + 0];
        float ox = a36[(g * 9 + k) * 2 + 1];
        float py = (float)(h + ky) + oy;
        float px = (float)(w + kx) + ox;
        float y0f = floorf(py), x0f = floorf(px);
        float fy = py - y0f, fx = px - x0f;
        int y0 = (int)y0f, x0 = (int)x0f;
        bool vy0 = ((unsigned)y0 < (unsigned)H);
        bool vy1 = ((unsigned)(y0 + 1) < (unsigned)H);
        bool vx0 = ((unsigned)x0 < (unsigned)H);
        bool vx1 = ((unsigned)(x0 + 1) < (unsigned)H);
        int y0c = min(max(y0, 0), H - 1), y1c = min(max(y0 + 1, 0), H - 1);
        int x0c = min(max(x0, 0), H - 1), x1c = min(max(x0 + 1, 0), H - 1);
        float w00 = (vy0 && vx0) ? (1.f - fy) * (1.f - fx) : 0.f;
        float w01 = (vy0 && vx1) ? (1.f - fy) * fx : 0.f;
        float w10 = (vy1 && vx0) ? fy * (1.f - fx) : 0.f;
        float w11 = (vy1 && vx1) ? fy * fx : 0.f;
        half8 s00 = splat8((_Float16)w00);
        half8 s01 = splat8((_Float16)w01);
        half8 s10 = splat8((_Float16)w10);
        half8 s11 = splat8((_Float16)w11);
        const unsigned short* p00 = f0h + ((size_t)y0c * H + x0c) * 16 + g * 8;
        const unsigned short* p01 = f0h + ((size_t)y0c * H + x1c) * 16 + g * 8;
        const unsigned short* p10 = f0h + ((size_t)y1c * H + x0c) * 16 + g * 8;
        const unsigned short* p11 = f0h + ((size_t)y1c * H + x1c) * 16 + g * 8;
        half8 a00 = *(const half8*)p00;
        half8 a01 = *(const half8*)p01;
        half8 a10 = *(const half8*)p10;
        half8 a11 = *(const half8*)p11;
        half8 vb = a00 * s00 + a01 * s01 + a10 * s10 + a11 * s11;
        uint4 vp = __builtin_bit_cast(uint4, vb);
        unsigned vpa[4] = {vp.x, vp.y, vp.z, vp.w};
        const unsigned* wk2 = wddc2 + ((size_t)k * 2 + g) * 8;
#pragma unroll
        for (int jp = 0; jp < 4; ++jp) {
          rr[0] = dot2acc(vpa[jp], wk2[jp * 2 + 0], rr[0]);
          rr[1] = dot2acc(vpa[jp], wk2[jp * 2 + 1], rr[1]);
        }
      }
    }
    out[((size_t)n * 2 + 0) * HH + (size_t)h * H + w] = rr[0];
    out[((size_t)n * 2 + 1) * HH + (size_t)h * H + w] = rr[1];
  }
}

extern "C" void kernel_launch(void* const* d_in, const int* in_sizes, int n_in,
                              void* d_out, int out_size, void* d_ws, size_t ws_size,
                              hipStream_t stream) {
  auto F = [&](int i) { return (const float*)d_in[i]; };
  const float* ref = F(0);
  const float* unr = F(1);
  const float* few1[3] = {F(2), F(6), F(10)};
  const float* feb1[3] = {F(3), F(7), F(11)};
  const float* few2[3] = {F(4), F(8), F(12)};
  const float* feb2[3] = {F(5), F(9), F(13)};
  const float* obw[3] = {F(14), F(16), F(18)};
  const float* obb[3] = {F(15), F(17), F(19)};
  const float* ogw[3] = {F(20), F(22), F(24)};
  const float* ogb[3] = {F(21), F(23), F(25)};
  const float* dcw[3] = {F(26), F(27), F(28)};
  const float* fcw[3] = {F(29), F(31), F(33)};
  const float* fcb[3] = {F(30), F(32), F(34)};
  const float* dobw = F(35);
  const float* dobb = F(36);
  const float* dogw = F(37);
  const float* dogb = F(38);
  const float* ddcw = F(39);

  // ---- workspace (floats) ----
  float* ws = (float*)d_ws;
  size_t p = 0;
  auto alloc = [&](size_t nf) { float* r = ws + p; p += nf; return r; };
  float* rf0 = alloc((size_t)4 * 16 * 65536);
  float* uf0 = alloc((size_t)4 * 16 * 65536);
  float* rf1 = alloc((size_t)4 * 16 * 16384);
  float* uf1 = alloc((size_t)4 * 16 * 16384);
  float* rf2 = alloc((size_t)4 * 16 * 4096);
  float* uf2 = alloc((size_t)4 * 16 * 4096);
  unsigned short* offs0 = (unsigned short*)alloc((size_t)4 * 18 * 65536 / 2);  // f16
  unsigned short* offs1 = (unsigned short*)alloc((size_t)4 * 18 * 16384 / 2);
  unsigned short* offs2 = (unsigned short*)alloc((size_t)4 * 18 * 4096 / 2);
  float* feats1 = alloc((size_t)4 * 16 * 16384);
  float* feats2 = alloc((size_t)4 * 16 * 4096);
  unsigned short* rfH0 = (unsigned short*)alloc((size_t)4 * 16 * 65536 / 2);  // f16 HWC
  unsigned short* ufH0 = (unsigned short*)alloc((size_t)4 * 16 * 65536 / 2);
  unsigned short* ufH1 = (unsigned short*)alloc((size_t)4 * 16 * 16384 / 2);
  unsigned short* ufH2 = (unsigned short*)alloc((size_t)4 * 16 * 4096 / 2);
  unsigned short* fHwc = (unsigned short*)alloc((size_t)4 * 16 * 65536 / 2);
  float* wdc2f = alloc(3600);   // dc dot2 pairs (3456) + ddc pairs (144)
  float* wmf = alloc(7680);     // 16-cin MFMA pack: 15360 u16 (5 convs + fe0 conv1)
  float* wm32f = alloc(16200);  // 32-cin MFMA pack: 32256 u16
  float* wspl = alloc(27648);   // split packs og0/og1/og2/dog: 55296 u16
  if (p * sizeof(float) > ws_size) return;
  unsigned* wdc2 = (unsigned*)wdc2f;
  unsigned short* wmh = (unsigned short*)wmf;
  unsigned short* wm32 = (unsigned short*)wm32f;
  unsigned short* wsp = (unsigned short*)wspl;

  // ---- 32-cin MFMA table: ob0 ob1 ob2 dob fc0 fc1 fc2(pad) ----
  W32Table T32;
  T32.e[0] = {obw[0], 32}; T32.e[1] = {obw[1], 32}; T32.e[2] = {obw[2], 32};
  T32.e[3] = {dobw, 32};   T32.e[4] = {fcw[0], 32}; T32.e[5] = {fcw[1], 32};
  T32.e[6] = {fcw[2], 16};
  auto o32 = [](int i) { return i * 4608; };

  // ---- split-pack table: og0, og1, og2(A only), dog ----
  SPTable TS;
  TS.e[0] = {ogw[0], 34, 18, 2, 0};
  TS.e[1] = {ogw[1], 34, 18, 2, 14336};
  TS.e[2] = {ogw[2], 16, 18, 2, 28672};
  TS.e[3] = {dogw, 34, 36, 3, 33792};
  const int o_og[3] = {0, 14336, 28672};
  const int o_dog = 33792;

  wdcpair_k<<<15, 256, 0, stream>>>(dcw[0], dcw[1], dcw[2], ddcw, wdc2);
  wmfma_k<<<60, 256, 0, stream>>>(few2[0], few1[1], few2[1], few1[2], few2[2],
                                  few1[0], wmh);
  wmfma32_k<<<126, 256, 0, stream>>>(T32, wm32);
  wsplit_k<<<dim3(84, 4), 256, 0, stream>>>(TS, wsp);

  // ---- feature pyramids ----
  fe0_fused_k<<<dim3(32, 32, 8), 256, 0, stream>>>(
      ref, unr, wmh + 5 * 2560, feb1[0], wmh, feb2[0], rf0, uf0, rfH0, ufH0);
  fe12_fused_k<<<dim3(16, 16, 8), 256, 0, stream>>>(
      rf0, wmh + 2560, feb1[1], wmh + 2 * 2560, feb2[1], rf1, ufH1, 256);
  fe12_fused_k<<<dim3(8, 8, 8), 256, 0, stream>>>(
      rf1, wmh + 3 * 2560, feb1[2], wmh + 4 * 2560, feb2[2], rf2, ufH2, 128);

  // ---- coarse-to-fine: fused [ob->og] then [deform->fc] per level ----
  obog_k<0><<<dim3(4, 8, 4), 256, 0, stream>>>(
      rf2, uf2, nullptr, wm32 + o32(2), obb[2], wsp + o_og[2], ogb[2], offs2, 64);
  defc_k<0><<<dim3(4, 8, 4), 256, 0, stream>>>(
      ufH2, offs2, wdc2 + 2 * 1152, nullptr, wm32 + o32(6), fcb[2], feats2, nullptr, 64);
  obog_k<1><<<dim3(8, 16, 4), 256, 0, stream>>>(
      rf1, uf1, offs2, wm32 + o32(1), obb[1], wsp + o_og[1], ogb[1], offs1, 128);
  defc_k<1><<<dim3(8, 16, 4), 256, 0, stream>>>(
      ufH1, offs1, wdc2 + 1 * 1152, feats2, wm32 + o32(5), fcb[1], feats1, nullptr, 128);
  obog_k<1><<<dim3(16, 32, 4), 256, 0, stream>>>(
      rf0, uf0, offs1, wm32 + o32(0), obb[0], wsp + o_og[0], ogb[0], offs0, 256);
  defc_k<1><<<dim3(16, 32, 4), 256, 0, stream>>>(
      ufH0, offs0, wdc2, feats1, wm32 + o32(4), fcb[0], nullptr, fHwc, 256);

  // ---- fused final head (f16 staging: rfH0 + f16 offs0) ----
  final_k<<<dim3(16, 16, 4), 256, 0, stream>>>(
      rfH0, fHwc, offs0, wm32 + o32(3), dobb, wsp + o_dog, dogb, wdc2 + 3456,
      (float*)d_out);
}

// Round 12
// 511.398 us; speedup vs baseline: 1.0671x; 1.0575x over previous
//
#include <hip/hip_runtime.h>
#include <math.h>

typedef _Float16 half2_t __attribute__((ext_vector_type(2)));
typedef _Float16 half8 __attribute__((ext_vector_type(8)));
typedef float floatx4 __attribute__((ext_vector_type(4)));

__device__ __forceinline__ unsigned packh2(float a, float b) {
  half2_t h;
  h.x = (_Float16)a;
  h.y = (_Float16)b;
  return __builtin_bit_cast(unsigned, h);
}
__device__ __forceinline__ unsigned short f2h(float a) {
  return __builtin_bit_cast(unsigned short, (_Float16)a);
}
__device__ __forceinline__ float h2f(unsigned short u) {
  return (float)__builtin_bit_cast(_Float16, u);
}
__device__ __forceinline__ float dot2acc(unsigned a, unsigned b, float c) {
  half2_t ha = __builtin_bit_cast(half2_t, a);
  half2_t hb = __builtin_bit_cast(half2_t, b);
#if __has_builtin(__builtin_amdgcn_fdot2)
  return __builtin_amdgcn_fdot2(ha, hb, c, false);
#else
  c = fmaf((float)ha.x, (float)hb.x, c);
  return fmaf((float)ha.y, (float)hb.y, c);
#endif
}
__device__ __forceinline__ half8 splat8(_Float16 x) {
  half8 r;
#pragma unroll
  for (int j = 0; j < 8; ++j) r[j] = x;
  return r;
}

// ---------------- dc/ddc weight pair pack ----------------
// [0..3456): dc convs 0..2: [conv][k][cp][o] u32 f16-pairs (cin pairs)
// [3456..3600): ddc dg=2: [k][g][jp][o] u32 f16-pairs
__global__ __launch_bounds__(256) void wdcpair_k(
    const float* __restrict__ a, const float* __restrict__ b,
    const float* __restrict__ c, const float* __restrict__ d,
    unsigned* __restrict__ out) {
  int t = blockIdx.x * 256 + threadIdx.x;
  if (t < 3456) {
    int conv = t / 1152, r = t % 1152;
    int k = r / 128, cp = (r / 16) % 8, o = r & 15;
    const float* w = conv == 0 ? a : (conv == 1 ? b : c);
    out[t] = packh2(w[(o * 16 + 2 * cp) * 9 + k], w[(o * 16 + 2 * cp + 1) * 9 + k]);
  } else if (t < 3600) {
    int r = t - 3456;
    int o = r & 1, jp = (r >> 1) & 3, g = (r >> 3) & 1, k = r >> 4;
    out[t] = packh2(d[(o * 16 + g * 8 + 2 * jp) * 9 + k],
                    d[(o * 16 + g * 8 + 2 * jp + 1) * 9 + k]);
  }
}

// ---------------- MFMA prepack, 16-cin convs (K=144 pad 160, 5 chunks, 2 taps/chunk) ----------------
// conv 0..4: regular 16-cin packs; conv 5: fe0 conv1 (cin=1 padded to 16, only cin0 nonzero)
__global__ __launch_bounds__(256) void wmfma_k(
    const float* __restrict__ w0, const float* __restrict__ w1,
    const float* __restrict__ w2, const float* __restrict__ w3,
    const float* __restrict__ w4, const float* __restrict__ w5,
    unsigned short* __restrict__ out) {
  int t = blockIdx.x * 256 + threadIdx.x;
  if (t >= 15360) return;
  int conv = t / 2560, r = t % 2560;
  int c = r / 512, L = (r / 8) % 64, j = r & 7;
  int quad = L >> 4, o = L & 15;
  int k = 32 * c + quad * 8 + j;
  int tap = k >> 4, cin = k & 15;
  float v;
  if (conv == 5) {
    v = (tap < 9 && cin == 0) ? w5[o * 9 + tap] : 0.f;
  } else {
    const float* w = conv == 0 ? w0 : conv == 1 ? w1 : conv == 2 ? w2 : conv == 3 ? w3 : w4;
    v = (tap < 9) ? w[((size_t)o * 16 + cin) * 9 + tap] : 0.f;
  }
  out[t] = f2h(v);
}

// ---------------- MFMA prepack, 32-cin convs (K=tap*32+c, 9 chunks = 1 tap each) ----------------
struct W32Entry { const float* src; int cin; };
struct W32Table { W32Entry e[8]; };  // 7 used
__global__ __launch_bounds__(256) void wmfma32_k(W32Table t, unsigned short* __restrict__ out) {
  int i = blockIdx.x * 256 + threadIdx.x;
  if (i >= 7 * 4608) return;
  int conv = i / 4608, r = i % 4608;
  int tap = r / 512, L = (r / 8) % 64, j = r & 7;
  int quad = L >> 4, o = L & 15;
  int c = quad * 8 + j;
  W32Entry en = t.e[conv];
  float v = (c < en.cin) ? en.src[((size_t)o * en.cin + c) * 9 + tap] : 0.f;
  out[i] = f2h(v);
}

// ---------------- split-cin MFMA prepack for og/dog: [A: ct*5*64*8][B: ct*9*64*8] ----------------
struct SPEntry { const float* src; int cin; int cout; int ct; int dstoff; };
struct SPTable { SPEntry e[4]; };
__global__ __launch_bounds__(256) void wsplit_k(SPTable t, unsigned short* __restrict__ out) {
  SPEntry en = t.e[blockIdx.y];
  int aSize = en.ct * 2560;
  int bSize = (en.cin > 16) ? en.ct * 4608 : 0;
  int i = blockIdx.x * 256 + threadIdx.x;
  if (i >= aSize + bSize) return;
  float v;
  if (i < aSize) {
    int ct = i / 2560, r = i % 2560;
    int c = r / 512, L = (r / 8) % 64, j = r & 7;
    int quad = L >> 4, o16 = L & 15;
    int k = 32 * c + quad * 8 + j;
    int tap = k >> 4, cin = k & 15;
    int o = ct * 16 + o16;
    v = (tap < 9 && o < en.cout) ? en.src[((size_t)o * en.cin + cin) * 9 + tap] : 0.f;
  } else {
    int r2 = i - aSize;
    int ct = r2 / 4608, r = r2 % 4608;
    int tap = r / 512, L = (r / 8) % 64, j = r & 7;
    int quad = L >> 4, o16 = L & 15;
    int cin = quad * 8 + j;
    int o = ct * 16 + o16;
    v = (cin < en.cin - 16 && o < en.cout)
            ? en.src[((size_t)o * en.cin + 16 + cin) * 9 + tap] : 0.f;
  }
  out[en.dstoff + i] = f2h(v);
}

// ---------------- MFMA 16-cin 3x3 conv over LDS HWC-16 tile (R15-verified) ----------------
__device__ __forceinline__ void conv_mfma(
    const unsigned short* __restrict__ src, int SW,
    unsigned short* __restrict__ dst, int DPS, const half8* __restrict__ bf,
    const float* __restrict__ bias, int POS, int OW, int tid, int relu,
    int domask, int gby, int gbx, int bound) {
  const int lane = tid & 63, wid = tid >> 6;
  const int quad = lane >> 4, m = lane & 15;
  const int tap01 = quad >> 1, cin8 = (quad & 1) * 8;
  const int ntiles = (POS + 15) >> 4;
  float bs = bias[m];
  half8 zero;
#pragma unroll
  for (int j = 0; j < 8; ++j) zero[j] = (_Float16)0;
  for (int T = wid; T < ntiles; T += 4) {
    int pa = T * 16 + m;
    pa = pa < POS ? pa : POS - 1;
    int ya = pa / OW, xa = pa - ya * OW;
    floatx4 acc = {0.f, 0.f, 0.f, 0.f};
#pragma unroll
    for (int c = 0; c < 5; ++c) {
      int tap = 2 * c + tap01;
      half8 a = zero;
      if (tap < 9) {
        int dy = tap / 3, dx = tap - (tap / 3) * 3;
        a = *(const half8*)(src + ((ya + dy) * SW + xa + dx) * 16 + cin8);
      }
      acc = __builtin_amdgcn_mfma_f32_16x16x32_f16(a, bf[c], acc, 0, 0, 0);
    }
#pragma unroll
    for (int r = 0; r < 4; ++r) {
      int pd = T * 16 + quad * 4 + r;
      if (pd < POS) {
        float v = acc[r] + bs;
        if (relu) v = fmaxf(v, 0.f);
        if (domask) {
          int yd = pd / OW, xd = pd - (pd / OW) * OW;
          int gy = gby + yd, gx = gbx + xd;
          if (gy < 0 || gy >= bound || gx < 0 || gx >= bound) v = 0.f;
        }
        dst[pd * DPS + m] = f2h(v);
      }
    }
  }
}

// ---------------- MFMA 32-cin 3x3 conv over LDS HWC-32 tile -> LDS HWC-16 out ----------------
__device__ __forceinline__ void conv_mfma32(
    const unsigned short* __restrict__ src, int SW,
    unsigned short* __restrict__ dst, int DPS, const half8* __restrict__ bf,
    const float* __restrict__ bias, int POS, int OW, int tid, int relu,
    int domask, int gby, int gbx, int bound) {
  const int lane = tid & 63, wid = tid >> 6;
  const int quad = lane >> 4, m = lane & 15;
  const int ntiles = (POS + 15) >> 4;
  float bs = bias[m];
  for (int T = wid; T < ntiles; T += 4) {
    int pa = T * 16 + m;
    pa = pa < POS ? pa : POS - 1;
    int ya = pa / OW, xa = pa - ya * OW;
    floatx4 acc = {0.f, 0.f, 0.f, 0.f};
#pragma unroll
    for (int tap = 0; tap < 9; ++tap) {
      int dy = tap / 3, dx = tap - (tap / 3) * 3;
      half8 a = *(const half8*)(src + ((ya + dy) * SW + xa + dx) * 32 + quad * 8);
      acc = __builtin_amdgcn_mfma_f32_16x16x32_f16(a, bf[tap], acc, 0, 0, 0);
    }
#pragma unroll
    for (int r = 0; r < 4; ++r) {
      int pd = T * 16 + quad * 4 + r;
      if (pd < POS) {
        float v = acc[r] + bs;
        if (relu) v = fmaxf(v, 0.f);
        if (domask) {
          int yd = pd / OW, xd = pd - (pd / OW) * OW;
          int gy = gby + yd, gx = gbx + xd;
          if (gy < 0 || gy >= bound || gx < 0 || gx >= bound) v = 0.f;
        }
        dst[pd * DPS + m] = f2h(v);
      }
    }
  }
}

// ---------------- split-cin MFMA 3x3 conv ----------------
template <int CT, int HASB, int NT>
__device__ __forceinline__ void conv_split_mfma(
    const unsigned short* __restrict__ srcB, const unsigned short* __restrict__ srcO,
    const unsigned short* __restrict__ wbase, float* __restrict__ outLds, int OSTRIDE,
    const float* __restrict__ bias, int NOUT, int relu, int tid) {
  const int lane = tid & 63, wid = tid >> 6;
  const int quad = lane >> 4, m = lane & 15;
  const int tap01 = quad >> 1, cin8 = (quad & 1) * 8;
  half8 zero;
#pragma unroll
  for (int j = 0; j < 8; ++j) zero[j] = (_Float16)0;
  floatx4 acc[CT][NT];
#pragma unroll
  for (int ct = 0; ct < CT; ++ct)
#pragma unroll
    for (int t = 0; t < NT; ++t) acc[ct][t] = floatx4{0.f, 0.f, 0.f, 0.f};
#pragma unroll
  for (int ct = 0; ct < CT; ++ct) {
    half8 bfA[5];
#pragma unroll
    for (int c = 0; c < 5; ++c)
      bfA[c] = *(const half8*)(wbase + ((ct * 5 + c) * 64 + lane) * 8);
#pragma unroll
    for (int t = 0; t < NT; ++t) {
      int pa = (wid + 4 * t) * 16 + m;
      int ya = pa >> 4, xa = pa & 15;
#pragma unroll
      for (int c = 0; c < 5; ++c) {
        int tap = 2 * c + tap01;
        half8 a = zero;
        if (tap < 9) {
          int dy = tap / 3, dx = tap - (tap / 3) * 3;
          a = *(const half8*)(srcB + ((ya + dy) * 18 + xa + dx) * 18 + cin8);
        }
        acc[ct][t] = __builtin_amdgcn_mfma_f32_16x16x32_f16(a, bfA[c], acc[ct][t], 0, 0, 0);
      }
    }
  }
  if (HASB) {
    const unsigned short* wb = wbase + CT * 2560;
#pragma unroll
    for (int ct = 0; ct < CT; ++ct) {
      half8 bfB[9];
#pragma unroll
      for (int c = 0; c < 9; ++c)
        bfB[c] = *(const half8*)(wb + ((ct * 9 + c) * 64 + lane) * 8);
#pragma unroll
      for (int t = 0; t < NT; ++t) {
        int pa = (wid + 4 * t) * 16 + m;
        int ya = pa >> 4, xa = pa & 15;
#pragma unroll
        for (int tap = 0; tap < 9; ++tap) {
          int dy = tap / 3, dx = tap - (tap / 3) * 3;
          half8 a = *(const half8*)(srcO + ((ya + dy) * 18 + xa + dx) * 34 + quad * 8);
          acc[ct][t] = __builtin_amdgcn_mfma_f32_16x16x32_f16(a, bfB[tap], acc[ct][t], 0, 0, 0);
        }
      }
    }
  }
  __syncthreads();
#pragma unroll
  for (int ct = 0; ct < CT; ++ct) {
    int o = ct * 16 + m;
#pragma unroll
    for (int t = 0; t < NT; ++t) {
#pragma unroll
      for (int r = 0; r < 4; ++r) {
        int pd = (wid + 4 * t) * 16 + quad * 4 + r;
        if (o < NOUT) {
          float v = acc[ct][t][r] + bias[o];
          if (relu) v = fmaxf(v, 0.f);
          outLds[pd * OSTRIDE + o] = v;
        }
      }
    }
  }
}

// ---------------- fused FE level-0 -> f16 HWC only ----------------
__global__ __launch_bounds__(256) void fe0_fused_k(
    const float* __restrict__ refI, const float* __restrict__ unrI,
    const unsigned short* __restrict__ wm1, const float* __restrict__ b1,
    const unsigned short* __restrict__ wm2, const float* __restrict__ b2,
    unsigned short* __restrict__ outH) {
  __shared__ __attribute__((aligned(16))) unsigned short bufA[441 * 16];
  __shared__ __attribute__((aligned(16))) unsigned short c1h[361 * 16];
  const int z = blockIdx.z;
  const int im = z >> 2, n = z & 3;
  const float* img = (im ? unrI : refI) + (size_t)n * 512 * 512;
  unsigned short* outh = outH + (size_t)z * 65536 * 16;
  const int py0 = blockIdx.y * 8, px0 = blockIdx.x * 8;
  const int tid = threadIdx.x;

  half8 bf1[5], bf2[5];
  {
    const int lane = tid & 63;
#pragma unroll
    for (int c = 0; c < 5; ++c) {
      bf1[c] = *(const half8*)(wm1 + (c * 64 + lane) * 8);
      bf2[c] = *(const half8*)(wm2 + (c * 64 + lane) * 8);
    }
  }

  {
    unsigned* s32 = (unsigned*)bufA;
    for (int i = tid; i < 441; i += 256) {
      int yi = i / 21, xi = i - yi * 21;
      int gy = 2 * py0 - 3 + yi, gx = 2 * px0 - 3 + xi;
      float v = 0.f;
      if (gy >= 0 && gy < 512 && gx >= 0 && gx < 512) v = img[gy * 512 + gx];
      uint4 q0 = {packh2(v, 0.f), 0u, 0u, 0u};
      uint4 q1 = {0u, 0u, 0u, 0u};
      *(uint4*)(s32 + i * 8) = q0;
      *(uint4*)(s32 + i * 8 + 4) = q1;
    }
  }
  __syncthreads();

  conv_mfma(bufA, 21, c1h, 16, bf1, b1, 361, 19, tid, 1, 1, 2 * py0 - 2, 2 * px0 - 2, 512);
  __syncthreads();
  conv_mfma(c1h, 19, bufA, 18, bf2, b2, 289, 17, tid, 1, 0, 0, 0, 0);
  __syncthreads();

  // maxpool (c-fast) with direct coalesced HWC f16 writes
  for (int i = tid; i < 1024; i += 256) {
    int c = i & 15, r = i >> 4;
    int py = r >> 3, px = r & 7;
    unsigned short m = 0;
#pragma unroll
    for (int dy = 0; dy < 3; ++dy) {
      int gy = 2 * (py0 + py) - 1 + dy;
      if (gy < 0 || gy >= 512) continue;
#pragma unroll
      for (int dx = 0; dx < 3; ++dx) {
        int gx = 2 * (px0 + px) - 1 + dx;
        if (gx < 0 || gx >= 512) continue;
        unsigned short v = bufA[((2 * py + dy) * 17 + 2 * px + dx) * 18 + c];
        m = (v > m) ? v : m;
      }
    }
    outh[(((size_t)(py0 + py)) * 256 + px0 + px) * 16 + c] = m;
  }
}

// ---------------- fused FE level-1/2: f16 HWC in, f16 HWC out ----------------
__global__ __launch_bounds__(256) void fe12_fused_k(
    const unsigned short* __restrict__ inH,
    const unsigned short* __restrict__ wm1, const float* __restrict__ b1,
    const unsigned short* __restrict__ wm2, const float* __restrict__ b2,
    unsigned short* __restrict__ outH, int Hin) {
  __shared__ __attribute__((aligned(16))) unsigned short inh[441 * 16];
  __shared__ __attribute__((aligned(16))) unsigned short c1h[361 * 16];
  const int n = blockIdx.z;
  const int Ho = Hin >> 1;
  const int py0 = blockIdx.y * 8, px0 = blockIdx.x * 8;
  const int tid = threadIdx.x;
  const unsigned short* inN = inH + (size_t)n * Hin * Hin * 16;

  half8 bf1[5], bf2[5];
  {
    const int lane = tid & 63;
#pragma unroll
    for (int c = 0; c < 5; ++c) {
      bf1[c] = *(const half8*)(wm1 + (c * 64 + lane) * 8);
      bf2[c] = *(const half8*)(wm2 + (c * 64 + lane) * 8);
    }
  }

  unsigned* inh32 = (unsigned*)inh;
  for (int i = tid; i < 8 * 441; i += 256) {
    int cp = i / 441, r = i - cp * 441;
    int yi = r / 21, xi = r - yi * 21;
    int gy = 2 * py0 - 3 + yi, gx = 2 * px0 - 3 + xi;
    unsigned val = 0u;
    if (gy >= 0 && gy < Hin && gx >= 0 && gx < Hin)
      val = *(const unsigned*)(inN + ((size_t)gy * Hin + gx) * 16 + 2 * cp);
    inh32[r * 8 + cp] = val;
  }
  __syncthreads();

  conv_mfma(inh, 21, c1h, 16, bf1, b1, 361, 19, tid, 1, 1, 2 * py0 - 2, 2 * px0 - 2, Hin);
  __syncthreads();
  conv_mfma(c1h, 19, inh, 18, bf2, b2, 289, 17, tid, 1, 0, 0, 0, 0);
  __syncthreads();

  unsigned short* outp = outH + (size_t)n * Ho * Ho * 16;
  for (int i = tid; i < 1024; i += 256) {
    int c = i & 15, r = i >> 4;
    int py = r >> 3, px = r & 7;
    unsigned short m = 0;
#pragma unroll
    for (int dy = 0; dy < 3; ++dy) {
      int gy = 2 * (py0 + py) - 1 + dy;
      if (gy < 0 || gy >= Hin) continue;
#pragma unroll
      for (int dx = 0; dx < 3; ++dx) {
        int gx = 2 * (px0 + px) - 1 + dx;
        if (gx < 0 || gx >= Hin) continue;
        unsigned short v = inh[((2 * py + dy) * 17 + 2 * px + dx) * 18 + c];
        m = (v > m) ? v : m;
      }
    }
    outp[(((size_t)(py0 + py)) * Ho + px0 + px) * 16 + c] = m;
  }
}

// ---------------- fused offset head (16x8 tiles): ob(MFMA) -> og(split MFMA) -> offs(f16) ----------------
template <int HAS_UP>
__global__ __launch_bounds__(256) void obog_k(
    const unsigned short* __restrict__ rfh, const unsigned short* __restrict__ ufh,
    const unsigned short* __restrict__ offsUp,
    const unsigned short* __restrict__ wmob, const float* __restrict__ bob,
    const unsigned short* __restrict__ wog, const float* __restrict__ bog,
    unsigned short* __restrict__ offsOut, int H) {
  __shared__ __attribute__((aligned(16))) unsigned POOL[5460];
  const int n = blockIdx.z;
  const int bx = blockIdx.x * 16, by = blockIdx.y * 8;
  const int tid = threadIdx.x;
  const size_t HH = (size_t)H * H;
  const unsigned short* r0h = rfh + (size_t)n * HH * 16;
  const unsigned short* u0h = ufh + (size_t)n * HH * 16;

  for (int i = tid; i < 3840; i += 256) {
    int cp = i / 240, r = i - cp * 240;
    int ly = r / 20, lx = r - ly * 20;
    int gy = by + ly - 2, gx = bx + lx - 2;
    unsigned val = 0u;
    if (gy >= 0 && gy < H && gx >= 0 && gx < H) {
      const unsigned short* s16 = (cp < 8) ? r0h : u0h;
      int ch = (cp < 8) ? 2 * cp : 2 * cp - 16;
      val = *(const unsigned*)(s16 + ((size_t)gy * H + gx) * 16 + ch);
    }
    POOL[r * 16 + cp] = val;
  }
  __syncthreads();

  {
    half8 bf[9];
    const int lane = tid & 63;
#pragma unroll
    for (int c = 0; c < 9; ++c) bf[c] = *(const half8*)(wmob + (c * 64 + lane) * 8);
    conv_mfma32((const unsigned short*)POOL, 20, (unsigned short*)(POOL + 3840), 18,
                bf, bob, 180, 18, tid, 1, 1, by - 1, bx - 1, H);
  }
  __syncthreads();

  if (HAS_UP) {
    const int H2 = H >> 1;
    const unsigned short* os = offsUp + (size_t)n * 18 * H2 * H2;
    for (int i = tid; i < 16 * 180; i += 256) {
      int cp = i / 180, r = i - cp * 180;
      unsigned val = 0u;
      if (cp < 9) {
        int y1 = r / 18, x1 = r - y1 * 18;
        int gy = by + y1 - 1, gx = bx + x1 - 1;
        if (gy >= 0 && gy < H && gx >= 0 && gx < H) {
          float sy = 0.5f * gy - 0.25f, sx = 0.5f * gx - 0.25f;
          float y0f = floorf(sy), x0f = floorf(sx);
          float wy = sy - y0f, wx = sx - x0f;
          int y0 = (int)y0f, x0 = (int)x0f;
          int y0c = min(max(y0, 0), H2 - 1), y1c = min(max(y0 + 1, 0), H2 - 1);
          int x0c = min(max(x0, 0), H2 - 1), x1c = min(max(x0 + 1, 0), H2 - 1);
          const unsigned short* sp = os + (size_t)(2 * cp) * H2 * H2;
          float v0 = (1.f - wy) * ((1.f - wx) * h2f(sp[y0c * H2 + x0c]) + wx * h2f(sp[y0c * H2 + x1c])) +
                     wy * ((1.f - wx) * h2f(sp[y1c * H2 + x0c]) + wx * h2f(sp[y1c * H2 + x1c]));
          sp += (size_t)H2 * H2;
          float v1 = (1.f - wy) * ((1.f - wx) * h2f(sp[y0c * H2 + x0c]) + wx * h2f(sp[y0c * H2 + x1c])) +
                     wy * ((1.f - wx) * h2f(sp[y1c * H2 + x0c]) + wx * h2f(sp[y1c * H2 + x1c]));
          val = packh2(v0, v1);
        }
      }
      POOL[r * 17 + cp] = val;
    }
    __syncthreads();
  }

  conv_split_mfma<2, HAS_UP, 2>((const unsigned short*)(POOL + 3840),
                                (const unsigned short*)POOL, wog,
                                (float*)POOL, 19, bog, 18, 1, tid);
  __syncthreads();

  {
    int pix = tid & 127, half = tid >> 7;
    const float* of = (const float*)POOL + (size_t)pix * 19 + half * 9;
    int ty = pix >> 4, tx = pix & 15;
    unsigned short* op = offsOut + (size_t)n * 18 * HH + (size_t)(half * 9) * HH +
                         (size_t)(by + ty) * H + (bx + tx);
#pragma unroll
    for (int o = 0; o < 9; ++o) op[(size_t)o * HH] = f2h(of[o]);
  }
}

// ---------------- fused feature head: deform(f16 pk blend + dot2) -> fc(MFMA) -> f16 HWC ----------------
template <int HAS_UP>
__global__ __launch_bounds__(256) void defc_k(
    const unsigned short* __restrict__ ufHWC, const unsigned short* __restrict__ offs,
    const unsigned* __restrict__ wdc2, const unsigned short* __restrict__ featsUpH,
    const unsigned short* __restrict__ wmfc, const float* __restrict__ bfc,
    unsigned short* __restrict__ outHwc, int H) {
  __shared__ __attribute__((aligned(16))) unsigned ldsC[180 * 17];
  const int n = blockIdx.z;
  const int bx = blockIdx.x * 16, by = blockIdx.y * 8;
  const int tid = threadIdx.x;
  const size_t HH = (size_t)H * H;
  const unsigned short* inN = ufHWC + (size_t)n * HH * 16;
  const unsigned short* offN = offs + (size_t)n * 18 * HH;

  half8 bf[9];
  {
    const int lane = tid & 63;
#pragma unroll
    for (int c = 0; c < 9; ++c) bf[c] = *(const half8*)(wmfc + (c * 64 + lane) * 8);
  }

  for (int p = tid; p < 180; p += 256) {
    int y1 = p / 18, x1 = p - y1 * 18;
    int h = by + y1 - 1, w = bx + x1 - 1;
    bool valid = (h >= 0 && h < H && w >= 0 && w < H);
    float acc[16];
#pragma unroll
    for (int o = 0; o < 16; ++o) acc[o] = 0.f;
    if (valid) {
      size_t hw = (size_t)h * H + w;
#pragma unroll
      for (int k = 0; k < 9; ++k) {
        int ky = k / 3 - 1, kx = k % 3 - 1;
        float oy = h2f(offN[(size_t)(2 * k) * HH + hw]);
        float ox = h2f(offN[(size_t)(2 * k + 1) * HH + hw]);
        float py = (float)(h + ky) + oy;
        float px = (float)(w + kx) + ox;
        float y0f = floorf(py), x0f = floorf(px);
        float fy = py - y0f, fx = px - x0f;
        int y0 = (int)y0f, x0 = (int)x0f;
        bool vy0 = ((unsigned)y0 < (unsigned)H);
        bool vy1 = ((unsigned)(y0 + 1) < (unsigned)H);
        bool vx0 = ((unsigned)x0 < (unsigned)H);
        bool vx1 = ((unsigned)(x0 + 1) < (unsigned)H);
        int y0c = min(max(y0, 0), H - 1), y1c = min(max(y0 + 1, 0), H - 1);
        int x0c = min(max(x0, 0), H - 1), x1c = min(max(x0 + 1, 0), H - 1);
        float w00 = (vy0 && vx0) ? (1.f - fy) * (1.f - fx) : 0.f;
        float w01 = (vy0 && vx1) ? (1.f - fy) * fx : 0.f;
        float w10 = (vy1 && vx0) ? fy * (1.f - fx) : 0.f;
        float w11 = (vy1 && vx1) ? fy * fx : 0.f;
        half8 s00 = splat8((_Float16)w00);
        half8 s01 = splat8((_Float16)w01);
        half8 s10 = splat8((_Float16)w10);
        half8 s11 = splat8((_Float16)w11);
        const unsigned short* p00 = inN + ((size_t)y0c * H + x0c) * 16;
        const unsigned short* p01 = inN + ((size_t)y0c * H + x1c) * 16;
        const unsigned short* p10 = inN + ((size_t)y1c * H + x0c) * 16;
        const unsigned short* p11 = inN + ((size_t)y1c * H + x1c) * 16;
        const unsigned* wk2 = wdc2 + k * 128;
#pragma unroll
        for (int c8 = 0; c8 < 2; ++c8) {
          half8 a00 = *(const half8*)(p00 + c8 * 8);
          half8 a01 = *(const half8*)(p01 + c8 * 8);
          half8 a10 = *(const half8*)(p10 + c8 * 8);
          half8 a11 = *(const half8*)(p11 + c8 * 8);
          half8 vb = a00 * s00 + a01 * s01 + a10 * s10 + a11 * s11;
          uint4 vp = __builtin_bit_cast(uint4, vb);
          unsigned vpa[4] = {vp.x, vp.y, vp.z, vp.w};
#pragma unroll
          for (int jp = 0; jp < 4; ++jp) {
            const unsigned* wrow = wk2 + (c8 * 4 + jp) * 16;
#pragma unroll
            for (int o = 0; o < 16; ++o)
              acc[o] = dot2acc(vpa[jp], wrow[o], acc[o]);
          }
        }
      }
    }
#pragma unroll
    for (int cc = 0; cc < 8; ++cc) {
      float a0 = valid ? fmaxf(acc[2 * cc], 0.f) : 0.f;
      float a1 = valid ? fmaxf(acc[2 * cc + 1], 0.f) : 0.f;
      ldsC[p * 17 + cc] = packh2(a0, a1);
      if (!HAS_UP) ldsC[p * 17 + 8 + cc] = 0u;
    }
  }

  if (HAS_UP) {  // up2(featsUpH f16 HWC) -> channels 16..31
    const int H2 = H >> 1;
    const unsigned short* fu = featsUpH + (size_t)n * H2 * H2 * 16;
    for (int i = tid; i < 8 * 180; i += 256) {
      int cp = i / 180, r = i - cp * 180;
      int y1 = r / 18, x1 = r - y1 * 18;
      int gy = by + y1 - 1, gx = bx + x1 - 1;
      unsigned val = 0u;
      if (gy >= 0 && gy < H && gx >= 0 && gx < H) {
        float sy = 0.5f * gy - 0.25f, sx = 0.5f * gx - 0.25f;
        float y0f = floorf(sy), x0f = floorf(sx);
        float wy = sy - y0f, wx = sx - x0f;
        int y0 = (int)y0f, x0 = (int)x0f;
        int y0c = min(max(y0, 0), H2 - 1), y1c = min(max(y0 + 1, 0), H2 - 1);
        int x0c = min(max(x0, 0), H2 - 1), x1c = min(max(x0 + 1, 0), H2 - 1);
        half2_t h00 = __builtin_bit_cast(half2_t, *(const unsigned*)(fu + ((size_t)y0c * H2 + x0c) * 16 + 2 * cp));
        half2_t h01 = __builtin_bit_cast(half2_t, *(const unsigned*)(fu + ((size_t)y0c * H2 + x1c) * 16 + 2 * cp));
        half2_t h10 = __builtin_bit_cast(half2_t, *(const unsigned*)(fu + ((size_t)y1c * H2 + x0c) * 16 + 2 * cp));
        half2_t h11 = __builtin_bit_cast(half2_t, *(const unsigned*)(fu + ((size_t)y1c * H2 + x1c) * 16 + 2 * cp));
        float v0 = (1.f - wy) * ((1.f - wx) * (float)h00.x + wx * (float)h01.x) +
                   wy * ((1.f - wx) * (float)h10.x + wx * (float)h11.x);
        float v1 = (1.f - wy) * ((1.f - wx) * (float)h00.y + wx * (float)h01.y) +
                   wy * ((1.f - wx) * (float)h10.y + wx * (float)h11.y);
        val = packh2(v0, v1);
      }
      ldsC[r * 17 + 8 + cp] = val;
    }
  }
  __syncthreads();

  // fc via MFMA: 128 output positions (8x16), pos stride 34 u16, f16 HWC out
  {
    const int lane = tid & 63, wid = tid >> 6;
    const int quad = lane >> 4, m = lane & 15;
    const unsigned short* src = (const unsigned short*)ldsC;
    float bs = bfc[m];
    for (int T = wid; T < 8; T += 4) {
      int pa = T * 16 + m;
      int ya = pa >> 4, xa = pa & 15;
      floatx4 acc = {0.f, 0.f, 0.f, 0.f};
#pragma unroll
      for (int tap = 0; tap < 9; ++tap) {
        int dy = tap / 3, dx = tap - (tap / 3) * 3;
        half8 a = *(const half8*)(src + ((ya + dy) * 18 + xa + dx) * 34 + quad * 8);
        acc = __builtin_amdgcn_mfma_f32_16x16x32_f16(a, bf[tap], acc, 0, 0, 0);
      }
#pragma unroll
      for (int r = 0; r < 4; ++r) {
        int pd = T * 16 + quad * 4 + r;
        int yd = pd >> 4, xd = pd & 15;
        float v = fmaxf(acc[r] + bs, 0.f);
        outHwc[((size_t)n * HH + (size_t)(by + yd) * H + bx + xd) * 16 + m] = f2h(v);
      }
    }
  }
}

// ---------------- fused final head (16x16): dob -> dog(split MFMA) -> deform dg=2 (pk+dot2) ----
__global__ __launch_bounds__(256) void final_k(
    const unsigned short* __restrict__ rfh, const unsigned short* __restrict__ f0hwc,
    const unsigned short* __restrict__ offs0,
    const unsigned short* __restrict__ wmdob, const float* __restrict__ bdob,
    const unsigned short* __restrict__ wdog, const float* __restrict__ bdog,
    const unsigned* __restrict__ wddc2, float* __restrict__ out) {
  __shared__ __attribute__((aligned(16))) unsigned POOL[9472];
  const int H = 256;
  const size_t HH = 65536;
  const int n = blockIdx.z;
  const int bx = blockIdx.x * 16, by = blockIdx.y * 16;
  const int tid = threadIdx.x;
  const unsigned short* r0h = rfh + (size_t)n * HH * 16;
  const unsigned short* f0h = f0hwc + (size_t)n * HH * 16;

  for (int i = tid; i < 6400; i += 256) {
    int cp = i / 400, r = i - cp * 400;
    int ly = r / 20, lx = r - ly * 20;
    int gy = by + ly - 2, gx = bx + lx - 2;
    unsigned val = 0u;
    if (gy >= 0 && gy < H && gx >= 0 && gx < H) {
      const unsigned short* base = (cp < 8) ? r0h : f0h;
      int ch = (cp < 8) ? 2 * cp : 2 * cp - 16;
      val = *(const unsigned*)(base + ((size_t)gy * H + gx) * 16 + ch);
    }
    POOL[r * 16 + cp] = val;
  }
  __syncthreads();

  {
    half8 bf[9];
    const int lane = tid & 63;
#pragma unroll
    for (int c = 0; c < 9; ++c) bf[c] = *(const half8*)(wmdob + (c * 64 + lane) * 8);
    conv_mfma32((const unsigned short*)POOL, 20, (unsigned short*)(POOL + 6400), 18,
                bf, bdob, 324, 18, tid, 0, 1, by - 1, bx - 1, H);
  }
  __syncthreads();

  {
    const unsigned short* os = offs0 + (size_t)n * 18 * HH;
    for (int i = tid; i < 16 * 324; i += 256) {
      int cp = i / 324, r = i - cp * 324;
      unsigned val = 0u;
      if (cp < 9) {
        int y1 = r / 18, x1 = r - y1 * 18;
        int gy = by + y1 - 1, gx = bx + x1 - 1;
        if (gy >= 0 && gy < H && gx >= 0 && gx < H) {
          const unsigned short* s = os + (size_t)(2 * cp) * HH + (size_t)gy * H + gx;
          val = (unsigned)s[0] | ((unsigned)s[HH] << 16);
        }
      }
      POOL[r * 17 + cp] = val;
    }
    __syncthreads();
  }

  conv_split_mfma<3, 1, 4>((const unsigned short*)(POOL + 6400),
                           (const unsigned short*)POOL, wdog,
                           (float*)POOL, 37, bdog, 36, 0, tid);
  __syncthreads();

  {
    const int ty = tid >> 4, tx = tid & 15;
    const int h = by + ty, w = bx + tx;
    const float* a36 = (const float*)POOL + (size_t)tid * 37;
    float rr[2] = {0.f, 0.f};
#pragma unroll
    for (int g = 0; g < 2; ++g) {
#pragma unroll
      for (int k = 0; k < 9; ++k) {
        int ky = k / 3 - 1, kx = k % 3 - 1;
        float oy = a36[(g * 9 + k) * 2 + 0];
        float ox = a36[(g * 9 + k) * 2 + 1];
        float py = (float)(h + ky) + oy;
        float px = (float)(w + kx) + ox;
        float y0f = floorf(py), x0f = floorf(px);
        float fy = py - y0f, fx = px - x0f;
        int y0 = (int)y0f, x0 = (int)x0f;
        bool vy0 = ((unsigned)y0 < (unsigned)H);
        bool vy1 = ((unsigned)(y0 + 1) < (unsigned)H);
        bool vx0 = ((unsigned)x0 < (unsigned)H);
        bool vx1 = ((unsigned)(x0 + 1) < (unsigned)H);
        int y0c = min(max(y0, 0), H - 1), y1c = min(max(y0 + 1, 0), H - 1);
        int x0c = min(max(x0, 0), H - 1), x1c = min(max(x0 + 1, 0), H - 1);
        float w00 = (vy0 && vx0) ? (1.f - fy) * (1.f - fx) : 0.f;
        float w01 = (vy0 && vx1) ? (1.f - fy) * fx : 0.f;
        float w10 = (vy1 && vx0) ? fy * (1.f - fx) : 0.f;
        float w11 = (vy1 && vx1) ? fy * fx : 0.f;
        half8 s00 = splat8((_Float16)w00);
        half8 s01 = splat8((_Float16)w01);
        half8 s10 = splat8((_Float16)w10);
        half8 s11 = splat8((_Float16)w11);
        const unsigned short* p00 = f0h + ((size_t)y0c * H + x0c) * 16 + g * 8;
        const unsigned short* p01 = f0h + ((size_t)y0c * H + x1c) * 16 + g * 8;
        const unsigned short* p10 = f0h + ((size_t)y1c * H + x0c) * 16 + g * 8;
        const unsigned short* p11 = f0h + ((size_t)y1c * H + x1c) * 16 + g * 8;
        half8 a00 = *(const half8*)p00;
        half8 a01 = *(const half8*)p01;
        half8 a10 = *(const half8*)p10;
        half8 a11 = *(const half8*)p11;
        half8 vb = a00 * s00 + a01 * s01 + a10 * s10 + a11 * s11;
        uint4 vp = __builtin_bit_cast(uint4, vb);
        unsigned vpa[4] = {vp.x, vp.y, vp.z, vp.w};
        const unsigned* wk2 = wddc2 + ((size_t)k * 2 + g) * 8;
#pragma unroll
        for (int jp = 0; jp < 4; ++jp) {
          rr[0] = dot2acc(vpa[jp], wk2[jp * 2 + 0], rr[0]);
          rr[1] = dot2acc(vpa[jp], wk2[jp * 2 + 1], rr[1]);
        }
      }
    }
    out[((size_t)n * 2 + 0) * HH + (size_t)h * H + w] = rr[0];
    out[((size_t)n * 2 + 1) * HH + (size_t)h * H + w] = rr[1];
  }
}

extern "C" void kernel_launch(void* const* d_in, const int* in_sizes, int n_in,
                              void* d_out, int out_size, void* d_ws, size_t ws_size,
                              hipStream_t stream) {
  auto F = [&](int i) { return (const float*)d_in[i]; };
  const float* ref = F(0);
  const float* unr = F(1);
  const float* few1[3] = {F(2), F(6), F(10)};
  const float* feb1[3] = {F(3), F(7), F(11)};
  const float* few2[3] = {F(4), F(8), F(12)};
  const float* feb2[3] = {F(5), F(9), F(13)};
  const float* obw[3] = {F(14), F(16), F(18)};
  const float* obb[3] = {F(15), F(17), F(19)};
  const float* ogw[3] = {F(20), F(22), F(24)};
  const float* ogb[3] = {F(21), F(23), F(25)};
  const float* dcw[3] = {F(26), F(27), F(28)};
  const float* fcw[3] = {F(29), F(31), F(33)};
  const float* fcb[3] = {F(30), F(32), F(34)};
  const float* dobw = F(35);
  const float* dobb = F(36);
  const float* dogw = F(37);
  const float* dogb = F(38);
  const float* ddcw = F(39);

  // ---- workspace (floats) ----
  float* ws = (float*)d_ws;
  size_t p = 0;
  auto alloc = [&](size_t nf) { float* r = ws + p; p += nf; return r; };
  // unified f16 HWC feature pyramids: [8 images][H*H][16] (ref 0-3, unr 4-7)
  unsigned short* fH0 = (unsigned short*)alloc((size_t)8 * 16 * 65536 / 2);
  unsigned short* fH1 = (unsigned short*)alloc((size_t)8 * 16 * 16384 / 2);
  unsigned short* fH2 = (unsigned short*)alloc((size_t)8 * 16 * 4096 / 2);
  // f16 HWC feats: [4][H*H][16]
  unsigned short* ftH1 = (unsigned short*)alloc((size_t)4 * 16 * 16384 / 2);
  unsigned short* ftH2 = (unsigned short*)alloc((size_t)4 * 16 * 4096 / 2);
  unsigned short* fHwc = (unsigned short*)alloc((size_t)4 * 16 * 65536 / 2);
  // f16 CHW offsets
  unsigned short* offs0 = (unsigned short*)alloc((size_t)4 * 18 * 65536 / 2);
  unsigned short* offs1 = (unsigned short*)alloc((size_t)4 * 18 * 16384 / 2);
  unsigned short* offs2 = (unsigned short*)alloc((size_t)4 * 18 * 4096 / 2);
  float* wdc2f = alloc(3600);   // dc dot2 pairs (3456) + ddc pairs (144)
  float* wmf = alloc(7680);     // 16-cin MFMA pack: 15360 u16 (5 convs + fe0 conv1)
  float* wm32f = alloc(16200);  // 32-cin MFMA pack: 32256 u16
  float* wspl = alloc(27648);   // split packs og0/og1/og2/dog: 55296 u16
  if (p * sizeof(float) > ws_size) return;
  unsigned* wdc2 = (unsigned*)wdc2f;
  unsigned short* wmh = (unsigned short*)wmf;
  unsigned short* wm32 = (unsigned short*)wm32f;
  unsigned short* wsp = (unsigned short*)wspl;

  // ---- 32-cin MFMA table: ob0 ob1 ob2 dob fc0 fc1 fc2(pad) ----
  W32Table T32;
  T32.e[0] = {obw[0], 32}; T32.e[1] = {obw[1], 32}; T32.e[2] = {obw[2], 32};
  T32.e[3] = {dobw, 32};   T32.e[4] = {fcw[0], 32}; T32.e[5] = {fcw[1], 32};
  T32.e[6] = {fcw[2], 16};
  auto o32 = [](int i) { return i * 4608; };

  // ---- split-pack table: og0, og1, og2(A only), dog ----
  SPTable TS;
  TS.e[0] = {ogw[0], 34, 18, 2, 0};
  TS.e[1] = {ogw[1], 34, 18, 2, 14336};
  TS.e[2] = {ogw[2], 16, 18, 2, 28672};
  TS.e[3] = {dogw, 34, 36, 3, 33792};
  const int o_og[3] = {0, 14336, 28672};
  const int o_dog = 33792;

  wdcpair_k<<<15, 256, 0, stream>>>(dcw[0], dcw[1], dcw[2], ddcw, wdc2);
  wmfma_k<<<60, 256, 0, stream>>>(few2[0], few1[1], few2[1], few1[2], few2[2],
                                  few1[0], wmh);
  wmfma32_k<<<126, 256, 0, stream>>>(T32, wm32);
  wsplit_k<<<dim3(84, 4), 256, 0, stream>>>(TS, wsp);

  // ---- feature pyramids (all f16 HWC) ----
  fe0_fused_k<<<dim3(32, 32, 8), 256, 0, stream>>>(
      ref, unr, wmh + 5 * 2560, feb1[0], wmh, feb2[0], fH0);
  fe12_fused_k<<<dim3(16, 16, 8), 256, 0, stream>>>(
      fH0, wmh + 2560, feb1[1], wmh + 2 * 2560, feb2[1], fH1, 256);
  fe12_fused_k<<<dim3(8, 8, 8), 256, 0, stream>>>(
      fH1, wmh + 3 * 2560, feb1[2], wmh + 4 * 2560, feb2[2], fH2, 128);

  const unsigned short* uH0 = fH0 + (size_t)4 * 65536 * 16;
  const unsigned short* uH1 = fH1 + (size_t)4 * 16384 * 16;
  const unsigned short* uH2 = fH2 + (size_t)4 * 4096 * 16;

  // ---- coarse-to-fine: fused [ob->og] then [deform->fc] per level ----
  obog_k<0><<<dim3(4, 8, 4), 256, 0, stream>>>(
      fH2, uH2, nullptr, wm32 + o32(2), obb[2], wsp + o_og[2], ogb[2], offs2, 64);
  defc_k<0><<<dim3(4, 8, 4), 256, 0, stream>>>(
      uH2, offs2, wdc2 + 2 * 1152, nullptr, wm32 + o32(6), fcb[2], ftH2, 64);
  obog_k<1><<<dim3(8, 16, 4), 256, 0, stream>>>(
      fH1, uH1, offs2, wm32 + o32(1), obb[1], wsp + o_og[1], ogb[1], offs1, 128);
  defc_k<1><<<dim3(8, 16, 4), 256, 0, stream>>>(
      uH1, offs1, wdc2 + 1 * 1152, ftH2, wm32 + o32(5), fcb[1], ftH1, 128);
  obog_k<1><<<dim3(16, 32, 4), 256, 0, stream>>>(
      fH0, uH0, offs1, wm32 + o32(0), obb[0], wsp + o_og[0], ogb[0], offs0, 256);
  defc_k<1><<<dim3(16, 32, 4), 256, 0, stream>>>(
      uH0, offs0, wdc2, ftH1, wm32 + o32(4), fcb[0], fHwc, 256);

  // ---- fused final head ----
  final_k<<<dim3(16, 16, 4), 256, 0, stream>>>(
      fH0, fHwc, offs0, wm32 + o32(3), dobb, wsp + o_dog, dogb, wdc2 + 3456,
      (float*)d_out);
}

// Round 14
// 508.854 us; speedup vs baseline: 1.0725x; 1.0050x over previous
//
#include <hip/hip_runtime.h>
#include <math.h>

typedef _Float16 half2_t __attribute__((ext_vector_type(2)));
typedef _Float16 half8 __attribute__((ext_vector_type(8)));
typedef float floatx4 __attribute__((ext_vector_type(4)));

__device__ __forceinline__ unsigned packh2(float a, float b) {
  half2_t h;
  h.x = (_Float16)a;
  h.y = (_Float16)b;
  return __builtin_bit_cast(unsigned, h);
}
__device__ __forceinline__ unsigned short f2h(float a) {
  return __builtin_bit_cast(unsigned short, (_Float16)a);
}
__device__ __forceinline__ float h2f(unsigned short u) {
  return (float)__builtin_bit_cast(_Float16, u);
}
__device__ __forceinline__ float dot2acc(unsigned a, unsigned b, float c) {
  half2_t ha = __builtin_bit_cast(half2_t, a);
  half2_t hb = __builtin_bit_cast(half2_t, b);
#if __has_builtin(__builtin_amdgcn_fdot2)
  return __builtin_amdgcn_fdot2(ha, hb, c, false);
#else
  c = fmaf((float)ha.x, (float)hb.x, c);
  return fmaf((float)ha.y, (float)hb.y, c);
#endif
}
__device__ __forceinline__ half8 splat8(_Float16 x) {
  half8 r;
#pragma unroll
  for (int j = 0; j < 8; ++j) r[j] = x;
  return r;
}

// ---------------- dc/ddc weight pair pack ----------------
__global__ __launch_bounds__(256) void wdcpair_k(
    const float* __restrict__ a, const float* __restrict__ b,
    const float* __restrict__ c, const float* __restrict__ d,
    unsigned* __restrict__ out) {
  int t = blockIdx.x * 256 + threadIdx.x;
  if (t < 3456) {
    int conv = t / 1152, r = t % 1152;
    int k = r / 128, cp = (r / 16) % 8, o = r & 15;
    const float* w = conv == 0 ? a : (conv == 1 ? b : c);
    out[t] = packh2(w[(o * 16 + 2 * cp) * 9 + k], w[(o * 16 + 2 * cp + 1) * 9 + k]);
  } else if (t < 3600) {
    int r = t - 3456;
    int o = r & 1, jp = (r >> 1) & 3, g = (r >> 3) & 1, k = r >> 4;
    out[t] = packh2(d[(o * 16 + g * 8 + 2 * jp) * 9 + k],
                    d[(o * 16 + g * 8 + 2 * jp + 1) * 9 + k]);
  }
}

// ---------------- MFMA prepack, 16-cin convs ----------------
__global__ __launch_bounds__(256) void wmfma_k(
    const float* __restrict__ w0, const float* __restrict__ w1,
    const float* __restrict__ w2, const float* __restrict__ w3,
    const float* __restrict__ w4, const float* __restrict__ w5,
    unsigned short* __restrict__ out) {
  int t = blockIdx.x * 256 + threadIdx.x;
  if (t >= 15360) return;
  int conv = t / 2560, r = t % 2560;
  int c = r / 512, L = (r / 8) % 64, j = r & 7;
  int quad = L >> 4, o = L & 15;
  int k = 32 * c + quad * 8 + j;
  int tap = k >> 4, cin = k & 15;
  float v;
  if (conv == 5) {
    v = (tap < 9 && cin == 0) ? w5[o * 9 + tap] : 0.f;
  } else {
    const float* w = conv == 0 ? w0 : conv == 1 ? w1 : conv == 2 ? w2 : conv == 3 ? w3 : w4;
    v = (tap < 9) ? w[((size_t)o * 16 + cin) * 9 + tap] : 0.f;
  }
  out[t] = f2h(v);
}

// ---------------- MFMA prepack, 32-cin convs ----------------
struct W32Entry { const float* src; int cin; };
struct W32Table { W32Entry e[8]; };
__global__ __launch_bounds__(256) void wmfma32_k(W32Table t, unsigned short* __restrict__ out) {
  int i = blockIdx.x * 256 + threadIdx.x;
  if (i >= 7 * 4608) return;
  int conv = i / 4608, r = i % 4608;
  int tap = r / 512, L = (r / 8) % 64, j = r & 7;
  int quad = L >> 4, o = L & 15;
  int c = quad * 8 + j;
  W32Entry en = t.e[conv];
  float v = (c < en.cin) ? en.src[((size_t)o * en.cin + c) * 9 + tap] : 0.f;
  out[i] = f2h(v);
}

// ---------------- split-cin MFMA prepack for og/dog ----------------
struct SPEntry { const float* src; int cin; int cout; int ct; int dstoff; };
struct SPTable { SPEntry e[4]; };
__global__ __launch_bounds__(256) void wsplit_k(SPTable t, unsigned short* __restrict__ out) {
  SPEntry en = t.e[blockIdx.y];
  int aSize = en.ct * 2560;
  int bSize = (en.cin > 16) ? en.ct * 4608 : 0;
  int i = blockIdx.x * 256 + threadIdx.x;
  if (i >= aSize + bSize) return;
  float v;
  if (i < aSize) {
    int ct = i / 2560, r = i % 2560;
    int c = r / 512, L = (r / 8) % 64, j = r & 7;
    int quad = L >> 4, o16 = L & 15;
    int k = 32 * c + quad * 8 + j;
    int tap = k >> 4, cin = k & 15;
    int o = ct * 16 + o16;
    v = (tap < 9 && o < en.cout) ? en.src[((size_t)o * en.cin + cin) * 9 + tap] : 0.f;
  } else {
    int r2 = i - aSize;
    int ct = r2 / 4608, r = r2 % 4608;
    int tap = r / 512, L = (r / 8) % 64, j = r & 7;
    int quad = L >> 4, o16 = L & 15;
    int cin = quad * 8 + j;
    int o = ct * 16 + o16;
    v = (cin < en.cin - 16 && o < en.cout)
            ? en.src[((size_t)o * en.cin + 16 + cin) * 9 + tap] : 0.f;
  }
  out[en.dstoff + i] = f2h(v);
}

// ---------------- MFMA 16-cin 3x3 conv over LDS HWC-16 tile (compile-time geometry) ----------------
template <int SW, int DPS, int POS, int OW, int RELU, int DOMASK>
__device__ __forceinline__ void conv_mfma(
    const unsigned short* __restrict__ src,
    unsigned short* __restrict__ dst, const half8* __restrict__ bf,
    const float* __restrict__ bias, int tid, int gby, int gbx, int bound) {
  const int lane = tid & 63, wid = tid >> 6;
  const int quad = lane >> 4, m = lane & 15;
  const int tap01 = quad >> 1, cin8 = (quad & 1) * 8;
  constexpr int ntiles = (POS + 15) >> 4;
  float bs = bias[m];
  half8 zero;
#pragma unroll
  for (int j = 0; j < 8; ++j) zero[j] = (_Float16)0;
  for (int T = wid; T < ntiles; T += 4) {
    int pa = T * 16 + m;
    pa = pa < POS ? pa : POS - 1;
    int ya = pa / OW, xa = pa - ya * OW;
    floatx4 acc = {0.f, 0.f, 0.f, 0.f};
#pragma unroll
    for (int c = 0; c < 5; ++c) {
      int tap = 2 * c + tap01;
      half8 a = zero;
      if (tap < 9) {
        int dy = tap / 3, dx = tap - (tap / 3) * 3;
        a = *(const half8*)(src + ((ya + dy) * SW + xa + dx) * 16 + cin8);
      }
      acc = __builtin_amdgcn_mfma_f32_16x16x32_f16(a, bf[c], acc, 0, 0, 0);
    }
#pragma unroll
    for (int r = 0; r < 4; ++r) {
      int pd = T * 16 + quad * 4 + r;
      if (pd < POS) {
        float v = acc[r] + bs;
        if (RELU) v = fmaxf(v, 0.f);
        if (DOMASK) {
          int yd = pd / OW, xd = pd - (pd / OW) * OW;
          int gy = gby + yd, gx = gbx + xd;
          if (gy < 0 || gy >= bound || gx < 0 || gx >= bound) v = 0.f;
        }
        dst[pd * DPS + m] = f2h(v);
      }
    }
  }
}

// ---------------- MFMA 32-cin 3x3 conv over LDS HWC-32 tile (compile-time geometry) ----------------
template <int SW, int DPS, int POS, int OW, int RELU, int DOMASK>
__device__ __forceinline__ void conv_mfma32(
    const unsigned short* __restrict__ src,
    unsigned short* __restrict__ dst, const half8* __restrict__ bf,
    const float* __restrict__ bias, int tid, int gby, int gbx, int bound) {
  const int lane = tid & 63, wid = tid >> 6;
  const int quad = lane >> 4, m = lane & 15;
  constexpr int ntiles = (POS + 15) >> 4;
  float bs = bias[m];
  for (int T = wid; T < ntiles; T += 4) {
    int pa = T * 16 + m;
    pa = pa < POS ? pa : POS - 1;
    int ya = pa / OW, xa = pa - ya * OW;
    floatx4 acc = {0.f, 0.f, 0.f, 0.f};
#pragma unroll
    for (int tap = 0; tap < 9; ++tap) {
      int dy = tap / 3, dx = tap - (tap / 3) * 3;
      half8 a = *(const half8*)(src + ((ya + dy) * SW + xa + dx) * 32 + quad * 8);
      acc = __builtin_amdgcn_mfma_f32_16x16x32_f16(a, bf[tap], acc, 0, 0, 0);
    }
#pragma unroll
    for (int r = 0; r < 4; ++r) {
      int pd = T * 16 + quad * 4 + r;
      if (pd < POS) {
        float v = acc[r] + bs;
        if (RELU) v = fmaxf(v, 0.f);
        if (DOMASK) {
          int yd = pd / OW, xd = pd - (pd / OW) * OW;
          int gy = gby + yd, gx = gbx + xd;
          if (gy < 0 || gy >= bound || gx < 0 || gx >= bound) v = 0.f;
        }
        dst[pd * DPS + m] = f2h(v);
      }
    }
  }
}

// ---------------- split-cin MFMA 3x3 conv ----------------
template <int CT, int HASB, int NT>
__device__ __forceinline__ void conv_split_mfma(
    const unsigned short* __restrict__ srcB, const unsigned short* __restrict__ srcO,
    const unsigned short* __restrict__ wbase, float* __restrict__ outLds, int OSTRIDE,
    const float* __restrict__ bias, int NOUT, int relu, int tid) {
  const int lane = tid & 63, wid = tid >> 6;
  const int quad = lane >> 4, m = lane & 15;
  const int tap01 = quad >> 1, cin8 = (quad & 1) * 8;
  half8 zero;
#pragma unroll
  for (int j = 0; j < 8; ++j) zero[j] = (_Float16)0;
  floatx4 acc[CT][NT];
#pragma unroll
  for (int ct = 0; ct < CT; ++ct)
#pragma unroll
    for (int t = 0; t < NT; ++t) acc[ct][t] = floatx4{0.f, 0.f, 0.f, 0.f};
#pragma unroll
  for (int ct = 0; ct < CT; ++ct) {
    half8 bfA[5];
#pragma unroll
    for (int c = 0; c < 5; ++c)
      bfA[c] = *(const half8*)(wbase + ((ct * 5 + c) * 64 + lane) * 8);
#pragma unroll
    for (int t = 0; t < NT; ++t) {
      int pa = (wid + 4 * t) * 16 + m;
      int ya = pa >> 4, xa = pa & 15;
#pragma unroll
      for (int c = 0; c < 5; ++c) {
        int tap = 2 * c + tap01;
        half8 a = zero;
        if (tap < 9) {
          int dy = tap / 3, dx = tap - (tap / 3) * 3;
          a = *(const half8*)(srcB + ((ya + dy) * 18 + xa + dx) * 18 + cin8);
        }
        acc[ct][t] = __builtin_amdgcn_mfma_f32_16x16x32_f16(a, bfA[c], acc[ct][t], 0, 0, 0);
      }
    }
  }
  if (HASB) {
    const unsigned short* wb = wbase + CT * 2560;
#pragma unroll
    for (int ct = 0; ct < CT; ++ct) {
      half8 bfB[9];
#pragma unroll
      for (int c = 0; c < 9; ++c)
        bfB[c] = *(const half8*)(wb + ((ct * 9 + c) * 64 + lane) * 8);
#pragma unroll
      for (int t = 0; t < NT; ++t) {
        int pa = (wid + 4 * t) * 16 + m;
        int ya = pa >> 4, xa = pa & 15;
#pragma unroll
        for (int tap = 0; tap < 9; ++tap) {
          int dy = tap / 3, dx = tap - (tap / 3) * 3;
          half8 a = *(const half8*)(srcO + ((ya + dy) * 18 + xa + dx) * 34 + quad * 8);
          acc[ct][t] = __builtin_amdgcn_mfma_f32_16x16x32_f16(a, bfB[tap], acc[ct][t], 0, 0, 0);
        }
      }
    }
  }
  __syncthreads();
#pragma unroll
  for (int ct = 0; ct < CT; ++ct) {
    int o = ct * 16 + m;
#pragma unroll
    for (int t = 0; t < NT; ++t) {
#pragma unroll
      for (int r = 0; r < 4; ++r) {
        int pd = (wid + 4 * t) * 16 + quad * 4 + r;
        if (o < NOUT) {
          float v = acc[ct][t][r] + bias[o];
          if (relu) v = fmaxf(v, 0.f);
          outLds[pd * OSTRIDE + o] = v;
        }
      }
    }
  }
}

// ---------------- fused FE level-0 -> f16 HWC only ----------------
__global__ __launch_bounds__(256) void fe0_fused_k(
    const float* __restrict__ refI, const float* __restrict__ unrI,
    const unsigned short* __restrict__ wm1, const float* __restrict__ b1,
    const unsigned short* __restrict__ wm2, const float* __restrict__ b2,
    unsigned short* __restrict__ outH) {
  __shared__ __attribute__((aligned(16))) unsigned short bufA[441 * 16];
  __shared__ __attribute__((aligned(16))) unsigned short c1h[361 * 16];
  const int z = blockIdx.z;
  const int im = z >> 2, n = z & 3;
  const float* img = (im ? unrI : refI) + (size_t)n * 512 * 512;
  unsigned short* outh = outH + (size_t)z * 65536 * 16;
  const int py0 = blockIdx.y * 8, px0 = blockIdx.x * 8;
  const int tid = threadIdx.x;

  half8 bf1[5], bf2[5];
  {
    const int lane = tid & 63;
#pragma unroll
    for (int c = 0; c < 5; ++c) {
      bf1[c] = *(const half8*)(wm1 + (c * 64 + lane) * 8);
      bf2[c] = *(const half8*)(wm2 + (c * 64 + lane) * 8);
    }
  }

  {
    unsigned* s32 = (unsigned*)bufA;
    for (int i = tid; i < 441; i += 256) {
      int yi = i / 21, xi = i - yi * 21;
      int gy = 2 * py0 - 3 + yi, gx = 2 * px0 - 3 + xi;
      float v = 0.f;
      if (gy >= 0 && gy < 512 && gx >= 0 && gx < 512) v = img[gy * 512 + gx];
      uint4 q0 = {packh2(v, 0.f), 0u, 0u, 0u};
      uint4 q1 = {0u, 0u, 0u, 0u};
      *(uint4*)(s32 + i * 8) = q0;
      *(uint4*)(s32 + i * 8 + 4) = q1;
    }
  }
  __syncthreads();

  conv_mfma<21, 16, 361, 19, 1, 1>(bufA, c1h, bf1, b1, tid, 2 * py0 - 2, 2 * px0 - 2, 512);
  __syncthreads();
  conv_mfma<19, 18, 289, 17, 1, 0>(c1h, bufA, bf2, b2, tid, 0, 0, 0);
  __syncthreads();

  // maxpool: channel-pair packed (v_pk_max_f16), direct coalesced HWC writes
  for (int i = tid; i < 512; i += 256) {
    int cp = i & 7, r = i >> 3;
    int py = r >> 3, px = r & 7;
    half2_t m;
    m.x = (_Float16)0;
    m.y = (_Float16)0;
#pragma unroll
    for (int dy = 0; dy < 3; ++dy) {
      int gy = 2 * (py0 + py) - 1 + dy;
      if (gy < 0 || gy >= 512) continue;
#pragma unroll
      for (int dx = 0; dx < 3; ++dx) {
        int gx = 2 * (px0 + px) - 1 + dx;
        if (gx < 0 || gx >= 512) continue;
        half2_t v = __builtin_bit_cast(
            half2_t, *(const unsigned*)(bufA + ((2 * py + dy) * 17 + 2 * px + dx) * 18 + 2 * cp));
        m = __builtin_elementwise_max(m, v);
      }
    }
    *(unsigned*)(outh + (((size_t)(py0 + py)) * 256 + px0 + px) * 16 + 2 * cp) =
        __builtin_bit_cast(unsigned, m);
  }
}

// ---------------- fused FE level-1/2: f16 HWC in, f16 HWC out ----------------
__global__ __launch_bounds__(256) void fe12_fused_k(
    const unsigned short* __restrict__ inH,
    const unsigned short* __restrict__ wm1, const float* __restrict__ b1,
    const unsigned short* __restrict__ wm2, const float* __restrict__ b2,
    unsigned short* __restrict__ outH, int Hin) {
  __shared__ __attribute__((aligned(16))) unsigned short inh[441 * 16];
  __shared__ __attribute__((aligned(16))) unsigned short c1h[361 * 16];
  const int n = blockIdx.z;
  const int Ho = Hin >> 1;
  const int py0 = blockIdx.y * 8, px0 = blockIdx.x * 8;
  const int tid = threadIdx.x;
  const unsigned short* inN = inH + (size_t)n * Hin * Hin * 16;

  half8 bf1[5], bf2[5];
  {
    const int lane = tid & 63;
#pragma unroll
    for (int c = 0; c < 5; ++c) {
      bf1[c] = *(const half8*)(wm1 + (c * 64 + lane) * 8);
      bf2[c] = *(const half8*)(wm2 + (c * 64 + lane) * 8);
    }
  }

  unsigned* inh32 = (unsigned*)inh;
  for (int i = tid; i < 8 * 441; i += 256) {
    int cp = i / 441, r = i - cp * 441;
    int yi = r / 21, xi = r - yi * 21;
    int gy = 2 * py0 - 3 + yi, gx = 2 * px0 - 3 + xi;
    unsigned val = 0u;
    if (gy >= 0 && gy < Hin && gx >= 0 && gx < Hin)
      val = *(const unsigned*)(inN + ((size_t)gy * Hin + gx) * 16 + 2 * cp);
    inh32[r * 8 + cp] = val;
  }
  __syncthreads();

  conv_mfma<21, 16, 361, 19, 1, 1>(inh, c1h, bf1, b1, tid, 2 * py0 - 2, 2 * px0 - 2, Hin);
  __syncthreads();
  conv_mfma<19, 18, 289, 17, 1, 0>(c1h, inh, bf2, b2, tid, 0, 0, 0);
  __syncthreads();

  unsigned short* outp = outH + (size_t)n * Ho * Ho * 16;
  for (int i = tid; i < 512; i += 256) {
    int cp = i & 7, r = i >> 3;
    int py = r >> 3, px = r & 7;
    half2_t m;
    m.x = (_Float16)0;
    m.y = (_Float16)0;
#pragma unroll
    for (int dy = 0; dy < 3; ++dy) {
      int gy = 2 * (py0 + py) - 1 + dy;
      if (gy < 0 || gy >= Hin) continue;
#pragma unroll
      for (int dx = 0; dx < 3; ++dx) {
        int gx = 2 * (px0 + px) - 1 + dx;
        if (gx < 0 || gx >= Hin) continue;
        half2_t v = __builtin_bit_cast(
            half2_t, *(const unsigned*)(inh + ((2 * py + dy) * 17 + 2 * px + dx) * 18 + 2 * cp));
        m = __builtin_elementwise_max(m, v);
      }
    }
    *(unsigned*)(outp + (((size_t)(py0 + py)) * Ho + px0 + px) * 16 + 2 * cp) =
        __builtin_bit_cast(unsigned, m);
  }
}

// ---------------- fused offset head (16x8 tiles): ob(MFMA) -> og(split MFMA) -> offs(f16) ----------------
template <int HAS_UP>
__global__ __launch_bounds__(256) void obog_k(
    const unsigned short* __restrict__ rfh, const unsigned short* __restrict__ ufh,
    const unsigned short* __restrict__ offsUp,
    const unsigned short* __restrict__ wmob, const float* __restrict__ bob,
    const unsigned short* __restrict__ wog, const float* __restrict__ bog,
    unsigned short* __restrict__ offsOut, int H) {
  __shared__ __attribute__((aligned(16))) unsigned POOL[5460];
  const int n = blockIdx.z;
  const int bx = blockIdx.x * 16, by = blockIdx.y * 8;
  const int tid = threadIdx.x;
  const size_t HH = (size_t)H * H;
  const unsigned short* r0h = rfh + (size_t)n * HH * 16;
  const unsigned short* u0h = ufh + (size_t)n * HH * 16;

  for (int i = tid; i < 3840; i += 256) {
    int cp = i / 240, r = i - cp * 240;
    int ly = r / 20, lx = r - ly * 20;
    int gy = by + ly - 2, gx = bx + lx - 2;
    unsigned val = 0u;
    if (gy >= 0 && gy < H && gx >= 0 && gx < H) {
      const unsigned short* s16 = (cp < 8) ? r0h : u0h;
      int ch = (cp < 8) ? 2 * cp : 2 * cp - 16;
      val = *(const unsigned*)(s16 + ((size_t)gy * H + gx) * 16 + ch);
    }
    POOL[r * 16 + cp] = val;
  }
  __syncthreads();

  {
    half8 bf[9];
    const int lane = tid & 63;
#pragma unroll
    for (int c = 0; c < 9; ++c) bf[c] = *(const half8*)(wmob + (c * 64 + lane) * 8);
    conv_mfma32<20, 18, 180, 18, 1, 1>((const unsigned short*)POOL,
                                       (unsigned short*)(POOL + 3840), bf, bob,
                                       tid, by - 1, bx - 1, H);
  }
  __syncthreads();

  if (HAS_UP) {
    const int H2 = H >> 1;
    const unsigned short* os = offsUp + (size_t)n * 18 * H2 * H2;
    for (int i = tid; i < 16 * 180; i += 256) {
      int cp = i / 180, r = i - cp * 180;
      unsigned val = 0u;
      if (cp < 9) {
        int y1 = r / 18, x1 = r - y1 * 18;
        int gy = by + y1 - 1, gx = bx + x1 - 1;
        if (gy >= 0 && gy < H && gx >= 0 && gx < H) {
          float sy = 0.5f * gy - 0.25f, sx = 0.5f * gx - 0.25f;
          float y0f = floorf(sy), x0f = floorf(sx);
          float wy = sy - y0f, wx = sx - x0f;
          int y0 = (int)y0f, x0 = (int)x0f;
          int y0c = min(max(y0, 0), H2 - 1), y1c = min(max(y0 + 1, 0), H2 - 1);
          int x0c = min(max(x0, 0), H2 - 1), x1c = min(max(x0 + 1, 0), H2 - 1);
          const unsigned short* sp = os + (size_t)(2 * cp) * H2 * H2;
          float v0 = (1.f - wy) * ((1.f - wx) * h2f(sp[y0c * H2 + x0c]) + wx * h2f(sp[y0c * H2 + x1c])) +
                     wy * ((1.f - wx) * h2f(sp[y1c * H2 + x0c]) + wx * h2f(sp[y1c * H2 + x1c]));
          sp += (size_t)H2 * H2;
          float v1 = (1.f - wy) * ((1.f - wx) * h2f(sp[y0c * H2 + x0c]) + wx * h2f(sp[y0c * H2 + x1c])) +
                     wy * ((1.f - wx) * h2f(sp[y1c * H2 + x0c]) + wx * h2f(sp[y1c * H2 + x1c]));
          val = packh2(v0, v1);
        }
      }
      POOL[r * 17 + cp] = val;
    }
    __syncthreads();
  }

  conv_split_mfma<2, HAS_UP, 2>((const unsigned short*)(POOL + 3840),
                                (const unsigned short*)POOL, wog,
                                (float*)POOL, 19, bog, 18, 1, tid);
  __syncthreads();

  {
    int pix = tid & 127, half = tid >> 7;
    const float* of = (const float*)POOL + (size_t)pix * 19 + half * 9;
    int ty = pix >> 4, tx = pix & 15;
    unsigned short* op = offsOut + (size_t)n * 18 * HH + (size_t)(half * 9) * HH +
                         (size_t)(by + ty) * H + (bx + tx);
#pragma unroll
    for (int o = 0; o < 9; ++o) op[(size_t)o * HH] = f2h(of[o]);
  }
}

// ---------------- fused feature head: deform(f16 pk blend + dot2) -> fc(MFMA) -> f16 HWC ----------------
template <int HAS_UP>
__global__ __launch_bounds__(256) void defc_k(
    const unsigned short* __restrict__ ufHWC, const unsigned short* __restrict__ offs,
    const unsigned* __restrict__ wdc2, const unsigned short* __restrict__ featsUpH,
    const unsigned short* __restrict__ wmfc, const float* __restrict__ bfc,
    unsigned short* __restrict__ outHwc, int H) {
  __shared__ __attribute__((aligned(16))) unsigned ldsC[180 * 17];
  const int n = blockIdx.z;
  const int bx = blockIdx.x * 16, by = blockIdx.y * 8;
  const int tid = threadIdx.x;
  const size_t HH = (size_t)H * H;
  const unsigned short* inN = ufHWC + (size_t)n * HH * 16;
  const unsigned short* offN = offs + (size_t)n * 18 * HH;

  half8 bf[9];
  {
    const int lane = tid & 63;
#pragma unroll
    for (int c = 0; c < 9; ++c) bf[c] = *(const half8*)(wmfc + (c * 64 + lane) * 8);
  }

  for (int p = tid; p < 180; p += 256) {
    int y1 = p / 18, x1 = p - y1 * 18;
    int h = by + y1 - 1, w = bx + x1 - 1;
    bool valid = (h >= 0 && h < H && w >= 0 && w < H);
    float acc[16];
#pragma unroll
    for (int o = 0; o < 16; ++o) acc[o] = 0.f;
    if (valid) {
      size_t hw = (size_t)h * H + w;
#pragma unroll
      for (int k = 0; k < 9; ++k) {
        int ky = k / 3 - 1, kx = k % 3 - 1;
        float oy = h2f(offN[(size_t)(2 * k) * HH + hw]);
        float ox = h2f(offN[(size_t)(2 * k + 1) * HH + hw]);
        float py = (float)(h + ky) + oy;
        float px = (float)(w + kx) + ox;
        float y0f = floorf(py), x0f = floorf(px);
        float fy = py - y0f, fx = px - x0f;
        int y0 = (int)y0f, x0 = (int)x0f;
        bool vy0 = ((unsigned)y0 < (unsigned)H);
        bool vy1 = ((unsigned)(y0 + 1) < (unsigned)H);
        bool vx0 = ((unsigned)x0 < (unsigned)H);
        bool vx1 = ((unsigned)(x0 + 1) < (unsigned)H);
        int y0c = min(max(y0, 0), H - 1), y1c = min(max(y0 + 1, 0), H - 1);
        int x0c = min(max(x0, 0), H - 1), x1c = min(max(x0 + 1, 0), H - 1);
        float w00 = (vy0 && vx0) ? (1.f - fy) * (1.f - fx) : 0.f;
        float w01 = (vy0 && vx1) ? (1.f - fy) * fx : 0.f;
        float w10 = (vy1 && vx0) ? fy * (1.f - fx) : 0.f;
        float w11 = (vy1 && vx1) ? fy * fx : 0.f;
        half8 s00 = splat8((_Float16)w00);
        half8 s01 = splat8((_Float16)w01);
        half8 s10 = splat8((_Float16)w10);
        half8 s11 = splat8((_Float16)w11);
        const unsigned short* p00 = inN + ((size_t)y0c * H + x0c) * 16;
        const unsigned short* p01 = inN + ((size_t)y0c * H + x1c) * 16;
        const unsigned short* p10 = inN + ((size_t)y1c * H + x0c) * 16;
        const unsigned short* p11 = inN + ((size_t)y1c * H + x1c) * 16;
        const unsigned* wk2 = wdc2 + k * 128;
#pragma unroll
        for (int c8 = 0; c8 < 2; ++c8) {
          half8 a00 = *(const half8*)(p00 + c8 * 8);
          half8 a01 = *(const half8*)(p01 + c8 * 8);
          half8 a10 = *(const half8*)(p10 + c8 * 8);
          half8 a11 = *(const half8*)(p11 + c8 * 8);
          half8 vb = a00 * s00 + a01 * s01 + a10 * s10 + a11 * s11;
          uint4 vp = __builtin_bit_cast(uint4, vb);
          unsigned vpa[4] = {vp.x, vp.y, vp.z, vp.w};
#pragma unroll
          for (int jp = 0; jp < 4; ++jp) {
            const unsigned* wrow = wk2 + (c8 * 4 + jp) * 16;
#pragma unroll
            for (int o = 0; o < 16; ++o)
              acc[o] = dot2acc(vpa[jp], wrow[o], acc[o]);
          }
        }
      }
    }
#pragma unroll
    for (int cc = 0; cc < 8; ++cc) {
      float a0 = valid ? fmaxf(acc[2 * cc], 0.f) : 0.f;
      float a1 = valid ? fmaxf(acc[2 * cc + 1], 0.f) : 0.f;
      ldsC[p * 17 + cc] = packh2(a0, a1);
      if (!HAS_UP) ldsC[p * 17 + 8 + cc] = 0u;
    }
  }

  if (HAS_UP) {
    const int H2 = H >> 1;
    const unsigned short* fu = featsUpH + (size_t)n * H2 * H2 * 16;
    for (int i = tid; i < 8 * 180; i += 256) {
      int cp = i / 180, r = i - cp * 180;
      int y1 = r / 18, x1 = r - y1 * 18;
      int gy = by + y1 - 1, gx = bx + x1 - 1;
      unsigned val = 0u;
      if (gy >= 0 && gy < H && gx >= 0 && gx < H) {
        float sy = 0.5f * gy - 0.25f, sx = 0.5f * gx - 0.25f;
        float y0f = floorf(sy), x0f = floorf(sx);
        float wy = sy - y0f, wx = sx - x0f;
        int y0 = (int)y0f, x0 = (int)x0f;
        int y0c = min(max(y0, 0), H2 - 1), y1c = min(max(y0 + 1, 0), H2 - 1);
        int x0c = min(max(x0, 0), H2 - 1), x1c = min(max(x0 + 1, 0), H2 - 1);
        half2_t h00 = __builtin_bit_cast(half2_t, *(const unsigned*)(fu + ((size_t)y0c * H2 + x0c) * 16 + 2 * cp));
        half2_t h01 = __builtin_bit_cast(half2_t, *(const unsigned*)(fu + ((size_t)y0c * H2 + x1c) * 16 + 2 * cp));
        half2_t h10 = __builtin_bit_cast(half2_t, *(const unsigned*)(fu + ((size_t)y1c * H2 + x0c) * 16 + 2 * cp));
        half2_t h11 = __builtin_bit_cast(half2_t, *(const unsigned*)(fu + ((size_t)y1c * H2 + x1c) * 16 + 2 * cp));
        float v0 = (1.f - wy) * ((1.f - wx) * (float)h00.x + wx * (float)h01.x) +
                   wy * ((1.f - wx) * (float)h10.x + wx * (float)h11.x);
        float v1 = (1.f - wy) * ((1.f - wx) * (float)h00.y + wx * (float)h01.y) +
                   wy * ((1.f - wx) * (float)h10.y + wx * (float)h11.y);
        val = packh2(v0, v1);
      }
      ldsC[r * 17 + 8 + cp] = val;
    }
  }
  __syncthreads();

  {
    const int lane = tid & 63, wid = tid >> 6;
    const int quad = lane >> 4, m = lane & 15;
    const unsigned short* src = (const unsigned short*)ldsC;
    float bs = bfc[m];
    for (int T = wid; T < 8; T += 4) {
      int pa = T * 16 + m;
      int ya = pa >> 4, xa = pa & 15;
      floatx4 acc = {0.f, 0.f, 0.f, 0.f};
#pragma unroll
      for (int tap = 0; tap < 9; ++tap) {
        int dy = tap / 3, dx = tap - (tap / 3) * 3;
        half8 a = *(const half8*)(src + ((ya + dy) * 18 + xa + dx) * 34 + quad * 8);
        acc = __builtin_amdgcn_mfma_f32_16x16x32_f16(a, bf[tap], acc, 0, 0, 0);
      }
#pragma unroll
      for (int r = 0; r < 4; ++r) {
        int pd = T * 16 + quad * 4 + r;
        int yd = pd >> 4, xd = pd & 15;
        float v = fmaxf(acc[r] + bs, 0.f);
        outHwc[((size_t)n * HH + (size_t)(by + yd) * H + bx + xd) * 16 + m] = f2h(v);
      }
    }
  }
}

// ---------------- fused final head (16x16): dob -> dog(split MFMA) -> deform dg=2 (pk+dot2) ----
__global__ __launch_bounds__(256) void final_k(
    const unsigned short* __restrict__ rfh, const unsigned short* __restrict__ f0hwc,
    const unsigned short* __restrict__ offs0,
    const unsigned short* __restrict__ wmdob, const float* __restrict__ bdob,
    const unsigned short* __restrict__ wdog, const float* __restrict__ bdog,
    const unsigned* __restrict__ wddc2, float* __restrict__ out) {
  __shared__ __attribute__((aligned(16))) unsigned POOL[9472];
  const int H = 256;
  const size_t HH = 65536;
  const int n = blockIdx.z;
  const int bx = blockIdx.x * 16, by = blockIdx.y * 16;
  const int tid = threadIdx.x;
  const unsigned short* r0h = rfh + (size_t)n * HH * 16;
  const unsigned short* f0h = f0hwc + (size_t)n * HH * 16;

  for (int i = tid; i < 6400; i += 256) {
    int cp = i / 400, r = i - cp * 400;
    int ly = r / 20, lx = r - ly * 20;
    int gy = by + ly - 2, gx = bx + lx - 2;
    unsigned val = 0u;
    if (gy >= 0 && gy < H && gx >= 0 && gx < H) {
      const unsigned short* base = (cp < 8) ? r0h : f0h;
      int ch = (cp < 8) ? 2 * cp : 2 * cp - 16;
      val = *(const unsigned*)(base + ((size_t)gy * H + gx) * 16 + ch);
    }
    POOL[r * 16 + cp] = val;
  }
  __syncthreads();

  {
    half8 bf[9];
    const int lane = tid & 63;
#pragma unroll
    for (int c = 0; c < 9; ++c) bf[c] = *(const half8*)(wmdob + (c * 64 + lane) * 8);
    conv_mfma32<20, 18, 324, 18, 0, 1>((const unsigned short*)POOL,
                                       (unsigned short*)(POOL + 6400), bf, bdob,
                                       tid, by - 1, bx - 1, H);
  }
  __syncthreads();

  {
    const unsigned short* os = offs0 + (size_t)n * 18 * HH;
    for (int i = tid; i < 16 * 324; i += 256) {
      int cp = i / 324, r = i - cp * 324;
      unsigned val = 0u;
      if (cp < 9) {
        int y1 = r / 18, x1 = r - y1 * 18;
        int gy = by + y1 - 1, gx = bx + x1 - 1;
        if (gy >= 0 && gy < H && gx >= 0 && gx < H) {
          const unsigned short* s = os + (size_t)(2 * cp) * HH + (size_t)gy * H + gx;
          val = (unsigned)s[0] | ((unsigned)s[HH] << 16);
        }
      }
      POOL[r * 17 + cp] = val;
    }
    __syncthreads();
  }

  conv_split_mfma<3, 1, 4>((const unsigned short*)(POOL + 6400),
                           (const unsigned short*)POOL, wdog,
                           (float*)POOL, 37, bdog, 36, 0, tid);
  __syncthreads();

  {
    const int ty = tid >> 4, tx = tid & 15;
    const int h = by + ty, w = bx + tx;
    const float* a36 = (const float*)POOL + (size_t)tid * 37;
    float rr[2] = {0.f, 0.f};
#pragma unroll
    for (int g = 0; g < 2; ++g) {
#pragma unroll
      for (int k = 0; k < 9; ++k) {
        int ky = k / 3 - 1, kx = k % 3 - 1;
        float oy = a36[(g * 9 + k) * 2 + 0];
        float ox = a36[(g * 9 + k) * 2 + 1];
        float py = (float)(h + ky) + oy;
        float px = (float)(w + kx) + ox;
        float y0f = floorf(py), x0f = floorf(px);
        float fy = py - y0f, fx = px - x0f;
        int y0 = (int)y0f, x0 = (int)x0f;
        bool vy0 = ((unsigned)y0 < (unsigned)H);
        bool vy1 = ((unsigned)(y0 + 1) < (unsigned)H);
        bool vx0 = ((unsigned)x0 < (unsigned)H);
        bool vx1 = ((unsigned)(x0 + 1) < (unsigned)H);
        int y0c = min(max(y0, 0), H - 1), y1c = min(max(y0 + 1, 0), H - 1);
        int x0c = min(max(x0, 0), H - 1), x1c = min(max(x0 + 1, 0), H - 1);
        float w00 = (vy0 && vx0) ? (1.f - fy) * (1.f - fx) : 0.f;
        float w01 = (vy0 && vx1) ? (1.f - fy) * fx : 0.f;
        float w10 = (vy1 && vx0) ? fy * (1.f - fx) : 0.f;
        float w11 = (vy1 && vx1) ? fy * fx : 0.f;
        half8 s00 = splat8((_Float16)w00);
        half8 s01 = splat8((_Float16)w01);
        half8 s10 = splat8((_Float16)w10);
        half8 s11 = splat8((_Float16)w11);
        const unsigned short* p00 = f0h + ((size_t)y0c * H + x0c) * 16 + g * 8;
        const unsigned short* p01 = f0h + ((size_t)y0c * H + x1c) * 16 + g * 8;
        const unsigned short* p10 = f0h + ((size_t)y1c * H + x0c) * 16 + g * 8;
        const unsigned short* p11 = f0h + ((size_t)y1c * H + x1c) * 16 + g * 8;
        half8 a00 = *(const half8*)p00;
        half8 a01 = *(const half8*)p01;
        half8 a10 = *(const half8*)p10;
        half8 a11 = *(const half8*)p11;
        half8 vb = a00 * s00 + a01 * s01 + a10 * s10 + a11 * s11;
        uint4 vp = __builtin_bit_cast(uint4, vb);
        unsigned vpa[4] = {vp.x, vp.y, vp.z, vp.w};
        const unsigned* wk2 = wddc2 + ((size_t)k * 2 + g) * 8;
#pragma unroll
        for (int jp = 0; jp < 4; ++jp) {
          rr[0] = dot2acc(vpa[jp], wk2[jp * 2 + 0], rr[0]);
          rr[1] = dot2acc(vpa[jp], wk2[jp * 2 + 1], rr[1]);
        }
      }
    }
    out[((size_t)n * 2 + 0) * HH + (size_t)h * H + w] = rr[0];
    out[((size_t)n * 2 + 1) * HH + (size_t)h * H + w] = rr[1];
  }
}

extern "C" void kernel_launch(void* const* d_in, const int* in_sizes, int n_in,
                              void* d_out, int out_size, void* d_ws, size_t ws_size,
                              hipStream_t stream) {
  auto F = [&](int i) { return (const float*)d_in[i]; };
  const float* ref = F(0);
  const float* unr = F(1);
  const float* few1[3] = {F(2), F(6), F(10)};
  const float* feb1[3] = {F(3), F(7), F(11)};
  const float* few2[3] = {F(4), F(8), F(12)};
  const float* feb2[3] = {F(5), F(9), F(13)};
  const float* obw[3] = {F(14), F(16), F(18)};
  const float* obb[3] = {F(15), F(17), F(19)};
  const float* ogw[3] = {F(20), F(22), F(24)};
  const float* ogb[3] = {F(21), F(23), F(25)};
  const float* dcw[3] = {F(26), F(27), F(28)};
  const float* fcw[3] = {F(29), F(31), F(33)};
  const float* fcb[3] = {F(30), F(32), F(34)};
  const float* dobw = F(35);
  const float* dobb = F(36);
  const float* dogw = F(37);
  const float* dogb = F(38);
  const float* ddcw = F(39);

  // ---- workspace (floats) ----
  float* ws = (float*)d_ws;
  size_t p = 0;
  auto alloc = [&](size_t nf) { float* r = ws + p; p += nf; return r; };
  unsigned short* fH0 = (unsigned short*)alloc((size_t)8 * 16 * 65536 / 2);
  unsigned short* fH1 = (unsigned short*)alloc((size_t)8 * 16 * 16384 / 2);
  unsigned short* fH2 = (unsigned short*)alloc((size_t)8 * 16 * 4096 / 2);
  unsigned short* ftH1 = (unsigned short*)alloc((size_t)4 * 16 * 16384 / 2);
  unsigned short* ftH2 = (unsigned short*)alloc((size_t)4 * 16 * 4096 / 2);
  unsigned short* fHwc = (unsigned short*)alloc((size_t)4 * 16 * 65536 / 2);
  unsigned short* offs0 = (unsigned short*)alloc((size_t)4 * 18 * 65536 / 2);
  unsigned short* offs1 = (unsigned short*)alloc((size_t)4 * 18 * 16384 / 2);
  unsigned short* offs2 = (unsigned short*)alloc((size_t)4 * 18 * 4096 / 2);
  float* wdc2f = alloc(3600);
  float* wmf = alloc(7680);
  float* wm32f = alloc(16200);
  float* wspl = alloc(27648);
  if (p * sizeof(float) > ws_size) return;
  unsigned* wdc2 = (unsigned*)wdc2f;
  unsigned short* wmh = (unsigned short*)wmf;
  unsigned short* wm32 = (unsigned short*)wm32f;
  unsigned short* wsp = (unsigned short*)wspl;

  W32Table T32;
  T32.e[0] = {obw[0], 32}; T32.e[1] = {obw[1], 32}; T32.e[2] = {obw[2], 32};
  T32.e[3] = {dobw, 32};   T32.e[4] = {fcw[0], 32}; T32.e[5] = {fcw[1], 32};
  T32.e[6] = {fcw[2], 16};
  auto o32 = [](int i) { return i * 4608; };

  SPTable TS;
  TS.e[0] = {ogw[0], 34, 18, 2, 0};
  TS.e[1] = {ogw[1], 34, 18, 2, 14336};
  TS.e[2] = {ogw[2], 16, 18, 2, 28672};
  TS.e[3] = {dogw, 34, 36, 3, 33792};
  const int o_og[3] = {0, 14336, 28672};
  const int o_dog = 33792;

  wdcpair_k<<<15, 256, 0, stream>>>(dcw[0], dcw[1], dcw[2], ddcw, wdc2);
  wmfma_k<<<60, 256, 0, stream>>>(few2[0], few1[1], few2[1], few1[2], few2[2],
                                  few1[0], wmh);
  wmfma32_k<<<126, 256, 0, stream>>>(T32, wm32);
  wsplit_k<<<dim3(84, 4), 256, 0, stream>>>(TS, wsp);

  // ---- feature pyramids (all f16 HWC) ----
  fe0_fused_k<<<dim3(32, 32, 8), 256, 0, stream>>>(
      ref, unr, wmh + 5 * 2560, feb1[0], wmh, feb2[0], fH0);
  fe12_fused_k<<<dim3(16, 16, 8), 256, 0, stream>>>(
      fH0, wmh + 2560, feb1[1], wmh + 2 * 2560, feb2[1], fH1, 256);
  fe12_fused_k<<<dim3(8, 8, 8), 256, 0, stream>>>(
      fH1, wmh + 3 * 2560, feb1[2], wmh + 4 * 2560, feb2[2], fH2, 128);

  const unsigned short* uH0 = fH0 + (size_t)4 * 65536 * 16;
  const unsigned short* uH1 = fH1 + (size_t)4 * 16384 * 16;
  const unsigned short* uH2 = fH2 + (size_t)4 * 4096 * 16;

  // ---- coarse-to-fine ----
  obog_k<0><<<dim3(4, 8, 4), 256, 0, stream>>>(
      fH2, uH2, nullptr, wm32 + o32(2), obb[2], wsp + o_og[2], ogb[2], offs2, 64);
  defc_k<0><<<dim3(4, 8, 4), 256, 0, stream>>>(
      uH2, offs2, wdc2 + 2 * 1152, nullptr, wm32 + o32(6), fcb[2], ftH2, 64);
  obog_k<1><<<dim3(8, 16, 4), 256, 0, stream>>>(
      fH1, uH1, offs2, wm32 + o32(1), obb[1], wsp + o_og[1], ogb[1], offs1, 128);
  defc_k<1><<<dim3(8, 16, 4), 256, 0, stream>>>(
      uH1, offs1, wdc2 + 1 * 1152, ftH2, wm32 + o32(5), fcb[1], ftH1, 128);
  obog_k<1><<<dim3(16, 32, 4), 256, 0, stream>>>(
      fH0, uH0, offs1, wm32 + o32(0), obb[0], wsp + o_og[0], ogb[0], offs0, 256);
  defc_k<1><<<dim3(16, 32, 4), 256, 0, stream>>>(
      uH0, offs0, wdc2, ftH1, wm32 + o32(4), fcb[0], fHwc, 256);

  // ---- fused final head ----
  final_k<<<dim3(16, 16, 4), 256, 0, stream>>>(
      fH0, fHwc, offs0, wm32 + o32(3), dobb, wsp + o_dog, dogb, wdc2 + 3456,
      (float*)d_out);
}

// Round 15
// 497.026 us; speedup vs baseline: 1.0980x; 1.0238x over previous
//
#include <hip/hip_runtime.h>
#include <math.h>

typedef _Float16 half2_t __attribute__((ext_vector_type(2)));
typedef _Float16 half8 __attribute__((ext_vector_type(8)));
typedef float floatx4 __attribute__((ext_vector_type(4)));

__device__ __forceinline__ unsigned packh2(float a, float b) {
  half2_t h;
  h.x = (_Float16)a;
  h.y = (_Float16)b;
  return __builtin_bit_cast(unsigned, h);
}
__device__ __forceinline__ unsigned short f2h(float a) {
  return __builtin_bit_cast(unsigned short, (_Float16)a);
}
__device__ __forceinline__ float h2f(unsigned short u) {
  return (float)__builtin_bit_cast(_Float16, u);
}
__device__ __forceinline__ float dot2acc(unsigned a, unsigned b, float c) {
  half2_t ha = __builtin_bit_cast(half2_t, a);
  half2_t hb = __builtin_bit_cast(half2_t, b);
#if __has_builtin(__builtin_amdgcn_fdot2)
  return __builtin_amdgcn_fdot2(ha, hb, c, false);
#else
  c = fmaf((float)ha.x, (float)hb.x, c);
  return fmaf((float)ha.y, (float)hb.y, c);
#endif
}
__device__ __forceinline__ half8 splat8(_Float16 x) {
  half8 r;
#pragma unroll
  for (int j = 0; j < 8; ++j) r[j] = x;
  return r;
}

// ---------------- dc/ddc weight pair pack ----------------
__global__ __launch_bounds__(256) void wdcpair_k(
    const float* __restrict__ a, const float* __restrict__ b,
    const float* __restrict__ c, const float* __restrict__ d,
    unsigned* __restrict__ out) {
  int t = blockIdx.x * 256 + threadIdx.x;
  if (t < 3456) {
    int conv = t / 1152, r = t % 1152;
    int k = r / 128, cp = (r / 16) % 8, o = r & 15;
    const float* w = conv == 0 ? a : (conv == 1 ? b : c);
    out[t] = packh2(w[(o * 16 + 2 * cp) * 9 + k], w[(o * 16 + 2 * cp + 1) * 9 + k]);
  } else if (t < 3600) {
    int r = t - 3456;
    int o = r & 1, jp = (r >> 1) & 3, g = (r >> 3) & 1, k = r >> 4;
    out[t] = packh2(d[(o * 16 + g * 8 + 2 * jp) * 9 + k],
                    d[(o * 16 + g * 8 + 2 * jp + 1) * 9 + k]);
  }
}

// ---------------- MFMA prepack, 16-cin convs ----------------
__global__ __launch_bounds__(256) void wmfma_k(
    const float* __restrict__ w0, const float* __restrict__ w1,
    const float* __restrict__ w2, const float* __restrict__ w3,
    const float* __restrict__ w4, const float* __restrict__ w5,
    unsigned short* __restrict__ out) {
  int t = blockIdx.x * 256 + threadIdx.x;
  if (t >= 15360) return;
  int conv = t / 2560, r = t % 2560;
  int c = r / 512, L = (r / 8) % 64, j = r & 7;
  int quad = L >> 4, o = L & 15;
  int k = 32 * c + quad * 8 + j;
  int tap = k >> 4, cin = k & 15;
  float v;
  if (conv == 5) {
    v = (tap < 9 && cin == 0) ? w5[o * 9 + tap] : 0.f;
  } else {
    const float* w = conv == 0 ? w0 : conv == 1 ? w1 : conv == 2 ? w2 : conv == 3 ? w3 : w4;
    v = (tap < 9) ? w[((size_t)o * 16 + cin) * 9 + tap] : 0.f;
  }
  out[t] = f2h(v);
}

// ---------------- MFMA prepack, 32-cin convs ----------------
struct W32Entry { const float* src; int cin; };
struct W32Table { W32Entry e[8]; };
__global__ __launch_bounds__(256) void wmfma32_k(W32Table t, unsigned short* __restrict__ out) {
  int i = blockIdx.x * 256 + threadIdx.x;
  if (i >= 7 * 4608) return;
  int conv = i / 4608, r = i % 4608;
  int tap = r / 512, L = (r / 8) % 64, j = r & 7;
  int quad = L >> 4, o = L & 15;
  int c = quad * 8 + j;
  W32Entry en = t.e[conv];
  float v = (c < en.cin) ? en.src[((size_t)o * en.cin + c) * 9 + tap] : 0.f;
  out[i] = f2h(v);
}

// ---------------- split-cin MFMA prepack for og/dog ----------------
struct SPEntry { const float* src; int cin; int cout; int ct; int dstoff; };
struct SPTable { SPEntry e[4]; };
__global__ __launch_bounds__(256) void wsplit_k(SPTable t, unsigned short* __restrict__ out) {
  SPEntry en = t.e[blockIdx.y];
  int aSize = en.ct * 2560;
  int bSize = (en.cin > 16) ? en.ct * 4608 : 0;
  int i = blockIdx.x * 256 + threadIdx.x;
  if (i >= aSize + bSize) return;
  float v;
  if (i < aSize) {
    int ct = i / 2560, r = i % 2560;
    int c = r / 512, L = (r / 8) % 64, j = r & 7;
    int quad = L >> 4, o16 = L & 15;
    int k = 32 * c + quad * 8 + j;
    int tap = k >> 4, cin = k & 15;
    int o = ct * 16 + o16;
    v = (tap < 9 && o < en.cout) ? en.src[((size_t)o * en.cin + cin) * 9 + tap] : 0.f;
  } else {
    int r2 = i - aSize;
    int ct = r2 / 4608, r = r2 % 4608;
    int tap = r / 512, L = (r / 8) % 64, j = r & 7;
    int quad = L >> 4, o16 = L & 15;
    int cin = quad * 8 + j;
    int o = ct * 16 + o16;
    v = (cin < en.cin - 16 && o < en.cout)
            ? en.src[((size_t)o * en.cin + 16 + cin) * 9 + tap] : 0.f;
  }
  out[en.dstoff + i] = f2h(v);
}

// ---------------- MFMA 16-cin 3x3 conv over LDS HWC-16 tile (compile-time geometry) ----------------
template <int SW, int DPS, int POS, int OW, int RELU, int DOMASK>
__device__ __forceinline__ void conv_mfma(
    const unsigned short* __restrict__ src,
    unsigned short* __restrict__ dst, const half8* __restrict__ bf,
    const float* __restrict__ bias, int tid, int gby, int gbx, int bound) {
  const int lane = tid & 63, wid = tid >> 6;
  const int quad = lane >> 4, m = lane & 15;
  const int tap01 = quad >> 1, cin8 = (quad & 1) * 8;
  constexpr int ntiles = (POS + 15) >> 4;
  float bs = bias[m];
  half8 zero;
#pragma unroll
  for (int j = 0; j < 8; ++j) zero[j] = (_Float16)0;
  for (int T = wid; T < ntiles; T += 4) {
    int pa = T * 16 + m;
    pa = pa < POS ? pa : POS - 1;
    int ya = pa / OW, xa = pa - ya * OW;
    floatx4 acc = {0.f, 0.f, 0.f, 0.f};
#pragma unroll
    for (int c = 0; c < 5; ++c) {
      int tap = 2 * c + tap01;
      half8 a = zero;
      if (tap < 9) {
        int dy = tap / 3, dx = tap - (tap / 3) * 3;
        a = *(const half8*)(src + ((ya + dy) * SW + xa + dx) * 16 + cin8);
      }
      acc = __builtin_amdgcn_mfma_f32_16x16x32_f16(a, bf[c], acc, 0, 0, 0);
    }
#pragma unroll
    for (int r = 0; r < 4; ++r) {
      int pd = T * 16 + quad * 4 + r;
      if (pd < POS) {
        float v = acc[r] + bs;
        if (RELU) v = fmaxf(v, 0.f);
        if (DOMASK) {
          int yd = pd / OW, xd = pd - (pd / OW) * OW;
          int gy = gby + yd, gx = gbx + xd;
          if (gy < 0 || gy >= bound || gx < 0 || gx >= bound) v = 0.f;
        }
        dst[pd * DPS + m] = f2h(v);
      }
    }
  }
}

// ---------------- MFMA 32-cin 3x3 conv over LDS HWC-32 tile (compile-time geometry) ----------------
template <int SW, int DPS, int POS, int OW, int RELU, int DOMASK>
__device__ __forceinline__ void conv_mfma32(
    const unsigned short* __restrict__ src,
    unsigned short* __restrict__ dst, const half8* __restrict__ bf,
    const float* __restrict__ bias, int tid, int gby, int gbx, int bound) {
  const int lane = tid & 63, wid = tid >> 6;
  const int quad = lane >> 4, m = lane & 15;
  constexpr int ntiles = (POS + 15) >> 4;
  float bs = bias[m];
  for (int T = wid; T < ntiles; T += 4) {
    int pa = T * 16 + m;
    pa = pa < POS ? pa : POS - 1;
    int ya = pa / OW, xa = pa - ya * OW;
    floatx4 acc = {0.f, 0.f, 0.f, 0.f};
#pragma unroll
    for (int tap = 0; tap < 9; ++tap) {
      int dy = tap / 3, dx = tap - (tap / 3) * 3;
      half8 a = *(const half8*)(src + ((ya + dy) * SW + xa + dx) * 32 + quad * 8);
      acc = __builtin_amdgcn_mfma_f32_16x16x32_f16(a, bf[tap], acc, 0, 0, 0);
    }
#pragma unroll
    for (int r = 0; r < 4; ++r) {
      int pd = T * 16 + quad * 4 + r;
      if (pd < POS) {
        float v = acc[r] + bs;
        if (RELU) v = fmaxf(v, 0.f);
        if (DOMASK) {
          int yd = pd / OW, xd = pd - (pd / OW) * OW;
          int gy = gby + yd, gx = gbx + xd;
          if (gy < 0 || gy >= bound || gx < 0 || gx >= bound) v = 0.f;
        }
        dst[pd * DPS + m] = f2h(v);
      }
    }
  }
}

// ---------------- split-cin MFMA 3x3 conv ----------------
template <int CT, int HASB, int NT>
__device__ __forceinline__ void conv_split_mfma(
    const unsigned short* __restrict__ srcB, const unsigned short* __restrict__ srcO,
    const unsigned short* __restrict__ wbase, float* __restrict__ outLds, int OSTRIDE,
    const float* __restrict__ bias, int NOUT, int relu, int tid) {
  const int lane = tid & 63, wid = tid >> 6;
  const int quad = lane >> 4, m = lane & 15;
  const int tap01 = quad >> 1, cin8 = (quad & 1) * 8;
  half8 zero;
#pragma unroll
  for (int j = 0; j < 8; ++j) zero[j] = (_Float16)0;
  floatx4 acc[CT][NT];
#pragma unroll
  for (int ct = 0; ct < CT; ++ct)
#pragma unroll
    for (int t = 0; t < NT; ++t) acc[ct][t] = floatx4{0.f, 0.f, 0.f, 0.f};
#pragma unroll
  for (int ct = 0; ct < CT; ++ct) {
    half8 bfA[5];
#pragma unroll
    for (int c = 0; c < 5; ++c)
      bfA[c] = *(const half8*)(wbase + ((ct * 5 + c) * 64 + lane) * 8);
#pragma unroll
    for (int t = 0; t < NT; ++t) {
      int pa = (wid + 4 * t) * 16 + m;
      int ya = pa >> 4, xa = pa & 15;
#pragma unroll
      for (int c = 0; c < 5; ++c) {
        int tap = 2 * c + tap01;
        half8 a = zero;
        if (tap < 9) {
          int dy = tap / 3, dx = tap - (tap / 3) * 3;
          a = *(const half8*)(srcB + ((ya + dy) * 18 + xa + dx) * 18 + cin8);
        }
        acc[ct][t] = __builtin_amdgcn_mfma_f32_16x16x32_f16(a, bfA[c], acc[ct][t], 0, 0, 0);
      }
    }
  }
  if (HASB) {
    const unsigned short* wb = wbase + CT * 2560;
#pragma unroll
    for (int ct = 0; ct < CT; ++ct) {
      half8 bfB[9];
#pragma unroll
      for (int c = 0; c < 9; ++c)
        bfB[c] = *(const half8*)(wb + ((ct * 9 + c) * 64 + lane) * 8);
#pragma unroll
      for (int t = 0; t < NT; ++t) {
        int pa = (wid + 4 * t) * 16 + m;
        int ya = pa >> 4, xa = pa & 15;
#pragma unroll
        for (int tap = 0; tap < 9; ++tap) {
          int dy = tap / 3, dx = tap - (tap / 3) * 3;
          half8 a = *(const half8*)(srcO + ((ya + dy) * 18 + xa + dx) * 34 + quad * 8);
          acc[ct][t] = __builtin_amdgcn_mfma_f32_16x16x32_f16(a, bfB[tap], acc[ct][t], 0, 0, 0);
        }
      }
    }
  }
  __syncthreads();
#pragma unroll
  for (int ct = 0; ct < CT; ++ct) {
    int o = ct * 16 + m;
#pragma unroll
    for (int t = 0; t < NT; ++t) {
#pragma unroll
      for (int r = 0; r < 4; ++r) {
        int pd = (wid + 4 * t) * 16 + quad * 4 + r;
        if (o < NOUT) {
          float v = acc[ct][t][r] + bias[o];
          if (relu) v = fmaxf(v, 0.f);
          outLds[pd * OSTRIDE + o] = v;
        }
      }
    }
  }
}

// ---------------- fused FE level-0 -> f16 HWC only ----------------
__global__ __launch_bounds__(256) void fe0_fused_k(
    const float* __restrict__ refI, const float* __restrict__ unrI,
    const unsigned short* __restrict__ wm1, const float* __restrict__ b1,
    const unsigned short* __restrict__ wm2, const float* __restrict__ b2,
    unsigned short* __restrict__ outH) {
  __shared__ __attribute__((aligned(16))) unsigned short bufA[441 * 16];
  __shared__ __attribute__((aligned(16))) unsigned short c1h[361 * 16];
  const int z = blockIdx.z;
  const int im = z >> 2, n = z & 3;
  const float* img = (im ? unrI : refI) + (size_t)n * 512 * 512;
  unsigned short* outh = outH + (size_t)z * 65536 * 16;
  const int py0 = blockIdx.y * 8, px0 = blockIdx.x * 8;
  const int tid = threadIdx.x;

  half8 bf1[5], bf2[5];
  {
    const int lane = tid & 63;
#pragma unroll
    for (int c = 0; c < 5; ++c) {
      bf1[c] = *(const half8*)(wm1 + (c * 64 + lane) * 8);
      bf2[c] = *(const half8*)(wm2 + (c * 64 + lane) * 8);
    }
  }

  {
    unsigned* s32 = (unsigned*)bufA;
    for (int i = tid; i < 441; i += 256) {
      int yi = i / 21, xi = i - yi * 21;
      int gy = 2 * py0 - 3 + yi, gx = 2 * px0 - 3 + xi;
      float v = 0.f;
      if (gy >= 0 && gy < 512 && gx >= 0 && gx < 512) v = img[gy * 512 + gx];
      uint4 q0 = {packh2(v, 0.f), 0u, 0u, 0u};
      uint4 q1 = {0u, 0u, 0u, 0u};
      *(uint4*)(s32 + i * 8) = q0;
      *(uint4*)(s32 + i * 8 + 4) = q1;
    }
  }
  __syncthreads();

  conv_mfma<21, 16, 361, 19, 1, 1>(bufA, c1h, bf1, b1, tid, 2 * py0 - 2, 2 * px0 - 2, 512);
  __syncthreads();
  conv_mfma<19, 18, 289, 17, 1, 0>(c1h, bufA, bf2, b2, tid, 0, 0, 0);
  __syncthreads();

  // maxpool: channel-pair packed (v_pk_max_f16), direct coalesced HWC writes
  for (int i = tid; i < 512; i += 256) {
    int cp = i & 7, r = i >> 3;
    int py = r >> 3, px = r & 7;
    half2_t m;
    m.x = (_Float16)0;
    m.y = (_Float16)0;
#pragma unroll
    for (int dy = 0; dy < 3; ++dy) {
      int gy = 2 * (py0 + py) - 1 + dy;
      if (gy < 0 || gy >= 512) continue;
#pragma unroll
      for (int dx = 0; dx < 3; ++dx) {
        int gx = 2 * (px0 + px) - 1 + dx;
        if (gx < 0 || gx >= 512) continue;
        half2_t v = __builtin_bit_cast(
            half2_t, *(const unsigned*)(bufA + ((2 * py + dy) * 17 + 2 * px + dx) * 18 + 2 * cp));
        m = __builtin_elementwise_max(m, v);
      }
    }
    *(unsigned*)(outh + (((size_t)(py0 + py)) * 256 + px0 + px) * 16 + 2 * cp) =
        __builtin_bit_cast(unsigned, m);
  }
}

// ---------------- fused FE level-1/2: f16 HWC in, f16 HWC out ----------------
__global__ __launch_bounds__(256) void fe12_fused_k(
    const unsigned short* __restrict__ inH,
    const unsigned short* __restrict__ wm1, const float* __restrict__ b1,
    const unsigned short* __restrict__ wm2, const float* __restrict__ b2,
    unsigned short* __restrict__ outH, int Hin) {
  __shared__ __attribute__((aligned(16))) unsigned short inh[441 * 16];
  __shared__ __attribute__((aligned(16))) unsigned short c1h[361 * 16];
  const int n = blockIdx.z;
  const int Ho = Hin >> 1;
  const int py0 = blockIdx.y * 8, px0 = blockIdx.x * 8;
  const int tid = threadIdx.x;
  const unsigned short* inN = inH + (size_t)n * Hin * Hin * 16;

  half8 bf1[5], bf2[5];
  {
    const int lane = tid & 63;
#pragma unroll
    for (int c = 0; c < 5; ++c) {
      bf1[c] = *(const half8*)(wm1 + (c * 64 + lane) * 8);
      bf2[c] = *(const half8*)(wm2 + (c * 64 + lane) * 8);
    }
  }

  unsigned* inh32 = (unsigned*)inh;
  for (int i = tid; i < 8 * 441; i += 256) {
    int cp = i / 441, r = i - cp * 441;
    int yi = r / 21, xi = r - yi * 21;
    int gy = 2 * py0 - 3 + yi, gx = 2 * px0 - 3 + xi;
    unsigned val = 0u;
    if (gy >= 0 && gy < Hin && gx >= 0 && gx < Hin)
      val = *(const unsigned*)(inN + ((size_t)gy * Hin + gx) * 16 + 2 * cp);
    inh32[r * 8 + cp] = val;
  }
  __syncthreads();

  conv_mfma<21, 16, 361, 19, 1, 1>(inh, c1h, bf1, b1, tid, 2 * py0 - 2, 2 * px0 - 2, Hin);
  __syncthreads();
  conv_mfma<19, 18, 289, 17, 1, 0>(c1h, inh, bf2, b2, tid, 0, 0, 0);
  __syncthreads();

  unsigned short* outp = outH + (size_t)n * Ho * Ho * 16;
  for (int i = tid; i < 512; i += 256) {
    int cp = i & 7, r = i >> 3;
    int py = r >> 3, px = r & 7;
    half2_t m;
    m.x = (_Float16)0;
    m.y = (_Float16)0;
#pragma unroll
    for (int dy = 0; dy < 3; ++dy) {
      int gy = 2 * (py0 + py) - 1 + dy;
      if (gy < 0 || gy >= Hin) continue;
#pragma unroll
      for (int dx = 0; dx < 3; ++dx) {
        int gx = 2 * (px0 + px) - 1 + dx;
        if (gx < 0 || gx >= Hin) continue;
        half2_t v = __builtin_bit_cast(
            half2_t, *(const unsigned*)(inh + ((2 * py + dy) * 17 + 2 * px + dx) * 18 + 2 * cp));
        m = __builtin_elementwise_max(m, v);
      }
    }
    *(unsigned*)(outp + (((size_t)(py0 + py)) * Ho + px0 + px) * 16 + 2 * cp) =
        __builtin_bit_cast(unsigned, m);
  }
}

// ---------------- fused offset head (16x8 tiles): ob(MFMA) -> og(split MFMA) -> offs(f16 HWC) ----
template <int HAS_UP>
__global__ __launch_bounds__(256) void obog_k(
    const unsigned short* __restrict__ rfh, const unsigned short* __restrict__ ufh,
    const unsigned short* __restrict__ offsUp,
    const unsigned short* __restrict__ wmob, const float* __restrict__ bob,
    const unsigned short* __restrict__ wog, const float* __restrict__ bog,
    unsigned short* __restrict__ offsOut, int H) {
  __shared__ __attribute__((aligned(16))) unsigned POOL[5460];
  const int n = blockIdx.z;
  const int bx = blockIdx.x * 16, by = blockIdx.y * 8;
  const int tid = threadIdx.x;
  const size_t HH = (size_t)H * H;
  const unsigned short* r0h = rfh + (size_t)n * HH * 16;
  const unsigned short* u0h = ufh + (size_t)n * HH * 16;

  for (int i = tid; i < 3840; i += 256) {
    int cp = i / 240, r = i - cp * 240;
    int ly = r / 20, lx = r - ly * 20;
    int gy = by + ly - 2, gx = bx + lx - 2;
    unsigned val = 0u;
    if (gy >= 0 && gy < H && gx >= 0 && gx < H) {
      const unsigned short* s16 = (cp < 8) ? r0h : u0h;
      int ch = (cp < 8) ? 2 * cp : 2 * cp - 16;
      val = *(const unsigned*)(s16 + ((size_t)gy * H + gx) * 16 + ch);
    }
    POOL[r * 16 + cp] = val;
  }
  __syncthreads();

  {
    half8 bf[9];
    const int lane = tid & 63;
#pragma unroll
    for (int c = 0; c < 9; ++c) bf[c] = *(const half8*)(wmob + (c * 64 + lane) * 8);
    conv_mfma32<20, 18, 180, 18, 1, 1>((const unsigned short*)POOL,
                                       (unsigned short*)(POOL + 3840), bf, bob,
                                       tid, by - 1, bx - 1, H);
  }
  __syncthreads();

  if (HAS_UP) {  // stage up2(offsUp f16 HWC) as pair-plane HWC-17 u32
    const int H2 = H >> 1;
    const unsigned short* os = offsUp + (size_t)n * H2 * H2 * 18;
    for (int i = tid; i < 16 * 180; i += 256) {
      int cp = i / 180, r = i - cp * 180;
      unsigned val = 0u;
      if (cp < 9) {
        int y1 = r / 18, x1 = r - y1 * 18;
        int gy = by + y1 - 1, gx = bx + x1 - 1;
        if (gy >= 0 && gy < H && gx >= 0 && gx < H) {
          float sy = 0.5f * gy - 0.25f, sx = 0.5f * gx - 0.25f;
          float y0f = floorf(sy), x0f = floorf(sx);
          float wy = sy - y0f, wx = sx - x0f;
          int y0 = (int)y0f, x0 = (int)x0f;
          int y0c = min(max(y0, 0), H2 - 1), y1c = min(max(y0 + 1, 0), H2 - 1);
          int x0c = min(max(x0, 0), H2 - 1), x1c = min(max(x0 + 1, 0), H2 - 1);
          half2_t h00 = __builtin_bit_cast(half2_t, *(const unsigned*)(os + ((size_t)y0c * H2 + x0c) * 18 + 2 * cp));
          half2_t h01 = __builtin_bit_cast(half2_t, *(const unsigned*)(os + ((size_t)y0c * H2 + x1c) * 18 + 2 * cp));
          half2_t h10 = __builtin_bit_cast(half2_t, *(const unsigned*)(os + ((size_t)y1c * H2 + x0c) * 18 + 2 * cp));
          half2_t h11 = __builtin_bit_cast(half2_t, *(const unsigned*)(os + ((size_t)y1c * H2 + x1c) * 18 + 2 * cp));
          float v0 = (1.f - wy) * ((1.f - wx) * (float)h00.x + wx * (float)h01.x) +
                     wy * ((1.f - wx) * (float)h10.x + wx * (float)h11.x);
          float v1 = (1.f - wy) * ((1.f - wx) * (float)h00.y + wx * (float)h01.y) +
                     wy * ((1.f - wx) * (float)h10.y + wx * (float)h11.y);
          val = packh2(v0, v1);
        }
      }
      POOL[r * 17 + cp] = val;
    }
    __syncthreads();
  }

  conv_split_mfma<2, HAS_UP, 2>((const unsigned short*)(POOL + 3840),
                                (const unsigned short*)POOL, wog,
                                (float*)POOL, 19, bog, 18, 1, tid);
  __syncthreads();

  {  // HWC epilogue: 9 contiguous u16 stores per thread
    int pix = tid & 127, half = tid >> 7;
    const float* of = (const float*)POOL + (size_t)pix * 19 + half * 9;
    int ty = pix >> 4, tx = pix & 15;
    unsigned short* op = offsOut + ((size_t)n * HH + (size_t)(by + ty) * H + (bx + tx)) * 18 +
                         half * 9;
#pragma unroll
    for (int o = 0; o < 9; ++o) op[o] = f2h(of[o]);
  }
}

// ---------------- fused feature head: deform(f16 pk blend + dot2) -> fc(MFMA) -> f16 HWC ----------------
template <int HAS_UP>
__global__ __launch_bounds__(256) void defc_k(
    const unsigned short* __restrict__ ufHWC, const unsigned short* __restrict__ offs,
    const unsigned* __restrict__ wdc2, const unsigned short* __restrict__ featsUpH,
    const unsigned short* __restrict__ wmfc, const float* __restrict__ bfc,
    unsigned short* __restrict__ outHwc, int H) {
  __shared__ __attribute__((aligned(16))) unsigned ldsC[180 * 17];
  const int n = blockIdx.z;
  const int bx = blockIdx.x * 16, by = blockIdx.y * 8;
  const int tid = threadIdx.x;
  const size_t HH = (size_t)H * H;
  const unsigned short* inN = ufHWC + (size_t)n * HH * 16;
  const unsigned short* offN = offs + (size_t)n * HH * 18;

  half8 bf[9];
  {
    const int lane = tid & 63;
#pragma unroll
    for (int c = 0; c < 9; ++c) bf[c] = *(const half8*)(wmfc + (c * 64 + lane) * 8);
  }

  for (int p = tid; p < 180; p += 256) {
    int y1 = p / 18, x1 = p - y1 * 18;
    int h = by + y1 - 1, w = bx + x1 - 1;
    bool valid = (h >= 0 && h < H && w >= 0 && w < H);
    float acc[16];
#pragma unroll
    for (int o = 0; o < 16; ++o) acc[o] = 0.f;
    if (valid) {
      const unsigned short* offP = offN + ((size_t)h * H + w) * 18;
#pragma unroll
      for (int k = 0; k < 9; ++k) {
        int ky = k / 3 - 1, kx = k % 3 - 1;
        half2_t o2 = __builtin_bit_cast(half2_t, *(const unsigned*)(offP + 2 * k));
        float oy = (float)o2.x;
        float ox = (float)o2.y;
        float py = (float)(h + ky) + oy;
        float px = (float)(w + kx) + ox;
        float y0f = floorf(py), x0f = floorf(px);
        float fy = py - y0f, fx = px - x0f;
        int y0 = (int)y0f, x0 = (int)x0f;
        bool vy0 = ((unsigned)y0 < (unsigned)H);
        bool vy1 = ((unsigned)(y0 + 1) < (unsigned)H);
        bool vx0 = ((unsigned)x0 < (unsigned)H);
        bool vx1 = ((unsigned)(x0 + 1) < (unsigned)H);
        int y0c = min(max(y0, 0), H - 1), y1c = min(max(y0 + 1, 0), H - 1);
        int x0c = min(max(x0, 0), H - 1), x1c = min(max(x0 + 1, 0), H - 1);
        float w00 = (vy0 && vx0) ? (1.f - fy) * (1.f - fx) : 0.f;
        float w01 = (vy0 && vx1) ? (1.f - fy) * fx : 0.f;
        float w10 = (vy1 && vx0) ? fy * (1.f - fx) : 0.f;
        float w11 = (vy1 && vx1) ? fy * fx : 0.f;
        half8 s00 = splat8((_Float16)w00);
        half8 s01 = splat8((_Float16)w01);
        half8 s10 = splat8((_Float16)w10);
        half8 s11 = splat8((_Float16)w11);
        const unsigned short* p00 = inN + ((size_t)y0c * H + x0c) * 16;
        const unsigned short* p01 = inN + ((size_t)y0c * H + x1c) * 16;
        const unsigned short* p10 = inN + ((size_t)y1c * H + x0c) * 16;
        const unsigned short* p11 = inN + ((size_t)y1c * H + x1c) * 16;
        const unsigned* wk2 = wdc2 + k * 128;
#pragma unroll
        for (int c8 = 0; c8 < 2; ++c8) {
          half8 a00 = *(const half8*)(p00 + c8 * 8);
          half8 a01 = *(const half8*)(p01 + c8 * 8);
          half8 a10 = *(const half8*)(p10 + c8 * 8);
          half8 a11 = *(const half8*)(p11 + c8 * 8);
          half8 vb = a00 * s00 + a01 * s01 + a10 * s10 + a11 * s11;
          uint4 vp = __builtin_bit_cast(uint4, vb);
          unsigned vpa[4] = {vp.x, vp.y, vp.z, vp.w};
#pragma unroll
          for (int jp = 0; jp < 4; ++jp) {
            const unsigned* wrow = wk2 + (c8 * 4 + jp) * 16;
#pragma unroll
            for (int o = 0; o < 16; ++o)
              acc[o] = dot2acc(vpa[jp], wrow[o], acc[o]);
          }
        }
      }
    }
#pragma unroll
    for (int cc = 0; cc < 8; ++cc) {
      float a0 = valid ? fmaxf(acc[2 * cc], 0.f) : 0.f;
      float a1 = valid ? fmaxf(acc[2 * cc + 1], 0.f) : 0.f;
      ldsC[p * 17 + cc] = packh2(a0, a1);
      if (!HAS_UP) ldsC[p * 17 + 8 + cc] = 0u;
    }
  }

  if (HAS_UP) {
    const int H2 = H >> 1;
    const unsigned short* fu = featsUpH + (size_t)n * H2 * H2 * 16;
    for (int i = tid; i < 8 * 180; i += 256) {
      int cp = i / 180, r = i - cp * 180;
      int y1 = r / 18, x1 = r - y1 * 18;
      int gy = by + y1 - 1, gx = bx + x1 - 1;
      unsigned val = 0u;
      if (gy >= 0 && gy < H && gx >= 0 && gx < H) {
        float sy = 0.5f * gy - 0.25f, sx = 0.5f * gx - 0.25f;
        float y0f = floorf(sy), x0f = floorf(sx);
        float wy = sy - y0f, wx = sx - x0f;
        int y0 = (int)y0f, x0 = (int)x0f;
        int y0c = min(max(y0, 0), H2 - 1), y1c = min(max(y0 + 1, 0), H2 - 1);
        int x0c = min(max(x0, 0), H2 - 1), x1c = min(max(x0 + 1, 0), H2 - 1);
        half2_t h00 = __builtin_bit_cast(half2_t, *(const unsigned*)(fu + ((size_t)y0c * H2 + x0c) * 16 + 2 * cp));
        half2_t h01 = __builtin_bit_cast(half2_t, *(const unsigned*)(fu + ((size_t)y0c * H2 + x1c) * 16 + 2 * cp));
        half2_t h10 = __builtin_bit_cast(half2_t, *(const unsigned*)(fu + ((size_t)y1c * H2 + x0c) * 16 + 2 * cp));
        half2_t h11 = __builtin_bit_cast(half2_t, *(const unsigned*)(fu + ((size_t)y1c * H2 + x1c) * 16 + 2 * cp));
        float v0 = (1.f - wy) * ((1.f - wx) * (float)h00.x + wx * (float)h01.x) +
                   wy * ((1.f - wx) * (float)h10.x + wx * (float)h11.x);
        float v1 = (1.f - wy) * ((1.f - wx) * (float)h00.y + wx * (float)h01.y) +
                   wy * ((1.f - wx) * (float)h10.y + wx * (float)h11.y);
        val = packh2(v0, v1);
      }
      ldsC[r * 17 + 8 + cp] = val;
    }
  }
  __syncthreads();

  {
    const int lane = tid & 63, wid = tid >> 6;
    const int quad = lane >> 4, m = lane & 15;
    const unsigned short* src = (const unsigned short*)ldsC;
    float bs = bfc[m];
    for (int T = wid; T < 8; T += 4) {
      int pa = T * 16 + m;
      int ya = pa >> 4, xa = pa & 15;
      floatx4 acc = {0.f, 0.f, 0.f, 0.f};
#pragma unroll
      for (int tap = 0; tap < 9; ++tap) {
        int dy = tap / 3, dx = tap - (tap / 3) * 3;
        half8 a = *(const half8*)(src + ((ya + dy) * 18 + xa + dx) * 34 + quad * 8);
        acc = __builtin_amdgcn_mfma_f32_16x16x32_f16(a, bf[tap], acc, 0, 0, 0);
      }
#pragma unroll
      for (int r = 0; r < 4; ++r) {
        int pd = T * 16 + quad * 4 + r;
        int yd = pd >> 4, xd = pd & 15;
        float v = fmaxf(acc[r] + bs, 0.f);
        outHwc[((size_t)n * HH + (size_t)(by + yd) * H + bx + xd) * 16 + m] = f2h(v);
      }
    }
  }
}

// ---------------- fused final head (16x16): dob -> dog(split MFMA) -> deform dg=2 (pk+dot2) ----
__global__ __launch_bounds__(256) void final_k(
    const unsigned short* __restrict__ rfh, const unsigned short* __restrict__ f0hwc,
    const unsigned short* __restrict__ offs0,
    const unsigned short* __restrict__ wmdob, const float* __restrict__ bdob,
    const unsigned short* __restrict__ wdog, const float* __restrict__ bdog,
    const unsigned* __restrict__ wddc2, float* __restrict__ out) {
  __shared__ __attribute__((aligned(16))) unsigned POOL[9472];
  const int H = 256;
  const size_t HH = 65536;
  const int n = blockIdx.z;
  const int bx = blockIdx.x * 16, by = blockIdx.y * 16;
  const int tid = threadIdx.x;
  const unsigned short* r0h = rfh + (size_t)n * HH * 16;
  const unsigned short* f0h = f0hwc + (size_t)n * HH * 16;

  for (int i = tid; i < 6400; i += 256) {
    int cp = i / 400, r = i - cp * 400;
    int ly = r / 20, lx = r - ly * 20;
    int gy = by + ly - 2, gx = bx + lx - 2;
    unsigned val = 0u;
    if (gy >= 0 && gy < H && gx >= 0 && gx < H) {
      const unsigned short* base = (cp < 8) ? r0h : f0h;
      int ch = (cp < 8) ? 2 * cp : 2 * cp - 16;
      val = *(const unsigned*)(base + ((size_t)gy * H + gx) * 16 + ch);
    }
    POOL[r * 16 + cp] = val;
  }
  __syncthreads();

  {
    half8 bf[9];
    const int lane = tid & 63;
#pragma unroll
    for (int c = 0; c < 9; ++c) bf[c] = *(const half8*)(wmdob + (c * 64 + lane) * 8);
    conv_mfma32<20, 18, 324, 18, 0, 1>((const unsigned short*)POOL,
                                       (unsigned short*)(POOL + 6400), bf, bdob,
                                       tid, by - 1, bx - 1, H);
  }
  __syncthreads();

  {  // stage offs0 (f16 HWC) as pair-plane HWC-17 u32
    const unsigned short* os = offs0 + (size_t)n * HH * 18;
    for (int i = tid; i < 16 * 324; i += 256) {
      int cp = i / 324, r = i - cp * 324;
      unsigned val = 0u;
      if (cp < 9) {
        int y1 = r / 18, x1 = r - y1 * 18;
        int gy = by + y1 - 1, gx = bx + x1 - 1;
        if (gy >= 0 && gy < H && gx >= 0 && gx < H)
          val = *(const unsigned*)(os + ((size_t)gy * H + gx) * 18 + 2 * cp);
      }
      POOL[r * 17 + cp] = val;
    }
    __syncthreads();
  }

  conv_split_mfma<3, 1, 4>((const unsigned short*)(POOL + 6400),
                           (const unsigned short*)POOL, wdog,
                           (float*)POOL, 37, bdog, 36, 0, tid);
  __syncthreads();

  {
    const int ty = tid >> 4, tx = tid & 15;
    const int h = by + ty, w = bx + tx;
    const float* a36 = (const float*)POOL + (size_t)tid * 37;
    float rr[2] = {0.f, 0.f};
#pragma unroll
    for (int g = 0; g < 2; ++g) {
#pragma unroll
      for (int k = 0; k < 9; ++k) {
        int ky = k / 3 - 1, kx = k % 3 - 1;
        float oy = a36[(g * 9 + k) * 2 + 0];
        float ox = a36[(g * 9 + k) * 2 + 1];
        float py = (float)(h + ky) + oy;
        float px = (float)(w + kx) + ox;
        float y0f = floorf(py), x0f = floorf(px);
        float fy = py - y0f, fx = px - x0f;
        int y0 = (int)y0f, x0 = (int)x0f;
        bool vy0 = ((unsigned)y0 < (unsigned)H);
        bool vy1 = ((unsigned)(y0 + 1) < (unsigned)H);
        bool vx0 = ((unsigned)x0 < (unsigned)H);
        bool vx1 = ((unsigned)(x0 + 1) < (unsigned)H);
        int y0c = min(max(y0, 0), H - 1), y1c = min(max(y0 + 1, 0), H - 1);
        int x0c = min(max(x0, 0), H - 1), x1c = min(max(x0 + 1, 0), H - 1);
        float w00 = (vy0 && vx0) ? (1.f - fy) * (1.f - fx) : 0.f;
        float w01 = (vy0 && vx1) ? (1.f - fy) * fx : 0.f;
        float w10 = (vy1 && vx0) ? fy * (1.f - fx) : 0.f;
        float w11 = (vy1 && vx1) ? fy * fx : 0.f;
        half8 s00 = splat8((_Float16)w00);
        half8 s01 = splat8((_Float16)w01);
        half8 s10 = splat8((_Float16)w10);
        half8 s11 = splat8((_Float16)w11);
        const unsigned short* p00 = f0h + ((size_t)y0c * H + x0c) * 16 + g * 8;
        const unsigned short* p01 = f0h + ((size_t)y0c * H + x1c) * 16 + g * 8;
        const unsigned short* p10 = f0h + ((size_t)y1c * H + x0c) * 16 + g * 8;
        const unsigned short* p11 = f0h + ((size_t)y1c * H + x1c) * 16 + g * 8;
        half8 a00 = *(const half8*)p00;
        half8 a01 = *(const half8*)p01;
        half8 a10 = *(const half8*)p10;
        half8 a11 = *(const half8*)p11;
        half8 vb = a00 * s00 + a01 * s01 + a10 * s10 + a11 * s11;
        uint4 vp = __builtin_bit_cast(uint4, vb);
        unsigned vpa[4] = {vp.x, vp.y, vp.z, vp.w};
        const unsigned* wk2 = wddc2 + ((size_t)k * 2 + g) * 8;
#pragma unroll
        for (int jp = 0; jp < 4; ++jp) {
          rr[0] = dot2acc(vpa[jp], wk2[jp * 2 + 0], rr[0]);
          rr[1] = dot2acc(vpa[jp], wk2[jp * 2 + 1], rr[1]);
        }
      }
    }
    out[((size_t)n * 2 + 0) * HH + (size_t)h * H + w] = rr[0];
    out[((size_t)n * 2 + 1) * HH + (size_t)h * H + w] = rr[1];
  }
}

extern "C" void kernel_launch(void* const* d_in, const int* in_sizes, int n_in,
                              void* d_out, int out_size, void* d_ws, size_t ws_size,
                              hipStream_t stream) {
  auto F = [&](int i) { return (const float*)d_in[i]; };
  const float* ref = F(0);
  const float* unr = F(1);
  const float* few1[3] = {F(2), F(6), F(10)};
  const float* feb1[3] = {F(3), F(7), F(11)};
  const float* few2[3] = {F(4), F(8), F(12)};
  const float* feb2[3] = {F(5), F(9), F(13)};
  const float* obw[3] = {F(14), F(16), F(18)};
  const float* obb[3] = {F(15), F(17), F(19)};
  const float* ogw[3] = {F(20), F(22), F(24)};
  const float* ogb[3] = {F(21), F(23), F(25)};
  const float* dcw[3] = {F(26), F(27), F(28)};
  const float* fcw[3] = {F(29), F(31), F(33)};
  const float* fcb[3] = {F(30), F(32), F(34)};
  const float* dobw = F(35);
  const float* dobb = F(36);
  const float* dogw = F(37);
  const float* dogb = F(38);
  const float* ddcw = F(39);

  // ---- workspace (floats) ----
  float* ws = (float*)d_ws;
  size_t p = 0;
  auto alloc = [&](size_t nf) { float* r = ws + p; p += nf; return r; };
  unsigned short* fH0 = (unsigned short*)alloc((size_t)8 * 16 * 65536 / 2);
  unsigned short* fH1 = (unsigned short*)alloc((size_t)8 * 16 * 16384 / 2);
  unsigned short* fH2 = (unsigned short*)alloc((size_t)8 * 16 * 4096 / 2);
  unsigned short* ftH1 = (unsigned short*)alloc((size_t)4 * 16 * 16384 / 2);
  unsigned short* ftH2 = (unsigned short*)alloc((size_t)4 * 16 * 4096 / 2);
  unsigned short* fHwc = (unsigned short*)alloc((size_t)4 * 16 * 65536 / 2);
  unsigned short* offs0 = (unsigned short*)alloc((size_t)4 * 18 * 65536 / 2);  // f16 HWC [n][px][18]
  unsigned short* offs1 = (unsigned short*)alloc((size_t)4 * 18 * 16384 / 2);
  unsigned short* offs2 = (unsigned short*)alloc((size_t)4 * 18 * 4096 / 2);
  float* wdc2f = alloc(3600);
  float* wmf = alloc(7680);
  float* wm32f = alloc(16200);
  float* wspl = alloc(27648);
  if (p * sizeof(float) > ws_size) return;
  unsigned* wdc2 = (unsigned*)wdc2f;
  unsigned short* wmh = (unsigned short*)wmf;
  unsigned short* wm32 = (unsigned short*)wm32f;
  unsigned short* wsp = (unsigned short*)wspl;

  W32Table T32;
  T32.e[0] = {obw[0], 32}; T32.e[1] = {obw[1], 32}; T32.e[2] = {obw[2], 32};
  T32.e[3] = {dobw, 32};   T32.e[4] = {fcw[0], 32}; T32.e[5] = {fcw[1], 32};
  T32.e[6] = {fcw[2], 16};
  auto o32 = [](int i) { return i * 4608; };

  SPTable TS;
  TS.e[0] = {ogw[0], 34, 18, 2, 0};
  TS.e[1] = {ogw[1], 34, 18, 2, 14336};
  TS.e[2] = {ogw[2], 16, 18, 2, 28672};
  TS.e[3] = {dogw, 34, 36, 3, 33792};
  const int o_og[3] = {0, 14336, 28672};
  const int o_dog = 33792;

  wdcpair_k<<<15, 256, 0, stream>>>(dcw[0], dcw[1], dcw[2], ddcw, wdc2);
  wmfma_k<<<60, 256, 0, stream>>>(few2[0], few1[1], few2[1], few1[2], few2[2],
                                  few1[0], wmh);
  wmfma32_k<<<126, 256, 0, stream>>>(T32, wm32);
  wsplit_k<<<dim3(84, 4), 256, 0, stream>>>(TS, wsp);

  // ---- feature pyramids (all f16 HWC) ----
  fe0_fused_k<<<dim3(32, 32, 8), 256, 0, stream>>>(
      ref, unr, wmh + 5 * 2560, feb1[0], wmh, feb2[0], fH0);
  fe12_fused_k<<<dim3(16, 16, 8), 256, 0, stream>>>(
      fH0, wmh + 2560, feb1[1], wmh + 2 * 2560, feb2[1], fH1, 256);
  fe12_fused_k<<<dim3(8, 8, 8), 256, 0, stream>>>(
      fH1, wmh + 3 * 2560, feb1[2], wmh + 4 * 2560, feb2[2], fH2, 128);

  const unsigned short* uH0 = fH0 + (size_t)4 * 65536 * 16;
  const unsigned short* uH1 = fH1 + (size_t)4 * 16384 * 16;
  const unsigned short* uH2 = fH2 + (size_t)4 * 4096 * 16;

  // ---- coarse-to-fine ----
  obog_k<0><<<dim3(4, 8, 4), 256, 0, stream>>>(
      fH2, uH2, nullptr, wm32 + o32(2), obb[2], wsp + o_og[2], ogb[2], offs2, 64);
  defc_k<0><<<dim3(4, 8, 4), 256, 0, stream>>>(
      uH2, offs2, wdc2 + 2 * 1152, nullptr, wm32 + o32(6), fcb[2], ftH2, 64);
  obog_k<1><<<dim3(8, 16, 4), 256, 0, stream>>>(
      fH1, uH1, offs2, wm32 + o32(1), obb[1], wsp + o_og[1], ogb[1], offs1, 128);
  defc_k<1><<<dim3(8, 16, 4), 256, 0, stream>>>(
      uH1, offs1, wdc2 + 1 * 1152, ftH2, wm32 + o32(5), fcb[1], ftH1, 128);
  obog_k<1><<<dim3(16, 32, 4), 256, 0, stream>>>(
      fH0, uH0, offs1, wm32 + o32(0), obb[0], wsp + o_og[0], ogb[0], offs0, 256);
  defc_k<1><<<dim3(16, 32, 4), 256, 0, stream>>>(
      uH0, offs0, wdc2, ftH1, wm32 + o32(4), fcb[0], fHwc, 256);

  // ---- fused final head ----
  final_k<<<dim3(16, 16, 4), 256, 0, stream>>>(
      fH0, fHwc, offs0, wm32 + o32(3), dobb, wsp + o_dog, dogb, wdc2 + 3456,
      (float*)d_out);
}